// Round 4
// baseline (637.793 us; speedup 1.0000x reference)
//
#include <hip/hip_runtime.h>
#include <hip/hip_bf16.h>
#include <cstddef>
#include <cstdint>

// Problem constants
#define BB   2
#define NN   8192
#define CA   128
#define CS   384
#define CZ   16
#define HH   4
#define DD   32
#define NQW  32      // NQ
#define NKW  128     // NK
#define NBLK 3
#define WW   256     // N / NQ
#define MR   (BB*NN) // 16384 rows
#define HIDN 256     // 2*CA

typedef unsigned short u16;
typedef __attribute__((ext_vector_type(8))) short short8;
typedef __attribute__((ext_vector_type(4))) float floatx4;

__device__ __forceinline__ float sigmoidf_(float x) { return 1.f / (1.f + __expf(-x)); }

__device__ __forceinline__ u16 f2bf(float x) {
  unsigned u = __float_as_uint(x);
  unsigned r = (u + 0x7fffu + ((u >> 16) & 1u)) >> 16;
  return (u16)r;
}
__device__ __forceinline__ float bf2f(u16 u) {
  return __uint_as_float(((unsigned)u) << 16);
}

// Async global->LDS, 16B per lane. LDS dest is wave-uniform base + lane*16.
// LDS layout must be linear in lane order (no padding) -- m173.
__device__ __forceinline__ void gload16(const u16* g, u16* l) {
  __builtin_amdgcn_global_load_lds(
      (const __attribute__((address_space(1))) unsigned int*)g,
      (__attribute__((address_space(3))) unsigned int*)l, 16, 0, 0);
}

// ---------------------------------------------------------------------------
// LayerNorm of s (C_S = 384), one wave per row -> bf16 out.
// ---------------------------------------------------------------------------
__global__ __launch_bounds__(256) void ln_s_kernel(const float* __restrict__ s,
                                                   u16* __restrict__ s_ln_bf) {
  int row  = blockIdx.x * 4 + (threadIdx.x >> 6);
  int lane = threadIdx.x & 63;
  const float* sr = s + (size_t)row * CS;
  float x[6];
  float sum = 0.f, sq = 0.f;
#pragma unroll
  for (int t = 0; t < 6; ++t) { x[t] = sr[lane + 64*t]; sum += x[t]; sq += x[t]*x[t]; }
#pragma unroll
  for (int off = 32; off; off >>= 1) { sum += __shfl_down(sum, off); sq += __shfl_down(sq, off); }
  sum = __shfl(sum, 0); sq = __shfl(sq, 0);
  float mean = sum * (1.f/CS);
  float var  = sq  * (1.f/CS) - mean*mean;
  float rstd = rsqrtf(var + 1e-5f);
  u16* orow = s_ln_bf + (size_t)row * CS;
#pragma unroll
  for (int t = 0; t < 6; ++t) orow[lane + 64*t] = f2bf((x[t]-mean)*rstd);
}

// ---------------------------------------------------------------------------
// LN(a) + adaLN modulation for attention (amod) and transition (tmod), bf16.
// ---------------------------------------------------------------------------
__global__ __launch_bounds__(256) void modln_kernel(const float* __restrict__ a,
                                                    const u16* __restrict__ sp0,
                                                    const u16* __restrict__ sp1,
                                                    const u16* __restrict__ sp3,
                                                    const u16* __restrict__ sp4,
                                                    u16* __restrict__ amod,
                                                    u16* __restrict__ tmod) {
  int row  = blockIdx.x * 4 + (threadIdx.x >> 6);
  int lane = threadIdx.x & 63;
  const float* ar = a + (size_t)row * CA;
  float x0 = ar[lane], x1 = ar[lane + 64];
  float sum = x0 + x1, sq = x0*x0 + x1*x1;
#pragma unroll
  for (int off = 32; off; off >>= 1) { sum += __shfl_down(sum, off); sq += __shfl_down(sq, off); }
  sum = __shfl(sum, 0); sq = __shfl(sq, 0);
  float mean = sum * (1.f/CA);
  float var  = sq  * (1.f/CA) - mean*mean;
  float rstd = rsqrtf(var + 1e-5f);
  float n0 = (x0-mean)*rstd, n1 = (x1-mean)*rstd;
  size_t i0 = (size_t)row * CA + lane;
  amod[i0]      = f2bf(bf2f(sp0[i0])     *n0 + bf2f(sp1[i0]));
  amod[i0 + 64] = f2bf(bf2f(sp0[i0 + 64])*n1 + bf2f(sp1[i0 + 64]));
  tmod[i0]      = f2bf(bf2f(sp3[i0])     *n0 + bf2f(sp4[i0]));
  tmod[i0 + 64] = f2bf(bf2f(sp3[i0 + 64])*n1 + bf2f(sp4[i0 + 64]));
}

// ---------------------------------------------------------------------------
// Weight transpose+convert: src fp32 K x N (row-major)  ->  dst bf16 N x K.
// ---------------------------------------------------------------------------
struct TJob { const float* src; u16* dst; int K; int N; };
struct TJobs { TJob j[42]; };

__global__ __launch_bounds__(256) void transpose_bf16(TJobs jobs) {
  TJob jb = jobs.j[blockIdx.z];
  int tk = blockIdx.x * 32, tn = blockIdx.y * 32;
  if (tk >= jb.K || tn >= jb.N) return;
  __shared__ float tile[32][33];
  int tx = threadIdx.x & 31;
  int ty = threadIdx.x >> 5;
#pragma unroll
  for (int r = ty; r < 32; r += 8) tile[r][tx] = jb.src[(size_t)(tk + r) * jb.N + tn + tx];
  __syncthreads();
#pragma unroll
  for (int r = ty; r < 32; r += 8)
    jb.dst[(size_t)(tn + r) * jb.K + tk + tx] = f2bf(tile[tx][r]);
}

// ---------------------------------------------------------------------------
// bf16 MFMA GEMM, job-fused: J jobs per block SHARING the same A and K.
// 128x128 tile per job, BK=32, 4 waves (2x2 of 64x64).  A k-chunk staged
// ONCE per step, J B-tiles staged alongside; 16*J MFMA per barrier drain.
// modes: 0 = (+bias)->bf16, 1 = sigmoid(+bias)->bf16,
// 4 (DUAL) = silu(A@B)*(A@B2) -> bf16, 5 = transposed bf16 write (V).
// ---------------------------------------------------------------------------
struct GemmJob {
  const u16* A;
  const u16* Bt;
  const u16* Bt2;
  const float* bias;
  u16* outbf;
  int K;
  int ostride;
  int mode;
  int pad;
};
struct GemmJobs { GemmJob j[18]; };

template <int J, bool DUAL>
__global__ __launch_bounds__(256) void gemm_mfma(GemmJobs jobs) {
  const int jbase = blockIdx.z * J;
  const GemmJob jb0 = jobs.j[jbase];
  const int bm = blockIdx.y * 128, bn = blockIdx.x * 128;
  const int K = jb0.K;

  __shared__ u16 As[2][4096];
  __shared__ u16 Bs[2][J][4096];
  __shared__ u16 Bs2[DUAL ? 2 : 1][DUAL ? 4096 : 8];

  const int tid  = threadIdx.x;
  const int lane = tid & 63;
  const int wave = tid >> 6;
  const int wr = wave >> 1, wc = wave & 1;
  const int l15 = lane & 15, quad = lane >> 4;

  floatx4 acc[J][4][4] = {};
  floatx4 acc2[DUAL ? 4 : 1][DUAL ? 4 : 1] = {};

  // staging: wave w stages k-chunk plane c==w (8 u16) for rows h*64+lane.
  const u16* Ab0 = jb0.A + ((size_t)bm + lane) * K + wave * 8;
  const u16* Ab1 = jb0.A + ((size_t)bm + 64 + lane) * K + wave * 8;
  const u16* Bb0[J];
  const u16* Bb1[J];
#pragma unroll
  for (int jj = 0; jj < J; ++jj) {
    const u16* Bt = jobs.j[jbase + jj].Bt;
    Bb0[jj] = Bt + ((size_t)bn + lane) * K + wave * 8;
    Bb1[jj] = Bt + ((size_t)bn + 64 + lane) * K + wave * 8;
  }
  const u16* B2b0 = DUAL ? (jb0.Bt2 + ((size_t)bn + lane) * K + wave * 8) : nullptr;
  const u16* B2b1 = DUAL ? (jb0.Bt2 + ((size_t)bn + 64 + lane) * K + wave * 8) : nullptr;

  auto stage = [&](int k0, int pb) {
    gload16(Ab0 + k0, As[pb] + wave * 1024);
    gload16(Ab1 + k0, As[pb] + wave * 1024 + 512);
#pragma unroll
    for (int jj = 0; jj < J; ++jj) {
      gload16(Bb0[jj] + k0, Bs[pb][jj] + wave * 1024);
      gload16(Bb1[jj] + k0, Bs[pb][jj] + wave * 1024 + 512);
    }
    if constexpr (DUAL) {
      gload16(B2b0 + k0, Bs2[pb] + wave * 1024);
      gload16(B2b1 + k0, Bs2[pb] + wave * 1024 + 512);
    }
  };

  stage(0, 0);
  __syncthreads();          // tile 0 staged (vmcnt0 + barrier)
  int cur = 0;
  for (int k0 = 0; k0 < K; k0 += 32) {
    if (k0 + 32 < K) stage(k0 + 32, cur ^ 1);   // prefetch next tile

    short8 a_frag[4];
#pragma unroll
    for (int mt = 0; mt < 4; ++mt)
      a_frag[mt] = *(const short8*)(As[cur] + quad * 1024 + (wr * 64 + mt * 16 + l15) * 8);
#pragma unroll
    for (int jj = 0; jj < J; ++jj) {
      short8 b_frag[4];
#pragma unroll
      for (int nt = 0; nt < 4; ++nt)
        b_frag[nt] = *(const short8*)(Bs[cur][jj] + quad * 1024 + (wc * 64 + nt * 16 + l15) * 8);
#pragma unroll
      for (int mt = 0; mt < 4; ++mt)
#pragma unroll
        for (int nt = 0; nt < 4; ++nt)
          acc[jj][mt][nt] = __builtin_amdgcn_mfma_f32_16x16x32_bf16(a_frag[mt], b_frag[nt], acc[jj][mt][nt], 0, 0, 0);
    }
    if constexpr (DUAL) {
      short8 b2_frag[4];
#pragma unroll
      for (int nt = 0; nt < 4; ++nt)
        b2_frag[nt] = *(const short8*)(Bs2[cur] + quad * 1024 + (wc * 64 + nt * 16 + l15) * 8);
#pragma unroll
      for (int mt = 0; mt < 4; ++mt)
#pragma unroll
        for (int nt = 0; nt < 4; ++nt)
          acc2[mt][nt] = __builtin_amdgcn_mfma_f32_16x16x32_bf16(a_frag[mt], b2_frag[nt], acc2[mt][nt], 0, 0, 0);
    }
    __syncthreads();        // drains prefetch; next tile ready
    cur ^= 1;
  }

  // Epilogue per job.  C/D layout: col = lane&15, row = quad*4 + reg.
#pragma unroll
  for (int jj = 0; jj < J; ++jj) {
    GemmJob jb = jobs.j[jbase + jj];
#pragma unroll
    for (int mt = 0; mt < 4; ++mt) {
#pragma unroll
      for (int nt = 0; nt < 4; ++nt) {
        int n = bn + wc * 64 + nt * 16 + l15;
        int mbase = bm + wr * 64 + mt * 16 + quad * 4;
        floatx4 v = acc[jj][mt][nt];
        if constexpr (DUAL) {
          floatx4 v2 = acc2[mt][nt];
#pragma unroll
          for (int r = 0; r < 4; ++r) {
            size_t idx = (size_t)(mbase + r) * jb.ostride + n;
            float x1 = v[r];
            jb.outbf[idx] = f2bf(x1 * sigmoidf_(x1) * v2[r]);
          }
        } else if (jb.mode == 5) {
          int bidx = mbase >> 13;          // m / NN
          int tok  = mbase & (NN - 1);
          ushort4 o;
          o.x = f2bf(v[0]); o.y = f2bf(v[1]); o.z = f2bf(v[2]); o.w = f2bf(v[3]);
          *(ushort4*)(jb.outbf + (size_t)(bidx * CA + n) * NN + tok) = o;
        } else {
          float bias = jb.bias ? jb.bias[n] : 0.f;
#pragma unroll
          for (int r = 0; r < 4; ++r) {
            size_t idx = (size_t)(mbase + r) * jb.ostride + n;
            float x = v[r] + bias;
            jb.outbf[idx] = f2bf(jb.mode == 1 ? sigmoidf_(x) : x);
          }
        }
      }
    }
  }
}

// ---------------------------------------------------------------------------
// Combo output kernel: out = (O @ woT)*g1 + (HID @ twoT)*g2, fp32.
// BM=64 (grid 256 blocks -> all CUs), pass-fused: one 8-step pipeline,
// steps 0-3 compute BOTH passes (pass1 K=128 + pass2 first half), 4-7 pass2.
// ---------------------------------------------------------------------------
__global__ __launch_bounds__(256) void combo_kernel(const u16* __restrict__ O,
                                                    const u16* __restrict__ HID,
                                                    const u16* __restrict__ woT,
                                                    const u16* __restrict__ twoT,
                                                    const u16* __restrict__ g1,
                                                    const u16* __restrict__ g2,
                                                    float* __restrict__ outp) {
  const int bm = blockIdx.y * 64;
  __shared__ u16 As1[2][2048];
  __shared__ u16 Bs1[2][4096];
  __shared__ u16 As2[2][2048];
  __shared__ u16 Bs2h[2][4096];
  const int tid  = threadIdx.x;
  const int lane = tid & 63;
  const int wave = tid >> 6;
  const int wr = wave >> 1, wc = wave & 1;
  const int l15 = lane & 15, quad = lane >> 4;

  floatx4 acc1[2][4] = {};
  floatx4 acc2[2][4] = {};

  const u16* A1  = O    + ((size_t)bm + lane) * CA + wave * 8;
  const u16* B10 = woT  + ((size_t)lane) * CA + wave * 8;
  const u16* B11 = woT  + ((size_t)64 + lane) * CA + wave * 8;
  const u16* A2  = HID  + ((size_t)bm + lane) * HIDN + wave * 8;
  const u16* B20 = twoT + ((size_t)lane) * HIDN + wave * 8;
  const u16* B21 = twoT + ((size_t)64 + lane) * HIDN + wave * 8;

  auto stage1 = [&](int k0, int pb) {
    gload16(A1  + k0, As1[pb] + wave * 512);
    gload16(B10 + k0, Bs1[pb] + wave * 1024);
    gload16(B11 + k0, Bs1[pb] + wave * 1024 + 512);
  };
  auto stage2 = [&](int k0, int pb) {
    gload16(A2  + k0, As2[pb] + wave * 512);
    gload16(B20 + k0, Bs2h[pb] + wave * 1024);
    gload16(B21 + k0, Bs2h[pb] + wave * 1024 + 512);
  };

  stage1(0, 0);
  stage2(0, 0);
  __syncthreads();
  int cur = 0;
  for (int t = 0; t < 8; ++t) {
    if (t + 1 < 4) stage1((t + 1) * 32, cur ^ 1);
    if (t + 1 < 8) stage2((t + 1) * 32, cur ^ 1);

    if (t < 4) {
      short8 a_frag[2], b_frag[4];
#pragma unroll
      for (int mt = 0; mt < 2; ++mt)
        a_frag[mt] = *(const short8*)(As1[cur] + quad * 512 + (wr * 32 + mt * 16 + l15) * 8);
#pragma unroll
      for (int nt = 0; nt < 4; ++nt)
        b_frag[nt] = *(const short8*)(Bs1[cur] + quad * 1024 + (wc * 64 + nt * 16 + l15) * 8);
#pragma unroll
      for (int mt = 0; mt < 2; ++mt)
#pragma unroll
        for (int nt = 0; nt < 4; ++nt)
          acc1[mt][nt] = __builtin_amdgcn_mfma_f32_16x16x32_bf16(a_frag[mt], b_frag[nt], acc1[mt][nt], 0, 0, 0);
    }
    {
      short8 a_frag[2], b_frag[4];
#pragma unroll
      for (int mt = 0; mt < 2; ++mt)
        a_frag[mt] = *(const short8*)(As2[cur] + quad * 512 + (wr * 32 + mt * 16 + l15) * 8);
#pragma unroll
      for (int nt = 0; nt < 4; ++nt)
        b_frag[nt] = *(const short8*)(Bs2h[cur] + quad * 1024 + (wc * 64 + nt * 16 + l15) * 8);
#pragma unroll
      for (int mt = 0; mt < 2; ++mt)
#pragma unroll
        for (int nt = 0; nt < 4; ++nt)
          acc2[mt][nt] = __builtin_amdgcn_mfma_f32_16x16x32_bf16(a_frag[mt], b_frag[nt], acc2[mt][nt], 0, 0, 0);
    }
    __syncthreads();
    cur ^= 1;
  }

#pragma unroll
  for (int mt = 0; mt < 2; ++mt) {
#pragma unroll
    for (int nt = 0; nt < 4; ++nt) {
      int n = wc * 64 + nt * 16 + l15;
      int mbase = bm + wr * 32 + mt * 16 + quad * 4;
#pragma unroll
      for (int r = 0; r < 4; ++r) {
        size_t idx = (size_t)(mbase + r) * CA + n;
        outp[idx] = acc1[mt][nt][r] * bf2f(g1[idx]) + acc2[mt][nt][r] * bf2f(g2[idx]);
      }
    }
  }
}

// ---------------------------------------------------------------------------
// Pair bias for ALL 3 blocks in one pass over p; no LDS transpose, direct
// ushort4 stores.  Grid (4 k-chunks, W, B).
// Output layout: biasT[i][b][w][h][k][q] (bf16).
// ---------------------------------------------------------------------------
__global__ __launch_bounds__(256) void bias3_kernel(const float* __restrict__ p,
                                                    const float* __restrict__ lnz_w,
                                                    const float* __restrict__ lnz_b,
                                                    const float* __restrict__ wb,
                                                    u16* __restrict__ biasT) {
  const int kc = blockIdx.x, w = blockIdx.y, b = blockIdx.z;
  __shared__ float effW[12][16];
  __shared__ float effb[12];
  const int t = threadIdx.x;
  if (t < 192) {
    int i = t >> 6, rem = t & 63, z = rem >> 2, hh = rem & 3;
    effW[i*4 + hh][z] = lnz_w[i*CZ + z] * wb[(i*CZ + z)*HH + hh];
  }
  if (t < 12) {
    int i = t >> 2, hh = t & 3;
    float acc = 0.f;
    for (int z = 0; z < 16; ++z) acc += lnz_b[i*CZ + z] * wb[(i*CZ + z)*HH + hh];
    effb[t] = acc;
  }
  __syncthreads();

  const int kk = t & 31, qg = (t >> 5) * 4;
  const int k = kc * 32 + kk;
  u16 out4[12][4];
#pragma unroll
  for (int r = 0; r < 4; ++r) {
    int qq = qg + r;
    const float4* pr = (const float4*)(p + (size_t)(((b * WW + w) * NQW + qq) * NKW + k) * 16);
    float4 p0 = pr[0], p1 = pr[1], p2 = pr[2], p3 = pr[3];
    float x[16] = {p0.x,p0.y,p0.z,p0.w, p1.x,p1.y,p1.z,p1.w,
                   p2.x,p2.y,p2.z,p2.w, p3.x,p3.y,p3.z,p3.w};
    float sum = 0.f, sq = 0.f;
#pragma unroll
    for (int z = 0; z < 16; ++z) { sum += x[z]; sq += x[z]*x[z]; }
    float mean = sum * (1.f/16.f);
    float var  = sq  * (1.f/16.f) - mean*mean;
    float rstd = rsqrtf(var + 1e-5f);
#pragma unroll
    for (int ih = 0; ih < 12; ++ih) {
      float acc = effb[ih];
#pragma unroll
      for (int z = 0; z < 16; ++z) acc += (x[z]-mean)*rstd * effW[ih][z];
      out4[ih][r] = f2bf(acc);
    }
  }
#pragma unroll
  for (int ih = 0; ih < 12; ++ih) {
    int i = ih >> 2, hh = ih & 3;
    u16* dst = biasT + ((((size_t)i * BB + b) * WW + w) * HH + hh) * 4096 + (size_t)k * 32 + qg;
    ushort4 uv; uv.x = out4[ih][0]; uv.y = out4[ih][1]; uv.z = out4[ih][2]; uv.w = out4[ih][3];
    *(ushort4*)dst = uv;
  }
}

// ---------------------------------------------------------------------------
// MFMA windowed attention: one WAVE per (w, h, b).
// ---------------------------------------------------------------------------
__global__ __launch_bounds__(64) void attn_mfma(const u16* __restrict__ Qb,
                                                const u16* __restrict__ Kb,
                                                const u16* __restrict__ Vtb,
                                                const u16* __restrict__ Gb,
                                                const u16* __restrict__ biasT,
                                                u16* __restrict__ Ob) {
  const int w = blockIdx.x, h = blockIdx.y, b = blockIdx.z;
  __shared__ u16 Pt[128 * 36];
  __shared__ float inv_s[32];
  const int lane = threadIdx.x;
  const int l15 = lane & 15, quad = lane >> 4;
  const int tok0 = w * NQW - 48;

  short8 qf[2];
#pragma unroll
  for (int mt = 0; mt < 2; ++mt) {
    int qq = w * NQW + mt * 16 + l15;
    qf[mt] = *(const short8*)(Qb + (size_t)(b * NN + qq) * CA + h * DD + quad * 8);
  }
  floatx4 lg[2][8] = {};
#pragma unroll
  for (int nt = 0; nt < 8; ++nt) {
    int tk = tok0 + nt * 16 + l15;
    int tc = min(max(tk, 0), NN - 1);
    short8 kf = *(const short8*)(Kb + (size_t)(b * NN + tc) * CA + h * DD + quad * 8);
#pragma unroll
    for (int mt = 0; mt < 2; ++mt)
      lg[mt][nt] = __builtin_amdgcn_mfma_f32_16x16x32_bf16(qf[mt], kf, lg[mt][nt], 0, 0, 0);
  }

  const float scale = 0.17677669529663687f;   // 1/sqrt(32)
  const u16* bb = biasT + ((((size_t)b * WW + w) * HH + h) << 12);
  float mrow[2][4];
#pragma unroll
  for (int mt = 0; mt < 2; ++mt)
#pragma unroll
    for (int r = 0; r < 4; ++r) mrow[mt][r] = -3.0e38f;
#pragma unroll
  for (int nt = 0; nt < 8; ++nt) {
    int tk = tok0 + nt * 16 + l15;
    bool valid = (tk >= 0) && (tk < NN);
#pragma unroll
    for (int mt = 0; mt < 2; ++mt) {
      ushort4 bv = *(const ushort4*)(bb + (nt * 16 + l15) * 32 + mt * 16 + quad * 4);
      float bvf[4] = {bf2f(bv.x), bf2f(bv.y), bf2f(bv.z), bf2f(bv.w)};
#pragma unroll
      for (int r = 0; r < 4; ++r) {
        float l = valid ? (lg[mt][nt][r] * scale + bvf[r]) : -1e9f;
        lg[mt][nt][r] = l;
        mrow[mt][r] = fmaxf(mrow[mt][r], l);
      }
    }
  }
#pragma unroll
  for (int mt = 0; mt < 2; ++mt)
#pragma unroll
    for (int r = 0; r < 4; ++r) {
      float m = mrow[mt][r];
      m = fmaxf(m, __shfl_xor(m, 1));
      m = fmaxf(m, __shfl_xor(m, 2));
      m = fmaxf(m, __shfl_xor(m, 4));
      m = fmaxf(m, __shfl_xor(m, 8));
      mrow[mt][r] = m;
    }

  float srow[2][4] = {};
#pragma unroll
  for (int nt = 0; nt < 8; ++nt)
#pragma unroll
    for (int mt = 0; mt < 2; ++mt) {
      u16 pv[4];
#pragma unroll
      for (int r = 0; r < 4; ++r) {
        float e = __expf(lg[mt][nt][r] - mrow[mt][r]);
        srow[mt][r] += e;
        pv[r] = f2bf(e);
      }
      ushort4 uv; uv.x = pv[0]; uv.y = pv[1]; uv.z = pv[2]; uv.w = pv[3];
      *(ushort4*)(Pt + (nt * 16 + l15) * 36 + mt * 16 + quad * 4) = uv;
    }
#pragma unroll
  for (int mt = 0; mt < 2; ++mt)
#pragma unroll
    for (int r = 0; r < 4; ++r) {
      float ssum = srow[mt][r];
      ssum += __shfl_xor(ssum, 1);
      ssum += __shfl_xor(ssum, 2);
      ssum += __shfl_xor(ssum, 4);
      ssum += __shfl_xor(ssum, 8);
      if (l15 == 0) inv_s[mt * 16 + quad * 4 + r] = 1.f / ssum;
    }
  __syncthreads();

  floatx4 oacc[2][2] = {};
#pragma unroll
  for (int ks = 0; ks < 4; ++ks) {
    short8 pf[2];
#pragma unroll
    for (int ntq = 0; ntq < 2; ++ntq)
#pragma unroll
      for (int j = 0; j < 8; ++j)
        pf[ntq][j] = (short)Pt[(ks * 32 + quad * 8 + j) * 36 + ntq * 16 + l15];
    int tb = tok0 + ks * 32 + quad * 8;
    tb = min(max(tb, 0), NN - 8);
#pragma unroll
    for (int mtd = 0; mtd < 2; ++mtd) {
      short8 vf = *(const short8*)(Vtb + (size_t)(b * CA + h * DD + mtd * 16 + l15) * NN + tb);
#pragma unroll
      for (int ntq = 0; ntq < 2; ++ntq)
        oacc[mtd][ntq] = __builtin_amdgcn_mfma_f32_16x16x32_bf16(vf, pf[ntq], oacc[mtd][ntq], 0, 0, 0);
    }
  }

#pragma unroll
  for (int mtd = 0; mtd < 2; ++mtd)
#pragma unroll
    for (int ntq = 0; ntq < 2; ++ntq) {
      int qq = ntq * 16 + l15;
      float inv = inv_s[qq];
      int tok = w * NQW + qq;
      size_t base = (size_t)(b * NN + tok) * CA + h * DD + mtd * 16 + quad * 4;
      ushort4 gv = *(const ushort4*)(Gb + base);
      floatx4 v = oacc[mtd][ntq];
      ushort4 o;
      o.x = f2bf(bf2f(gv.x) * v[0] * inv);
      o.y = f2bf(bf2f(gv.y) * v[1] * inv);
      o.z = f2bf(bf2f(gv.z) * v[2] * inv);
      o.w = f2bf(bf2f(gv.w) * v[3] * inv);
      *(ushort4*)(Ob + base) = o;
    }
}

// ---------------------------------------------------------------------------
// Host-side orchestration.
// ---------------------------------------------------------------------------
extern "C" void kernel_launch(void* const* d_in, const int* in_sizes, int n_in,
                              void* d_out, int out_size, void* d_ws, size_t ws_size,
                              hipStream_t stream) {
  const float* q             = (const float*)d_in[0];
  const float* s             = (const float*)d_in[1];
  const float* p             = (const float*)d_in[2];
  const float* adaln_scale_w = (const float*)d_in[3];
  const float* adaln_scale_b = (const float*)d_in[4];
  const float* adaln_shift_w = (const float*)d_in[5];
  const float* wq            = (const float*)d_in[6];
  const float* bq            = (const float*)d_in[7];
  const float* wk            = (const float*)d_in[8];
  const float* wv            = (const float*)d_in[9];
  const float* lnz_w         = (const float*)d_in[10];
  const float* lnz_b         = (const float*)d_in[11];
  const float* wb_pair       = (const float*)d_in[12];
  const float* wg            = (const float*)d_in[13];
  const float* wo            = (const float*)d_in[14];
  const float* sgate_w       = (const float*)d_in[15];
  const float* sgate_b       = (const float*)d_in[16];
  const float* t_scale_w     = (const float*)d_in[17];
  const float* t_scale_b     = (const float*)d_in[18];
  const float* t_shift_w     = (const float*)d_in[19];
  const float* t_wa          = (const float*)d_in[20];
  const float* t_wb          = (const float*)d_in[21];
  const float* t_wo          = (const float*)d_in[22];
  const float* t_sgate_w     = (const float*)d_in[23];
  const float* t_sgate_b     = (const float*)d_in[24];
  float* out = (float*)d_out;

  const size_t MC = (size_t)MR * CA; // 2097152
  float* fws   = (float*)d_ws;
  float* abuf0 = fws;
  float* abuf1 = abuf0 + MC;
  u16* uws     = (u16*)(abuf1 + MC);
  u16* s_ln_bf = uws;                          // MR*CS
  u16* SP      = s_ln_bf + (size_t)MR * CS;    // 18*MC
  u16* amod    = SP + 18*MC;
  u16* tmod    = amod + MC;
  u16* Qb      = tmod + MC;
  u16* Kb      = Qb + MC;
  u16* Vtb     = Kb + MC;                      // [b][128][NN]
  u16* Gb      = Vtb + MC;
  u16* Ob      = Gb + MC;
  u16* HIDb    = Ob + MC;                      // MR*HIDN = 2*MC
  u16* biasT   = HIDb + 2*MC;                  // 3*BB*WW*HH*4096
  u16* wbuf    = biasT + (size_t)3*BB*WW*HH*NQW*NKW;

  const size_t WBLK = 6*(size_t)CA*CS + 5*(size_t)CA*CA + 3*(size_t)CA*HIDN;
  const size_t o_ascale = 0;
  const size_t o_ashift = o_ascale + (size_t)CA*CS;
  const size_t o_sgate  = o_ashift + (size_t)CA*CS;
  const size_t o_tscale = o_sgate  + (size_t)CA*CS;
  const size_t o_tshift = o_tscale + (size_t)CA*CS;
  const size_t o_tsgate = o_tshift + (size_t)CA*CS;
  const size_t o_wq     = o_tsgate + (size_t)CA*CS;
  const size_t o_wk     = o_wq + (size_t)CA*CA;
  const size_t o_wv     = o_wk + (size_t)CA*CA;
  const size_t o_wg     = o_wv + (size_t)CA*CA;
  const size_t o_wo     = o_wg + (size_t)CA*CA;
  const size_t o_twa    = o_wo + (size_t)CA*CA;
  const size_t o_twb    = o_twa + (size_t)HIDN*CA;
  const size_t o_two    = o_twb + (size_t)HIDN*CA;

  // ---- one-time work ----
  ln_s_kernel<<<MR/4, 256, 0, stream>>>(s, s_ln_bf);

  TJobs tj;
  for (int i = 0; i < NBLK; ++i) {
    u16* wb0 = wbuf + (size_t)i * WBLK;
    int b14 = i * 14;
    tj.j[b14+0]  = TJob{adaln_scale_w + (size_t)i*CS*CA, wb0 + o_ascale, CS, CA};
    tj.j[b14+1]  = TJob{adaln_shift_w + (size_t)i*CS*CA, wb0 + o_ashift, CS, CA};
    tj.j[b14+2]  = TJob{sgate_w       + (size_t)i*CS*CA, wb0 + o_sgate,  CS, CA};
    tj.j[b14+3]  = TJob{t_scale_w     + (size_t)i*CS*CA, wb0 + o_tscale, CS, CA};
    tj.j[b14+4]  = TJob{t_shift_w     + (size_t)i*CS*CA, wb0 + o_tshift, CS, CA};
    tj.j[b14+5]  = TJob{t_sgate_w     + (size_t)i*CS*CA, wb0 + o_tsgate, CS, CA};
    tj.j[b14+6]  = TJob{wq   + (size_t)i*CA*CA,   wb0 + o_wq,  CA, CA};
    tj.j[b14+7]  = TJob{wk   + (size_t)i*CA*CA,   wb0 + o_wk,  CA, CA};
    tj.j[b14+8]  = TJob{wv   + (size_t)i*CA*CA,   wb0 + o_wv,  CA, CA};
    tj.j[b14+9]  = TJob{wg   + (size_t)i*CA*CA,   wb0 + o_wg,  CA, CA};
    tj.j[b14+10] = TJob{wo   + (size_t)i*CA*CA,   wb0 + o_wo,  CA, CA};
    tj.j[b14+11] = TJob{t_wa + (size_t)i*CA*HIDN, wb0 + o_twa, CA, HIDN};
    tj.j[b14+12] = TJob{t_wb + (size_t)i*CA*HIDN, wb0 + o_twb, CA, HIDN};
    tj.j[b14+13] = TJob{t_wo + (size_t)i*HIDN*CA, wb0 + o_two, HIDN, CA};
  }
  transpose_bf16<<<dim3(12, 8, 42), 256, 0, stream>>>(tj);

  bias3_kernel<<<dim3(4, WW, BB), 256, 0, stream>>>(p, lnz_w, lnz_b, wb_pair, biasT);

  // ALL 18 s_ln projections (iteration-invariant), J=3 job-fused (shared A)
  {
    GemmJobs js = {};
    for (int i = 0; i < NBLK; ++i) {
      u16* wb0 = wbuf + (size_t)i * WBLK;
      js.j[i*6+0] = GemmJob{s_ln_bf, wb0 + o_ascale, nullptr, adaln_scale_b + i*CA, SP + (i*6+0)*MC, CS, CA, 1, 0};
      js.j[i*6+1] = GemmJob{s_ln_bf, wb0 + o_ashift, nullptr, nullptr,              SP + (i*6+1)*MC, CS, CA, 0, 0};
      js.j[i*6+2] = GemmJob{s_ln_bf, wb0 + o_sgate,  nullptr, sgate_b   + i*CA,     SP + (i*6+2)*MC, CS, CA, 1, 0};
      js.j[i*6+3] = GemmJob{s_ln_bf, wb0 + o_tscale, nullptr, t_scale_b + i*CA,     SP + (i*6+3)*MC, CS, CA, 1, 0};
      js.j[i*6+4] = GemmJob{s_ln_bf, wb0 + o_tshift, nullptr, nullptr,              SP + (i*6+4)*MC, CS, CA, 0, 0};
      js.j[i*6+5] = GemmJob{s_ln_bf, wb0 + o_tsgate, nullptr, t_sgate_b + i*CA,     SP + (i*6+5)*MC, CS, CA, 1, 0};
    }
    gemm_mfma<3, false><<<dim3(1, MR/128, 6), 256, 0, stream>>>(js);
  }

  for (int i = 0; i < NBLK; ++i) {
    const float* a_in = (i == 0) ? q : (i == 1 ? abuf0 : abuf1);
    float* a_out = (i == 2) ? out : (i == 0 ? abuf0 : abuf1);
    u16* wb0 = wbuf + (size_t)i * WBLK;

    // LN(a) + both modulations -> bf16
    modln_kernel<<<MR/4, 256, 0, stream>>>(a_in, SP + (i*6+0)*MC, SP + (i*6+1)*MC,
                                           SP + (i*6+3)*MC, SP + (i*6+4)*MC, amod, tmod);

    // Q, K, V(transposed), G projections -> bf16, J=2 job-fused (shared amod)
    GemmJobs jq = {};
    jq.j[0] = GemmJob{amod, wb0 + o_wq, nullptr, bq + i*CA, Qb,  CA, CA, 0, 0};
    jq.j[1] = GemmJob{amod, wb0 + o_wk, nullptr, nullptr,   Kb,  CA, CA, 0, 0};
    jq.j[2] = GemmJob{amod, wb0 + o_wv, nullptr, nullptr,   Vtb, CA, CA, 5, 0};
    jq.j[3] = GemmJob{amod, wb0 + o_wg, nullptr, nullptr,   Gb,  CA, CA, 1, 0};
    gemm_mfma<2, false><<<dim3(1, MR/128, 2), 256, 0, stream>>>(jq);

    // hidden = silu(tmod @ t_wa) * (tmod @ t_wb)  -> bf16 (N=256)
    GemmJobs jh = {};
    jh.j[0] = GemmJob{tmod, wb0 + o_twa, wb0 + o_twb, nullptr, HIDb, CA, HIDN, 4, 0};
    gemm_mfma<1, true><<<dim3(2, MR/128, 1), 256, 0, stream>>>(jh);

    // windowed attention (MFMA, g-gated bf16 out)
    attn_mfma<<<dim3(WW, HH, BB), 64, 0, stream>>>(
        Qb, Kb, Vtb, Gb, biasT + (size_t)i * BB*WW*HH*4096, Ob);

    // a_out = (O @ wo)*sgate + (HID @ two)*tsgate
    combo_kernel<<<dim3(1, MR/64), 256, 0, stream>>>(
        Ob, HIDb, wb0 + o_wo, wb0 + o_two,
        SP + (i*6+2)*MC, SP + (i*6+5)*MC, a_out);
  }
}

// Round 5
// 576.871 us; speedup vs baseline: 1.1056x; 1.1056x over previous
//
#include <hip/hip_runtime.h>
#include <hip/hip_bf16.h>
#include <cstddef>
#include <cstdint>

// Problem constants
#define BB   2
#define NN   8192
#define CA   128
#define CS   384
#define CZ   16
#define HH   4
#define DD   32
#define NQW  32      // NQ
#define NKW  128     // NK
#define NBLK 3
#define WW   256     // N / NQ
#define MR   (BB*NN) // 16384 rows
#define HIDN 256     // 2*CA

typedef unsigned short u16;
typedef __attribute__((ext_vector_type(8))) short short8;
typedef __attribute__((ext_vector_type(4))) float floatx4;

__device__ __forceinline__ float sigmoidf_(float x) { return 1.f / (1.f + __expf(-x)); }

__device__ __forceinline__ u16 f2bf(float x) {
  unsigned u = __float_as_uint(x);
  unsigned r = (u + 0x7fffu + ((u >> 16) & 1u)) >> 16;
  return (u16)r;
}
__device__ __forceinline__ float bf2f(u16 u) {
  return __uint_as_float(((unsigned)u) << 16);
}

// Async global->LDS, 16B per lane. LDS dest is wave-uniform base + lane*16.
// LDS layout must be linear in lane order (no padding) -- m173.
__device__ __forceinline__ void gload16(const u16* g, u16* l) {
  __builtin_amdgcn_global_load_lds(
      (const __attribute__((address_space(1))) unsigned int*)g,
      (__attribute__((address_space(3))) unsigned int*)l, 16, 0, 0);
}

// ---------------------------------------------------------------------------
// LayerNorm of s (C_S = 384), one wave per row -> bf16 out.
// ---------------------------------------------------------------------------
__global__ __launch_bounds__(256) void ln_s_kernel(const float* __restrict__ s,
                                                   u16* __restrict__ s_ln_bf) {
  int row  = blockIdx.x * 4 + (threadIdx.x >> 6);
  int lane = threadIdx.x & 63;
  const float* sr = s + (size_t)row * CS;
  float x[6];
  float sum = 0.f, sq = 0.f;
#pragma unroll
  for (int t = 0; t < 6; ++t) { x[t] = sr[lane + 64*t]; sum += x[t]; sq += x[t]*x[t]; }
#pragma unroll
  for (int off = 32; off; off >>= 1) { sum += __shfl_down(sum, off); sq += __shfl_down(sq, off); }
  sum = __shfl(sum, 0); sq = __shfl(sq, 0);
  float mean = sum * (1.f/CS);
  float var  = sq  * (1.f/CS) - mean*mean;
  float rstd = rsqrtf(var + 1e-5f);
  u16* orow = s_ln_bf + (size_t)row * CS;
#pragma unroll
  for (int t = 0; t < 6; ++t) orow[lane + 64*t] = f2bf((x[t]-mean)*rstd);
}

// ---------------------------------------------------------------------------
// LN(a) + adaLN modulation for attention (amod) and transition (tmod), bf16.
// ---------------------------------------------------------------------------
__global__ __launch_bounds__(256) void modln_kernel(const float* __restrict__ a,
                                                    const u16* __restrict__ sp0,
                                                    const u16* __restrict__ sp1,
                                                    const u16* __restrict__ sp3,
                                                    const u16* __restrict__ sp4,
                                                    u16* __restrict__ amod,
                                                    u16* __restrict__ tmod) {
  int row  = blockIdx.x * 4 + (threadIdx.x >> 6);
  int lane = threadIdx.x & 63;
  const float* ar = a + (size_t)row * CA;
  float x0 = ar[lane], x1 = ar[lane + 64];
  float sum = x0 + x1, sq = x0*x0 + x1*x1;
#pragma unroll
  for (int off = 32; off; off >>= 1) { sum += __shfl_down(sum, off); sq += __shfl_down(sq, off); }
  sum = __shfl(sum, 0); sq = __shfl(sq, 0);
  float mean = sum * (1.f/CA);
  float var  = sq  * (1.f/CA) - mean*mean;
  float rstd = rsqrtf(var + 1e-5f);
  float n0 = (x0-mean)*rstd, n1 = (x1-mean)*rstd;
  size_t i0 = (size_t)row * CA + lane;
  amod[i0]      = f2bf(bf2f(sp0[i0])     *n0 + bf2f(sp1[i0]));
  amod[i0 + 64] = f2bf(bf2f(sp0[i0 + 64])*n1 + bf2f(sp1[i0 + 64]));
  tmod[i0]      = f2bf(bf2f(sp3[i0])     *n0 + bf2f(sp4[i0]));
  tmod[i0 + 64] = f2bf(bf2f(sp3[i0 + 64])*n1 + bf2f(sp4[i0 + 64]));
}

// ---------------------------------------------------------------------------
// Weight transpose+convert: src fp32 K x N (row-major)  ->  dst bf16 N x K.
// ---------------------------------------------------------------------------
struct TJob { const float* src; u16* dst; int K; int N; };
struct TJobs { TJob j[42]; };

__global__ __launch_bounds__(256) void transpose_bf16(TJobs jobs) {
  TJob jb = jobs.j[blockIdx.z];
  int tk = blockIdx.x * 32, tn = blockIdx.y * 32;
  if (tk >= jb.K || tn >= jb.N) return;
  __shared__ float tile[32][33];
  int tx = threadIdx.x & 31;
  int ty = threadIdx.x >> 5;
#pragma unroll
  for (int r = ty; r < 32; r += 8) tile[r][tx] = jb.src[(size_t)(tk + r) * jb.N + tn + tx];
  __syncthreads();
#pragma unroll
  for (int r = ty; r < 32; r += 8)
    jb.dst[(size_t)(tn + r) * jb.K + tk + tx] = f2bf(tile[tx][r]);
}

// ---------------------------------------------------------------------------
// bf16 MFMA GEMM.  128x128 block tile, BK=32, 4 waves (2x2 of 64x64).
// 2-phase dbuf global_load_lds pipeline (one barrier drain per k-step).
// 1-D grid, job-fastest decode + bijective XCD chunk swizzle: co-resident
// blocks on an XCD share the A strip (jobs adjacent) -> A/B L2-resident.
// modes: 0 = (+bias)->bf16, 1 = sigmoid(+bias)->bf16,
// 4 (DUAL) = silu(A@B)*(A@B2) -> bf16, 5 = transposed bf16 write (V).
// ---------------------------------------------------------------------------
struct GemmJob {
  const u16* A;
  const u16* Bt;
  const u16* Bt2;
  const float* bias;
  u16* outbf;
  int K;
  int ostride;
  int mode;
  int pad;
};
struct GemmJobs { GemmJob j[18]; };

template <int NJ, int NX, bool DUAL>
__global__ __launch_bounds__(256) void gemm_mfma(GemmJobs jobs) {
  constexpr int NWG = NJ * NX * (MR / 128);           // total blocks, % 8 == 0
  const int lin = blockIdx.x;
  const int swz = (lin & 7) * (NWG >> 3) + (lin >> 3); // XCD chunk swizzle
  const int job  = swz % NJ;                           // job fastest: A reuse
  const int rest = swz / NJ;
  const int bn = (rest % NX) * 128;
  const int bm = (rest / NX) * 128;

  GemmJob jb = jobs.j[job];
  const int K = jb.K;

  __shared__ u16 As[2][4096];
  __shared__ u16 Bs[2][4096];
  __shared__ u16 Bs2[DUAL ? 2 : 1][DUAL ? 4096 : 8];

  const int tid  = threadIdx.x;
  const int lane = tid & 63;
  const int wave = tid >> 6;
  const int wr = wave >> 1, wc = wave & 1;
  const int l15 = lane & 15, quad = lane >> 4;

  floatx4 acc[4][4] = {};
  floatx4 acc2[DUAL ? 4 : 1][DUAL ? 4 : 1] = {};

  // staging: wave w stages k-chunk plane c==w (8 u16) for rows h*64+lane.
  const u16* Ab0  = jb.A  + ((size_t)bm + lane) * K + wave * 8;
  const u16* Ab1  = jb.A  + ((size_t)bm + 64 + lane) * K + wave * 8;
  const u16* Bb0  = jb.Bt + ((size_t)bn + lane) * K + wave * 8;
  const u16* Bb1  = jb.Bt + ((size_t)bn + 64 + lane) * K + wave * 8;
  const u16* B2b0 = DUAL ? (jb.Bt2 + ((size_t)bn + lane) * K + wave * 8) : nullptr;
  const u16* B2b1 = DUAL ? (jb.Bt2 + ((size_t)bn + 64 + lane) * K + wave * 8) : nullptr;

  auto stage = [&](int k0, int pb) {
    gload16(Ab0 + k0, As[pb] + wave * 1024);
    gload16(Ab1 + k0, As[pb] + wave * 1024 + 512);
    gload16(Bb0 + k0, Bs[pb] + wave * 1024);
    gload16(Bb1 + k0, Bs[pb] + wave * 1024 + 512);
    if constexpr (DUAL) {
      gload16(B2b0 + k0, Bs2[pb] + wave * 1024);
      gload16(B2b1 + k0, Bs2[pb] + wave * 1024 + 512);
    }
  };

  stage(0, 0);
  __syncthreads();          // tile 0 staged (vmcnt0 + barrier)
  int cur = 0;
  for (int k0 = 0; k0 < K; k0 += 32) {
    if (k0 + 32 < K) stage(k0 + 32, cur ^ 1);   // prefetch next tile

    short8 a_frag[4], b_frag[4];
#pragma unroll
    for (int mt = 0; mt < 4; ++mt)
      a_frag[mt] = *(const short8*)(As[cur] + quad * 1024 + (wr * 64 + mt * 16 + l15) * 8);
#pragma unroll
    for (int nt = 0; nt < 4; ++nt)
      b_frag[nt] = *(const short8*)(Bs[cur] + quad * 1024 + (wc * 64 + nt * 16 + l15) * 8);
#pragma unroll
    for (int mt = 0; mt < 4; ++mt)
#pragma unroll
      for (int nt = 0; nt < 4; ++nt)
        acc[mt][nt] = __builtin_amdgcn_mfma_f32_16x16x32_bf16(a_frag[mt], b_frag[nt], acc[mt][nt], 0, 0, 0);
    if constexpr (DUAL) {
      short8 b2_frag[4];
#pragma unroll
      for (int nt = 0; nt < 4; ++nt)
        b2_frag[nt] = *(const short8*)(Bs2[cur] + quad * 1024 + (wc * 64 + nt * 16 + l15) * 8);
#pragma unroll
      for (int mt = 0; mt < 4; ++mt)
#pragma unroll
        for (int nt = 0; nt < 4; ++nt)
          acc2[mt][nt] = __builtin_amdgcn_mfma_f32_16x16x32_bf16(a_frag[mt], b2_frag[nt], acc2[mt][nt], 0, 0, 0);
    }
    __syncthreads();        // drains prefetch; next tile ready
    cur ^= 1;
  }

  // Epilogue.  C/D layout: col = lane&15, row = quad*4 + reg.
#pragma unroll
  for (int mt = 0; mt < 4; ++mt) {
#pragma unroll
    for (int nt = 0; nt < 4; ++nt) {
      int n = bn + wc * 64 + nt * 16 + l15;
      int mbase = bm + wr * 64 + mt * 16 + quad * 4;
      floatx4 v = acc[mt][nt];
      if constexpr (DUAL) {
        floatx4 v2 = acc2[mt][nt];
#pragma unroll
        for (int r = 0; r < 4; ++r) {
          size_t idx = (size_t)(mbase + r) * jb.ostride + n;
          float x1 = v[r];
          jb.outbf[idx] = f2bf(x1 * sigmoidf_(x1) * v2[r]);
        }
      } else if (jb.mode == 5) {
        int bidx = mbase >> 13;          // m / NN
        int tok  = mbase & (NN - 1);
        ushort4 o;
        o.x = f2bf(v[0]); o.y = f2bf(v[1]); o.z = f2bf(v[2]); o.w = f2bf(v[3]);
        *(ushort4*)(jb.outbf + (size_t)(bidx * CA + n) * NN + tok) = o;
      } else {
        float bias = jb.bias ? jb.bias[n] : 0.f;
#pragma unroll
        for (int r = 0; r < 4; ++r) {
          size_t idx = (size_t)(mbase + r) * jb.ostride + n;
          float x = v[r] + bias;
          jb.outbf[idx] = f2bf(jb.mode == 1 ? sigmoidf_(x) : x);
        }
      }
    }
  }
}

// ---------------------------------------------------------------------------
// Combo output kernel: out = (O @ woT)*g1 + (HID @ twoT)*g2, fp32.
// BM=64 (grid 256 blocks -> all CUs), pass-fused: one 8-step pipeline,
// steps 0-3 compute BOTH passes (pass1 K=128 + pass2 first half), 4-7 pass2.
// ---------------------------------------------------------------------------
__global__ __launch_bounds__(256) void combo_kernel(const u16* __restrict__ O,
                                                    const u16* __restrict__ HID,
                                                    const u16* __restrict__ woT,
                                                    const u16* __restrict__ twoT,
                                                    const u16* __restrict__ g1,
                                                    const u16* __restrict__ g2,
                                                    float* __restrict__ outp) {
  const int bm = blockIdx.y * 64;
  __shared__ u16 As1[2][2048];
  __shared__ u16 Bs1[2][4096];
  __shared__ u16 As2[2][2048];
  __shared__ u16 Bs2h[2][4096];
  const int tid  = threadIdx.x;
  const int lane = tid & 63;
  const int wave = tid >> 6;
  const int wr = wave >> 1, wc = wave & 1;
  const int l15 = lane & 15, quad = lane >> 4;

  floatx4 acc1[2][4] = {};
  floatx4 acc2[2][4] = {};

  const u16* A1  = O    + ((size_t)bm + lane) * CA + wave * 8;
  const u16* B10 = woT  + ((size_t)lane) * CA + wave * 8;
  const u16* B11 = woT  + ((size_t)64 + lane) * CA + wave * 8;
  const u16* A2  = HID  + ((size_t)bm + lane) * HIDN + wave * 8;
  const u16* B20 = twoT + ((size_t)lane) * HIDN + wave * 8;
  const u16* B21 = twoT + ((size_t)64 + lane) * HIDN + wave * 8;

  auto stage1 = [&](int k0, int pb) {
    gload16(A1  + k0, As1[pb] + wave * 512);
    gload16(B10 + k0, Bs1[pb] + wave * 1024);
    gload16(B11 + k0, Bs1[pb] + wave * 1024 + 512);
  };
  auto stage2 = [&](int k0, int pb) {
    gload16(A2  + k0, As2[pb] + wave * 512);
    gload16(B20 + k0, Bs2h[pb] + wave * 1024);
    gload16(B21 + k0, Bs2h[pb] + wave * 1024 + 512);
  };

  stage1(0, 0);
  stage2(0, 0);
  __syncthreads();
  int cur = 0;
  for (int t = 0; t < 8; ++t) {
    if (t + 1 < 4) stage1((t + 1) * 32, cur ^ 1);
    if (t + 1 < 8) stage2((t + 1) * 32, cur ^ 1);

    if (t < 4) {
      short8 a_frag[2], b_frag[4];
#pragma unroll
      for (int mt = 0; mt < 2; ++mt)
        a_frag[mt] = *(const short8*)(As1[cur] + quad * 512 + (wr * 32 + mt * 16 + l15) * 8);
#pragma unroll
      for (int nt = 0; nt < 4; ++nt)
        b_frag[nt] = *(const short8*)(Bs1[cur] + quad * 1024 + (wc * 64 + nt * 16 + l15) * 8);
#pragma unroll
      for (int mt = 0; mt < 2; ++mt)
#pragma unroll
        for (int nt = 0; nt < 4; ++nt)
          acc1[mt][nt] = __builtin_amdgcn_mfma_f32_16x16x32_bf16(a_frag[mt], b_frag[nt], acc1[mt][nt], 0, 0, 0);
    }
    {
      short8 a_frag[2], b_frag[4];
#pragma unroll
      for (int mt = 0; mt < 2; ++mt)
        a_frag[mt] = *(const short8*)(As2[cur] + quad * 512 + (wr * 32 + mt * 16 + l15) * 8);
#pragma unroll
      for (int nt = 0; nt < 4; ++nt)
        b_frag[nt] = *(const short8*)(Bs2h[cur] + quad * 1024 + (wc * 64 + nt * 16 + l15) * 8);
#pragma unroll
      for (int mt = 0; mt < 2; ++mt)
#pragma unroll
        for (int nt = 0; nt < 4; ++nt)
          acc2[mt][nt] = __builtin_amdgcn_mfma_f32_16x16x32_bf16(a_frag[mt], b_frag[nt], acc2[mt][nt], 0, 0, 0);
    }
    __syncthreads();
    cur ^= 1;
  }

#pragma unroll
  for (int mt = 0; mt < 2; ++mt) {
#pragma unroll
    for (int nt = 0; nt < 4; ++nt) {
      int n = wc * 64 + nt * 16 + l15;
      int mbase = bm + wr * 32 + mt * 16 + quad * 4;
#pragma unroll
      for (int r = 0; r < 4; ++r) {
        size_t idx = (size_t)(mbase + r) * CA + n;
        outp[idx] = acc1[mt][nt][r] * bf2f(g1[idx]) + acc2[mt][nt][r] * bf2f(g2[idx]);
      }
    }
  }
}

// ---------------------------------------------------------------------------
// Pair bias for ALL 3 blocks in one pass over p; no LDS transpose, direct
// ushort4 stores.  Grid (4 k-chunks, W, B).
// Output layout: biasT[i][b][w][h][k][q] (bf16).
// ---------------------------------------------------------------------------
__global__ __launch_bounds__(256) void bias3_kernel(const float* __restrict__ p,
                                                    const float* __restrict__ lnz_w,
                                                    const float* __restrict__ lnz_b,
                                                    const float* __restrict__ wb,
                                                    u16* __restrict__ biasT) {
  const int kc = blockIdx.x, w = blockIdx.y, b = blockIdx.z;
  __shared__ float effW[12][16];
  __shared__ float effb[12];
  const int t = threadIdx.x;
  if (t < 192) {
    int i = t >> 6, rem = t & 63, z = rem >> 2, hh = rem & 3;
    effW[i*4 + hh][z] = lnz_w[i*CZ + z] * wb[(i*CZ + z)*HH + hh];
  }
  if (t < 12) {
    int i = t >> 2, hh = t & 3;
    float acc = 0.f;
    for (int z = 0; z < 16; ++z) acc += lnz_b[i*CZ + z] * wb[(i*CZ + z)*HH + hh];
    effb[t] = acc;
  }
  __syncthreads();

  const int kk = t & 31, qg = (t >> 5) * 4;
  const int k = kc * 32 + kk;
  u16 out4[12][4];
#pragma unroll
  for (int r = 0; r < 4; ++r) {
    int qq = qg + r;
    const float4* pr = (const float4*)(p + (size_t)(((b * WW + w) * NQW + qq) * NKW + k) * 16);
    float4 p0 = pr[0], p1 = pr[1], p2 = pr[2], p3 = pr[3];
    float x[16] = {p0.x,p0.y,p0.z,p0.w, p1.x,p1.y,p1.z,p1.w,
                   p2.x,p2.y,p2.z,p2.w, p3.x,p3.y,p3.z,p3.w};
    float sum = 0.f, sq = 0.f;
#pragma unroll
    for (int z = 0; z < 16; ++z) { sum += x[z]; sq += x[z]*x[z]; }
    float mean = sum * (1.f/16.f);
    float var  = sq  * (1.f/16.f) - mean*mean;
    float rstd = rsqrtf(var + 1e-5f);
#pragma unroll
    for (int ih = 0; ih < 12; ++ih) {
      float acc = effb[ih];
#pragma unroll
      for (int z = 0; z < 16; ++z) acc += (x[z]-mean)*rstd * effW[ih][z];
      out4[ih][r] = f2bf(acc);
    }
  }
#pragma unroll
  for (int ih = 0; ih < 12; ++ih) {
    int i = ih >> 2, hh = ih & 3;
    u16* dst = biasT + ((((size_t)i * BB + b) * WW + w) * HH + hh) * 4096 + (size_t)k * 32 + qg;
    ushort4 uv; uv.x = out4[ih][0]; uv.y = out4[ih][1]; uv.z = out4[ih][2]; uv.w = out4[ih][3];
    *(ushort4*)dst = uv;
  }
}

// ---------------------------------------------------------------------------
// MFMA windowed attention: one WAVE per (w, h, b).
// ---------------------------------------------------------------------------
__global__ __launch_bounds__(64) void attn_mfma(const u16* __restrict__ Qb,
                                                const u16* __restrict__ Kb,
                                                const u16* __restrict__ Vtb,
                                                const u16* __restrict__ Gb,
                                                const u16* __restrict__ biasT,
                                                u16* __restrict__ Ob) {
  const int w = blockIdx.x, h = blockIdx.y, b = blockIdx.z;
  __shared__ u16 Pt[128 * 36];
  __shared__ float inv_s[32];
  const int lane = threadIdx.x;
  const int l15 = lane & 15, quad = lane >> 4;
  const int tok0 = w * NQW - 48;

  short8 qf[2];
#pragma unroll
  for (int mt = 0; mt < 2; ++mt) {
    int qq = w * NQW + mt * 16 + l15;
    qf[mt] = *(const short8*)(Qb + (size_t)(b * NN + qq) * CA + h * DD + quad * 8);
  }
  floatx4 lg[2][8] = {};
#pragma unroll
  for (int nt = 0; nt < 8; ++nt) {
    int tk = tok0 + nt * 16 + l15;
    int tc = min(max(tk, 0), NN - 1);
    short8 kf = *(const short8*)(Kb + (size_t)(b * NN + tc) * CA + h * DD + quad * 8);
#pragma unroll
    for (int mt = 0; mt < 2; ++mt)
      lg[mt][nt] = __builtin_amdgcn_mfma_f32_16x16x32_bf16(qf[mt], kf, lg[mt][nt], 0, 0, 0);
  }

  const float scale = 0.17677669529663687f;   // 1/sqrt(32)
  const u16* bb = biasT + ((((size_t)b * WW + w) * HH + h) << 12);
  float mrow[2][4];
#pragma unroll
  for (int mt = 0; mt < 2; ++mt)
#pragma unroll
    for (int r = 0; r < 4; ++r) mrow[mt][r] = -3.0e38f;
#pragma unroll
  for (int nt = 0; nt < 8; ++nt) {
    int tk = tok0 + nt * 16 + l15;
    bool valid = (tk >= 0) && (tk < NN);
#pragma unroll
    for (int mt = 0; mt < 2; ++mt) {
      ushort4 bv = *(const ushort4*)(bb + (nt * 16 + l15) * 32 + mt * 16 + quad * 4);
      float bvf[4] = {bf2f(bv.x), bf2f(bv.y), bf2f(bv.z), bf2f(bv.w)};
#pragma unroll
      for (int r = 0; r < 4; ++r) {
        float l = valid ? (lg[mt][nt][r] * scale + bvf[r]) : -1e9f;
        lg[mt][nt][r] = l;
        mrow[mt][r] = fmaxf(mrow[mt][r], l);
      }
    }
  }
#pragma unroll
  for (int mt = 0; mt < 2; ++mt)
#pragma unroll
    for (int r = 0; r < 4; ++r) {
      float m = mrow[mt][r];
      m = fmaxf(m, __shfl_xor(m, 1));
      m = fmaxf(m, __shfl_xor(m, 2));
      m = fmaxf(m, __shfl_xor(m, 4));
      m = fmaxf(m, __shfl_xor(m, 8));
      mrow[mt][r] = m;
    }

  float srow[2][4] = {};
#pragma unroll
  for (int nt = 0; nt < 8; ++nt)
#pragma unroll
    for (int mt = 0; mt < 2; ++mt) {
      u16 pv[4];
#pragma unroll
      for (int r = 0; r < 4; ++r) {
        float e = __expf(lg[mt][nt][r] - mrow[mt][r]);
        srow[mt][r] += e;
        pv[r] = f2bf(e);
      }
      ushort4 uv; uv.x = pv[0]; uv.y = pv[1]; uv.z = pv[2]; uv.w = pv[3];
      *(ushort4*)(Pt + (nt * 16 + l15) * 36 + mt * 16 + quad * 4) = uv;
    }
#pragma unroll
  for (int mt = 0; mt < 2; ++mt)
#pragma unroll
    for (int r = 0; r < 4; ++r) {
      float ssum = srow[mt][r];
      ssum += __shfl_xor(ssum, 1);
      ssum += __shfl_xor(ssum, 2);
      ssum += __shfl_xor(ssum, 4);
      ssum += __shfl_xor(ssum, 8);
      if (l15 == 0) inv_s[mt * 16 + quad * 4 + r] = 1.f / ssum;
    }
  __syncthreads();

  floatx4 oacc[2][2] = {};
#pragma unroll
  for (int ks = 0; ks < 4; ++ks) {
    short8 pf[2];
#pragma unroll
    for (int ntq = 0; ntq < 2; ++ntq)
#pragma unroll
      for (int j = 0; j < 8; ++j)
        pf[ntq][j] = (short)Pt[(ks * 32 + quad * 8 + j) * 36 + ntq * 16 + l15];
    int tb = tok0 + ks * 32 + quad * 8;
    tb = min(max(tb, 0), NN - 8);
#pragma unroll
    for (int mtd = 0; mtd < 2; ++mtd) {
      short8 vf = *(const short8*)(Vtb + (size_t)(b * CA + h * DD + mtd * 16 + l15) * NN + tb);
#pragma unroll
      for (int ntq = 0; ntq < 2; ++ntq)
        oacc[mtd][ntq] = __builtin_amdgcn_mfma_f32_16x16x32_bf16(vf, pf[ntq], oacc[mtd][ntq], 0, 0, 0);
    }
  }

#pragma unroll
  for (int mtd = 0; mtd < 2; ++mtd)
#pragma unroll
    for (int ntq = 0; ntq < 2; ++ntq) {
      int qq = ntq * 16 + l15;
      float inv = inv_s[qq];
      int tok = w * NQW + qq;
      size_t base = (size_t)(b * NN + tok) * CA + h * DD + mtd * 16 + quad * 4;
      ushort4 gv = *(const ushort4*)(Gb + base);
      floatx4 v = oacc[mtd][ntq];
      ushort4 o;
      o.x = f2bf(bf2f(gv.x) * v[0] * inv);
      o.y = f2bf(bf2f(gv.y) * v[1] * inv);
      o.z = f2bf(bf2f(gv.z) * v[2] * inv);
      o.w = f2bf(bf2f(gv.w) * v[3] * inv);
      *(ushort4*)(Ob + base) = o;
    }
}

// ---------------------------------------------------------------------------
// Host-side orchestration.
// ---------------------------------------------------------------------------
extern "C" void kernel_launch(void* const* d_in, const int* in_sizes, int n_in,
                              void* d_out, int out_size, void* d_ws, size_t ws_size,
                              hipStream_t stream) {
  const float* q             = (const float*)d_in[0];
  const float* s             = (const float*)d_in[1];
  const float* p             = (const float*)d_in[2];
  const float* adaln_scale_w = (const float*)d_in[3];
  const float* adaln_scale_b = (const float*)d_in[4];
  const float* adaln_shift_w = (const float*)d_in[5];
  const float* wq            = (const float*)d_in[6];
  const float* bq            = (const float*)d_in[7];
  const float* wk            = (const float*)d_in[8];
  const float* wv            = (const float*)d_in[9];
  const float* lnz_w         = (const float*)d_in[10];
  const float* lnz_b         = (const float*)d_in[11];
  const float* wb_pair       = (const float*)d_in[12];
  const float* wg            = (const float*)d_in[13];
  const float* wo            = (const float*)d_in[14];
  const float* sgate_w       = (const float*)d_in[15];
  const float* sgate_b       = (const float*)d_in[16];
  const float* t_scale_w     = (const float*)d_in[17];
  const float* t_scale_b     = (const float*)d_in[18];
  const float* t_shift_w     = (const float*)d_in[19];
  const float* t_wa          = (const float*)d_in[20];
  const float* t_wb          = (const float*)d_in[21];
  const float* t_wo          = (const float*)d_in[22];
  const float* t_sgate_w     = (const float*)d_in[23];
  const float* t_sgate_b     = (const float*)d_in[24];
  float* out = (float*)d_out;

  const size_t MC = (size_t)MR * CA; // 2097152
  float* fws   = (float*)d_ws;
  float* abuf0 = fws;
  float* abuf1 = abuf0 + MC;
  u16* uws     = (u16*)(abuf1 + MC);
  u16* s_ln_bf = uws;                          // MR*CS
  u16* SP      = s_ln_bf + (size_t)MR * CS;    // 18*MC
  u16* amod    = SP + 18*MC;
  u16* tmod    = amod + MC;
  u16* Qb      = tmod + MC;
  u16* Kb      = Qb + MC;
  u16* Vtb     = Kb + MC;                      // [b][128][NN]
  u16* Gb      = Vtb + MC;
  u16* Ob      = Gb + MC;
  u16* HIDb    = Ob + MC;                      // MR*HIDN = 2*MC
  u16* biasT   = HIDb + 2*MC;                  // 3*BB*WW*HH*4096
  u16* wbuf    = biasT + (size_t)3*BB*WW*HH*NQW*NKW;

  const size_t WBLK = 6*(size_t)CA*CS + 5*(size_t)CA*CA + 3*(size_t)CA*HIDN;
  const size_t o_ascale = 0;
  const size_t o_ashift = o_ascale + (size_t)CA*CS;
  const size_t o_sgate  = o_ashift + (size_t)CA*CS;
  const size_t o_tscale = o_sgate  + (size_t)CA*CS;
  const size_t o_tshift = o_tscale + (size_t)CA*CS;
  const size_t o_tsgate = o_tshift + (size_t)CA*CS;
  const size_t o_wq     = o_tsgate + (size_t)CA*CS;
  const size_t o_wk     = o_wq + (size_t)CA*CA;
  const size_t o_wv     = o_wk + (size_t)CA*CA;
  const size_t o_wg     = o_wv + (size_t)CA*CA;
  const size_t o_wo     = o_wg + (size_t)CA*CA;
  const size_t o_twa    = o_wo + (size_t)CA*CA;
  const size_t o_twb    = o_twa + (size_t)HIDN*CA;
  const size_t o_two    = o_twb + (size_t)HIDN*CA;

  // ---- one-time work ----
  ln_s_kernel<<<MR/4, 256, 0, stream>>>(s, s_ln_bf);

  TJobs tj;
  for (int i = 0; i < NBLK; ++i) {
    u16* wb0 = wbuf + (size_t)i * WBLK;
    int b14 = i * 14;
    tj.j[b14+0]  = TJob{adaln_scale_w + (size_t)i*CS*CA, wb0 + o_ascale, CS, CA};
    tj.j[b14+1]  = TJob{adaln_shift_w + (size_t)i*CS*CA, wb0 + o_ashift, CS, CA};
    tj.j[b14+2]  = TJob{sgate_w       + (size_t)i*CS*CA, wb0 + o_sgate,  CS, CA};
    tj.j[b14+3]  = TJob{t_scale_w     + (size_t)i*CS*CA, wb0 + o_tscale, CS, CA};
    tj.j[b14+4]  = TJob{t_shift_w     + (size_t)i*CS*CA, wb0 + o_tshift, CS, CA};
    tj.j[b14+5]  = TJob{t_sgate_w     + (size_t)i*CS*CA, wb0 + o_tsgate, CS, CA};
    tj.j[b14+6]  = TJob{wq   + (size_t)i*CA*CA,   wb0 + o_wq,  CA, CA};
    tj.j[b14+7]  = TJob{wk   + (size_t)i*CA*CA,   wb0 + o_wk,  CA, CA};
    tj.j[b14+8]  = TJob{wv   + (size_t)i*CA*CA,   wb0 + o_wv,  CA, CA};
    tj.j[b14+9]  = TJob{wg   + (size_t)i*CA*CA,   wb0 + o_wg,  CA, CA};
    tj.j[b14+10] = TJob{wo   + (size_t)i*CA*CA,   wb0 + o_wo,  CA, CA};
    tj.j[b14+11] = TJob{t_wa + (size_t)i*CA*HIDN, wb0 + o_twa, CA, HIDN};
    tj.j[b14+12] = TJob{t_wb + (size_t)i*CA*HIDN, wb0 + o_twb, CA, HIDN};
    tj.j[b14+13] = TJob{t_wo + (size_t)i*HIDN*CA, wb0 + o_two, HIDN, CA};
  }
  transpose_bf16<<<dim3(12, 8, 42), 256, 0, stream>>>(tj);

  bias3_kernel<<<dim3(4, WW, BB), 256, 0, stream>>>(p, lnz_w, lnz_b, wb_pair, biasT);

  // ALL 18 s_ln projections (iteration-invariant), job-fastest 1-D grid
  {
    GemmJobs js = {};
    for (int i = 0; i < NBLK; ++i) {
      u16* wb0 = wbuf + (size_t)i * WBLK;
      js.j[i*6+0] = GemmJob{s_ln_bf, wb0 + o_ascale, nullptr, adaln_scale_b + i*CA, SP + (i*6+0)*MC, CS, CA, 1, 0};
      js.j[i*6+1] = GemmJob{s_ln_bf, wb0 + o_ashift, nullptr, nullptr,              SP + (i*6+1)*MC, CS, CA, 0, 0};
      js.j[i*6+2] = GemmJob{s_ln_bf, wb0 + o_sgate,  nullptr, sgate_b   + i*CA,     SP + (i*6+2)*MC, CS, CA, 1, 0};
      js.j[i*6+3] = GemmJob{s_ln_bf, wb0 + o_tscale, nullptr, t_scale_b + i*CA,     SP + (i*6+3)*MC, CS, CA, 1, 0};
      js.j[i*6+4] = GemmJob{s_ln_bf, wb0 + o_tshift, nullptr, nullptr,              SP + (i*6+4)*MC, CS, CA, 0, 0};
      js.j[i*6+5] = GemmJob{s_ln_bf, wb0 + o_tsgate, nullptr, t_sgate_b + i*CA,     SP + (i*6+5)*MC, CS, CA, 1, 0};
    }
    gemm_mfma<18, 1, false><<<18 * (MR/128), 256, 0, stream>>>(js);
  }

  for (int i = 0; i < NBLK; ++i) {
    const float* a_in = (i == 0) ? q : (i == 1 ? abuf0 : abuf1);
    float* a_out = (i == 2) ? out : (i == 0 ? abuf0 : abuf1);
    u16* wb0 = wbuf + (size_t)i * WBLK;

    // LN(a) + both modulations -> bf16
    modln_kernel<<<MR/4, 256, 0, stream>>>(a_in, SP + (i*6+0)*MC, SP + (i*6+1)*MC,
                                           SP + (i*6+3)*MC, SP + (i*6+4)*MC, amod, tmod);

    // Q, K, V(transposed), G projections -> bf16, job-fastest 1-D grid
    GemmJobs jq = {};
    jq.j[0] = GemmJob{amod, wb0 + o_wq, nullptr, bq + i*CA, Qb,  CA, CA, 0, 0};
    jq.j[1] = GemmJob{amod, wb0 + o_wk, nullptr, nullptr,   Kb,  CA, CA, 0, 0};
    jq.j[2] = GemmJob{amod, wb0 + o_wv, nullptr, nullptr,   Vtb, CA, CA, 5, 0};
    jq.j[3] = GemmJob{amod, wb0 + o_wg, nullptr, nullptr,   Gb,  CA, CA, 1, 0};
    gemm_mfma<4, 1, false><<<4 * (MR/128), 256, 0, stream>>>(jq);

    // hidden = silu(tmod @ t_wa) * (tmod @ t_wb)  -> bf16 (N=256)
    GemmJobs jh = {};
    jh.j[0] = GemmJob{tmod, wb0 + o_twa, wb0 + o_twb, nullptr, HIDb, CA, HIDN, 4, 0};
    gemm_mfma<1, 2, true><<<2 * (MR/128), 256, 0, stream>>>(jh);

    // windowed attention (MFMA, g-gated bf16 out)
    attn_mfma<<<dim3(WW, HH, BB), 64, 0, stream>>>(
        Qb, Kb, Vtb, Gb, biasT + (size_t)i * BB*WW*HH*4096, Ob);

    // a_out = (O @ wo)*sgate + (HID @ two)*tsgate
    combo_kernel<<<dim3(1, MR/64), 256, 0, stream>>>(
        Ob, HIDb, wb0 + o_wo, wb0 + o_two,
        SP + (i*6+2)*MC, SP + (i*6+5)*MC, a_out);
  }
}

// Round 6
// 573.113 us; speedup vs baseline: 1.1129x; 1.0066x over previous
//
#include <hip/hip_runtime.h>
#include <hip/hip_bf16.h>
#include <cstddef>
#include <cstdint>

// Problem constants
#define BB   2
#define NN   8192
#define CA   128
#define CS   384
#define CZ   16
#define HH   4
#define DD   32
#define NQW  32      // NQ
#define NKW  128     // NK
#define NBLK 3
#define WW   256     // N / NQ
#define MR   (BB*NN) // 16384 rows
#define HIDN 256     // 2*CA

typedef unsigned short u16;
typedef __attribute__((ext_vector_type(8))) short short8;
typedef __attribute__((ext_vector_type(4))) float floatx4;

__device__ __forceinline__ float sigmoidf_(float x) { return 1.f / (1.f + __expf(-x)); }

__device__ __forceinline__ u16 f2bf(float x) {
  unsigned u = __float_as_uint(x);
  unsigned r = (u + 0x7fffu + ((u >> 16) & 1u)) >> 16;
  return (u16)r;
}
__device__ __forceinline__ float bf2f(u16 u) {
  return __uint_as_float(((unsigned)u) << 16);
}

// Async global->LDS, 16B per lane. LDS dest is wave-uniform base + lane*16.
// LDS layout must be linear in lane order (no padding) -- m173.
__device__ __forceinline__ void gload16(const u16* g, u16* l) {
  __builtin_amdgcn_global_load_lds(
      (const __attribute__((address_space(1))) unsigned int*)g,
      (__attribute__((address_space(3))) unsigned int*)l, 16, 0, 0);
}

// ---------------------------------------------------------------------------
// LayerNorm of s (C_S = 384), one wave per row -> bf16 out.
// ---------------------------------------------------------------------------
__global__ __launch_bounds__(256) void ln_s_kernel(const float* __restrict__ s,
                                                   u16* __restrict__ s_ln_bf) {
  int row  = blockIdx.x * 4 + (threadIdx.x >> 6);
  int lane = threadIdx.x & 63;
  const float* sr = s + (size_t)row * CS;
  float x[6];
  float sum = 0.f, sq = 0.f;
#pragma unroll
  for (int t = 0; t < 6; ++t) { x[t] = sr[lane + 64*t]; sum += x[t]; sq += x[t]*x[t]; }
#pragma unroll
  for (int off = 32; off; off >>= 1) { sum += __shfl_down(sum, off); sq += __shfl_down(sq, off); }
  sum = __shfl(sum, 0); sq = __shfl(sq, 0);
  float mean = sum * (1.f/CS);
  float var  = sq  * (1.f/CS) - mean*mean;
  float rstd = rsqrtf(var + 1e-5f);
  u16* orow = s_ln_bf + (size_t)row * CS;
#pragma unroll
  for (int t = 0; t < 6; ++t) orow[lane + 64*t] = f2bf((x[t]-mean)*rstd);
}

// ---------------------------------------------------------------------------
// LN(a) + adaLN modulation for attention (amod) and transition (tmod), bf16.
// ---------------------------------------------------------------------------
__global__ __launch_bounds__(256) void modln_kernel(const float* __restrict__ a,
                                                    const u16* __restrict__ sp0,
                                                    const u16* __restrict__ sp1,
                                                    const u16* __restrict__ sp3,
                                                    const u16* __restrict__ sp4,
                                                    u16* __restrict__ amod,
                                                    u16* __restrict__ tmod) {
  int row  = blockIdx.x * 4 + (threadIdx.x >> 6);
  int lane = threadIdx.x & 63;
  const float* ar = a + (size_t)row * CA;
  float x0 = ar[lane], x1 = ar[lane + 64];
  float sum = x0 + x1, sq = x0*x0 + x1*x1;
#pragma unroll
  for (int off = 32; off; off >>= 1) { sum += __shfl_down(sum, off); sq += __shfl_down(sq, off); }
  sum = __shfl(sum, 0); sq = __shfl(sq, 0);
  float mean = sum * (1.f/CA);
  float var  = sq  * (1.f/CA) - mean*mean;
  float rstd = rsqrtf(var + 1e-5f);
  float n0 = (x0-mean)*rstd, n1 = (x1-mean)*rstd;
  size_t i0 = (size_t)row * CA + lane;
  amod[i0]      = f2bf(bf2f(sp0[i0])     *n0 + bf2f(sp1[i0]));
  amod[i0 + 64] = f2bf(bf2f(sp0[i0 + 64])*n1 + bf2f(sp1[i0 + 64]));
  tmod[i0]      = f2bf(bf2f(sp3[i0])     *n0 + bf2f(sp4[i0]));
  tmod[i0 + 64] = f2bf(bf2f(sp3[i0 + 64])*n1 + bf2f(sp4[i0 + 64]));
}

// ---------------------------------------------------------------------------
// Weight transpose+convert: src fp32 K x N (row-major)  ->  dst bf16 N x K.
// ---------------------------------------------------------------------------
struct TJob { const float* src; u16* dst; int K; int N; };
struct TJobs { TJob j[42]; };

__global__ __launch_bounds__(256) void transpose_bf16(TJobs jobs) {
  TJob jb = jobs.j[blockIdx.z];
  int tk = blockIdx.x * 32, tn = blockIdx.y * 32;
  if (tk >= jb.K || tn >= jb.N) return;
  __shared__ float tile[32][33];
  int tx = threadIdx.x & 31;
  int ty = threadIdx.x >> 5;
#pragma unroll
  for (int r = ty; r < 32; r += 8) tile[r][tx] = jb.src[(size_t)(tk + r) * jb.N + tn + tx];
  __syncthreads();
#pragma unroll
  for (int r = ty; r < 32; r += 8)
    jb.dst[(size_t)(tn + r) * jb.K + tk + tx] = f2bf(tile[tx][r]);
}

// ---------------------------------------------------------------------------
// bf16 MFMA GEMM.  128x128 block tile, BK=32, 4 waves (2x2 of 64x64).
// COUNTED-VMCNT pipeline (T4): 3 LDS buffers, depth-2 prefetch; raw s_barrier
// with s_waitcnt vmcnt(2L) -- tile t+1/t+2 loads stay IN FLIGHT across the
// barrier (no vmcnt(0) drain; that drain was the stall in rounds 0-5).
// modes: 0 = (+bias)->bf16, 1 = sigmoid(+bias)->bf16,
// 4 (DUAL) = silu(A@B)*(A@B2) -> bf16, 5 = transposed bf16 write (V).
// ---------------------------------------------------------------------------
struct GemmJob {
  const u16* A;
  const u16* Bt;
  const u16* Bt2;
  const float* bias;
  u16* outbf;
  int K;
  int ostride;
  int mode;
  int pad;
};
struct GemmJobs { GemmJob j[18]; };

template <bool DUAL>
__global__ __launch_bounds__(256) void gemm_mfma(GemmJobs jobs) {
  GemmJob jb = jobs.j[blockIdx.z];
  const int bm = blockIdx.y * 128, bn = blockIdx.x * 128;
  const int K = jb.K;

  __shared__ u16 As[3][4096];
  __shared__ u16 Bs[3][4096];
  __shared__ u16 Bs2[DUAL ? 3 : 1][DUAL ? 4096 : 8];

  const int tid  = threadIdx.x;
  const int lane = tid & 63;
  const int wave = tid >> 6;
  const int wr = wave >> 1, wc = wave & 1;
  const int l15 = lane & 15, quad = lane >> 4;

  floatx4 acc[4][4] = {};
  floatx4 acc2[DUAL ? 4 : 1][DUAL ? 4 : 1] = {};

  // staging: wave w stages k-chunk plane c==w (8 u16) for rows h*64+lane.
  const u16* Ab0  = jb.A  + ((size_t)bm + lane) * K + wave * 8;
  const u16* Ab1  = jb.A  + ((size_t)bm + 64 + lane) * K + wave * 8;
  const u16* Bb0  = jb.Bt + ((size_t)bn + lane) * K + wave * 8;
  const u16* Bb1  = jb.Bt + ((size_t)bn + 64 + lane) * K + wave * 8;
  const u16* B2b0 = DUAL ? (jb.Bt2 + ((size_t)bn + lane) * K + wave * 8) : nullptr;
  const u16* B2b1 = DUAL ? (jb.Bt2 + ((size_t)bn + 64 + lane) * K + wave * 8) : nullptr;

  auto stage = [&](int k0, int pb) {
    gload16(Ab0 + k0, As[pb] + wave * 1024);
    gload16(Ab1 + k0, As[pb] + wave * 1024 + 512);
    gload16(Bb0 + k0, Bs[pb] + wave * 1024);
    gload16(Bb1 + k0, Bs[pb] + wave * 1024 + 512);
    if constexpr (DUAL) {
      gload16(B2b0 + k0, Bs2[pb] + wave * 1024);
      gload16(B2b1 + k0, Bs2[pb] + wave * 1024 + 512);
    }
  };

  auto compute = [&](int pb) {
    short8 a_frag[4], b_frag[4];
#pragma unroll
    for (int mt = 0; mt < 4; ++mt)
      a_frag[mt] = *(const short8*)(As[pb] + quad * 1024 + (wr * 64 + mt * 16 + l15) * 8);
#pragma unroll
    for (int nt = 0; nt < 4; ++nt)
      b_frag[nt] = *(const short8*)(Bs[pb] + quad * 1024 + (wc * 64 + nt * 16 + l15) * 8);
#pragma unroll
    for (int mt = 0; mt < 4; ++mt)
#pragma unroll
      for (int nt = 0; nt < 4; ++nt)
        acc[mt][nt] = __builtin_amdgcn_mfma_f32_16x16x32_bf16(a_frag[mt], b_frag[nt], acc[mt][nt], 0, 0, 0);
    if constexpr (DUAL) {
      short8 b2_frag[4];
#pragma unroll
      for (int nt = 0; nt < 4; ++nt)
        b2_frag[nt] = *(const short8*)(Bs2[pb] + quad * 1024 + (wc * 64 + nt * 16 + l15) * 8);
#pragma unroll
      for (int mt = 0; mt < 4; ++mt)
#pragma unroll
        for (int nt = 0; nt < 4; ++nt)
          acc2[mt][nt] = __builtin_amdgcn_mfma_f32_16x16x32_bf16(a_frag[mt], b2_frag[nt], acc2[mt][nt], 0, 0, 0);
    }
  };

  // prologue: depth-2 prefetch
  stage(0, 0);
  stage(32, 1);
  int cur = 0;
  // main: K/32 - 2 steps with counted wait (tile t done; t+1,t+2 in flight)
  for (int k0 = 0; k0 + 64 < K; k0 += 32) {
    stage(k0 + 64, (cur + 2) % 3);
    if constexpr (DUAL) asm volatile("s_waitcnt vmcnt(12)" ::: "memory");
    else                asm volatile("s_waitcnt vmcnt(8)"  ::: "memory");
    __builtin_amdgcn_s_barrier();
    compute(cur);
    __builtin_amdgcn_s_barrier();   // frags in regs; buffer may be restaged
    cur = (cur + 1) % 3;
  }
  // tail t = nt-2 (only t+1 in flight)
  if constexpr (DUAL) asm volatile("s_waitcnt vmcnt(6)" ::: "memory");
  else                asm volatile("s_waitcnt vmcnt(4)" ::: "memory");
  __builtin_amdgcn_s_barrier();
  compute(cur);
  __builtin_amdgcn_s_barrier();
  cur = (cur + 1) % 3;
  // tail t = nt-1
  asm volatile("s_waitcnt vmcnt(0)" ::: "memory");
  __builtin_amdgcn_s_barrier();
  compute(cur);

  // Epilogue.  C/D layout: col = lane&15, row = quad*4 + reg.
#pragma unroll
  for (int mt = 0; mt < 4; ++mt) {
#pragma unroll
    for (int nt = 0; nt < 4; ++nt) {
      int n = bn + wc * 64 + nt * 16 + l15;
      int mbase = bm + wr * 64 + mt * 16 + quad * 4;
      floatx4 v = acc[mt][nt];
      if constexpr (DUAL) {
        floatx4 v2 = acc2[mt][nt];
#pragma unroll
        for (int r = 0; r < 4; ++r) {
          size_t idx = (size_t)(mbase + r) * jb.ostride + n;
          float x1 = v[r];
          jb.outbf[idx] = f2bf(x1 * sigmoidf_(x1) * v2[r]);
        }
      } else if (jb.mode == 5) {
        int bidx = mbase >> 13;          // m / NN
        int tok  = mbase & (NN - 1);
        ushort4 o;
        o.x = f2bf(v[0]); o.y = f2bf(v[1]); o.z = f2bf(v[2]); o.w = f2bf(v[3]);
        *(ushort4*)(jb.outbf + (size_t)(bidx * CA + n) * NN + tok) = o;
      } else {
        float bias = jb.bias ? jb.bias[n] : 0.f;
#pragma unroll
        for (int r = 0; r < 4; ++r) {
          size_t idx = (size_t)(mbase + r) * jb.ostride + n;
          float x = v[r] + bias;
          jb.outbf[idx] = f2bf(jb.mode == 1 ? sigmoidf_(x) : x);
        }
      }
    }
  }
}

// ---------------------------------------------------------------------------
// Combo output kernel: out = (O @ woT)*g1 + (HID @ twoT)*g2, fp32.
// BM=64 (grid 256 blocks -> all CUs), pass-fused: one 8-step pipeline,
// steps 0-3 compute BOTH passes (pass1 K=128 + pass2 first half), 4-7 pass2.
// ---------------------------------------------------------------------------
__global__ __launch_bounds__(256) void combo_kernel(const u16* __restrict__ O,
                                                    const u16* __restrict__ HID,
                                                    const u16* __restrict__ woT,
                                                    const u16* __restrict__ twoT,
                                                    const u16* __restrict__ g1,
                                                    const u16* __restrict__ g2,
                                                    float* __restrict__ outp) {
  const int bm = blockIdx.y * 64;
  __shared__ u16 As1[2][2048];
  __shared__ u16 Bs1[2][4096];
  __shared__ u16 As2[2][2048];
  __shared__ u16 Bs2h[2][4096];
  const int tid  = threadIdx.x;
  const int lane = tid & 63;
  const int wave = tid >> 6;
  const int wr = wave >> 1, wc = wave & 1;
  const int l15 = lane & 15, quad = lane >> 4;

  floatx4 acc1[2][4] = {};
  floatx4 acc2[2][4] = {};

  const u16* A1  = O    + ((size_t)bm + lane) * CA + wave * 8;
  const u16* B10 = woT  + ((size_t)lane) * CA + wave * 8;
  const u16* B11 = woT  + ((size_t)64 + lane) * CA + wave * 8;
  const u16* A2  = HID  + ((size_t)bm + lane) * HIDN + wave * 8;
  const u16* B20 = twoT + ((size_t)lane) * HIDN + wave * 8;
  const u16* B21 = twoT + ((size_t)64 + lane) * HIDN + wave * 8;

  auto stage1 = [&](int k0, int pb) {
    gload16(A1  + k0, As1[pb] + wave * 512);
    gload16(B10 + k0, Bs1[pb] + wave * 1024);
    gload16(B11 + k0, Bs1[pb] + wave * 1024 + 512);
  };
  auto stage2 = [&](int k0, int pb) {
    gload16(A2  + k0, As2[pb] + wave * 512);
    gload16(B20 + k0, Bs2h[pb] + wave * 1024);
    gload16(B21 + k0, Bs2h[pb] + wave * 1024 + 512);
  };

  stage1(0, 0);
  stage2(0, 0);
  __syncthreads();
  int cur = 0;
  for (int t = 0; t < 8; ++t) {
    if (t + 1 < 4) stage1((t + 1) * 32, cur ^ 1);
    if (t + 1 < 8) stage2((t + 1) * 32, cur ^ 1);

    if (t < 4) {
      short8 a_frag[2], b_frag[4];
#pragma unroll
      for (int mt = 0; mt < 2; ++mt)
        a_frag[mt] = *(const short8*)(As1[cur] + quad * 512 + (wr * 32 + mt * 16 + l15) * 8);
#pragma unroll
      for (int nt = 0; nt < 4; ++nt)
        b_frag[nt] = *(const short8*)(Bs1[cur] + quad * 1024 + (wc * 64 + nt * 16 + l15) * 8);
#pragma unroll
      for (int mt = 0; mt < 2; ++mt)
#pragma unroll
        for (int nt = 0; nt < 4; ++nt)
          acc1[mt][nt] = __builtin_amdgcn_mfma_f32_16x16x32_bf16(a_frag[mt], b_frag[nt], acc1[mt][nt], 0, 0, 0);
    }
    {
      short8 a_frag[2], b_frag[4];
#pragma unroll
      for (int mt = 0; mt < 2; ++mt)
        a_frag[mt] = *(const short8*)(As2[cur] + quad * 512 + (wr * 32 + mt * 16 + l15) * 8);
#pragma unroll
      for (int nt = 0; nt < 4; ++nt)
        b_frag[nt] = *(const short8*)(Bs2h[cur] + quad * 1024 + (wc * 64 + nt * 16 + l15) * 8);
#pragma unroll
      for (int mt = 0; mt < 2; ++mt)
#pragma unroll
        for (int nt = 0; nt < 4; ++nt)
          acc2[mt][nt] = __builtin_amdgcn_mfma_f32_16x16x32_bf16(a_frag[mt], b_frag[nt], acc2[mt][nt], 0, 0, 0);
    }
    __syncthreads();
    cur ^= 1;
  }

#pragma unroll
  for (int mt = 0; mt < 2; ++mt) {
#pragma unroll
    for (int nt = 0; nt < 4; ++nt) {
      int n = wc * 64 + nt * 16 + l15;
      int mbase = bm + wr * 32 + mt * 16 + quad * 4;
#pragma unroll
      for (int r = 0; r < 4; ++r) {
        size_t idx = (size_t)(mbase + r) * CA + n;
        outp[idx] = acc1[mt][nt][r] * bf2f(g1[idx]) + acc2[mt][nt][r] * bf2f(g2[idx]);
      }
    }
  }
}

// ---------------------------------------------------------------------------
// Pair bias for ALL 3 blocks in one pass over p; no LDS transpose, direct
// ushort4 stores.  Grid (4 k-chunks, W, B).
// Output layout: biasT[i][b][w][h][k][q] (bf16).
// ---------------------------------------------------------------------------
__global__ __launch_bounds__(256) void bias3_kernel(const float* __restrict__ p,
                                                    const float* __restrict__ lnz_w,
                                                    const float* __restrict__ lnz_b,
                                                    const float* __restrict__ wb,
                                                    u16* __restrict__ biasT) {
  const int kc = blockIdx.x, w = blockIdx.y, b = blockIdx.z;
  __shared__ float effW[12][16];
  __shared__ float effb[12];
  const int t = threadIdx.x;
  if (t < 192) {
    int i = t >> 6, rem = t & 63, z = rem >> 2, hh = rem & 3;
    effW[i*4 + hh][z] = lnz_w[i*CZ + z] * wb[(i*CZ + z)*HH + hh];
  }
  if (t < 12) {
    int i = t >> 2, hh = t & 3;
    float acc = 0.f;
    for (int z = 0; z < 16; ++z) acc += lnz_b[i*CZ + z] * wb[(i*CZ + z)*HH + hh];
    effb[t] = acc;
  }
  __syncthreads();

  const int kk = t & 31, qg = (t >> 5) * 4;
  const int k = kc * 32 + kk;
  u16 out4[12][4];
#pragma unroll
  for (int r = 0; r < 4; ++r) {
    int qq = qg + r;
    const float4* pr = (const float4*)(p + (size_t)(((b * WW + w) * NQW + qq) * NKW + k) * 16);
    float4 p0 = pr[0], p1 = pr[1], p2 = pr[2], p3 = pr[3];
    float x[16] = {p0.x,p0.y,p0.z,p0.w, p1.x,p1.y,p1.z,p1.w,
                   p2.x,p2.y,p2.z,p2.w, p3.x,p3.y,p3.z,p3.w};
    float sum = 0.f, sq = 0.f;
#pragma unroll
    for (int z = 0; z < 16; ++z) { sum += x[z]; sq += x[z]*x[z]; }
    float mean = sum * (1.f/16.f);
    float var  = sq  * (1.f/16.f) - mean*mean;
    float rstd = rsqrtf(var + 1e-5f);
#pragma unroll
    for (int ih = 0; ih < 12; ++ih) {
      float acc = effb[ih];
#pragma unroll
      for (int z = 0; z < 16; ++z) acc += (x[z]-mean)*rstd * effW[ih][z];
      out4[ih][r] = f2bf(acc);
    }
  }
#pragma unroll
  for (int ih = 0; ih < 12; ++ih) {
    int i = ih >> 2, hh = ih & 3;
    u16* dst = biasT + ((((size_t)i * BB + b) * WW + w) * HH + hh) * 4096 + (size_t)k * 32 + qg;
    ushort4 uv; uv.x = out4[ih][0]; uv.y = out4[ih][1]; uv.z = out4[ih][2]; uv.w = out4[ih][3];
    *(ushort4*)dst = uv;
  }
}

// ---------------------------------------------------------------------------
// MFMA windowed attention: one WAVE per (w, h, b).
// ---------------------------------------------------------------------------
__global__ __launch_bounds__(64) void attn_mfma(const u16* __restrict__ Qb,
                                                const u16* __restrict__ Kb,
                                                const u16* __restrict__ Vtb,
                                                const u16* __restrict__ Gb,
                                                const u16* __restrict__ biasT,
                                                u16* __restrict__ Ob) {
  const int w = blockIdx.x, h = blockIdx.y, b = blockIdx.z;
  __shared__ u16 Pt[128 * 36];
  __shared__ float inv_s[32];
  const int lane = threadIdx.x;
  const int l15 = lane & 15, quad = lane >> 4;
  const int tok0 = w * NQW - 48;

  short8 qf[2];
#pragma unroll
  for (int mt = 0; mt < 2; ++mt) {
    int qq = w * NQW + mt * 16 + l15;
    qf[mt] = *(const short8*)(Qb + (size_t)(b * NN + qq) * CA + h * DD + quad * 8);
  }
  floatx4 lg[2][8] = {};
#pragma unroll
  for (int nt = 0; nt < 8; ++nt) {
    int tk = tok0 + nt * 16 + l15;
    int tc = min(max(tk, 0), NN - 1);
    short8 kf = *(const short8*)(Kb + (size_t)(b * NN + tc) * CA + h * DD + quad * 8);
#pragma unroll
    for (int mt = 0; mt < 2; ++mt)
      lg[mt][nt] = __builtin_amdgcn_mfma_f32_16x16x32_bf16(qf[mt], kf, lg[mt][nt], 0, 0, 0);
  }

  const float scale = 0.17677669529663687f;   // 1/sqrt(32)
  const u16* bb = biasT + ((((size_t)b * WW + w) * HH + h) << 12);
  float mrow[2][4];
#pragma unroll
  for (int mt = 0; mt < 2; ++mt)
#pragma unroll
    for (int r = 0; r < 4; ++r) mrow[mt][r] = -3.0e38f;
#pragma unroll
  for (int nt = 0; nt < 8; ++nt) {
    int tk = tok0 + nt * 16 + l15;
    bool valid = (tk >= 0) && (tk < NN);
#pragma unroll
    for (int mt = 0; mt < 2; ++mt) {
      ushort4 bv = *(const ushort4*)(bb + (nt * 16 + l15) * 32 + mt * 16 + quad * 4);
      float bvf[4] = {bf2f(bv.x), bf2f(bv.y), bf2f(bv.z), bf2f(bv.w)};
#pragma unroll
      for (int r = 0; r < 4; ++r) {
        float l = valid ? (lg[mt][nt][r] * scale + bvf[r]) : -1e9f;
        lg[mt][nt][r] = l;
        mrow[mt][r] = fmaxf(mrow[mt][r], l);
      }
    }
  }
#pragma unroll
  for (int mt = 0; mt < 2; ++mt)
#pragma unroll
    for (int r = 0; r < 4; ++r) {
      float m = mrow[mt][r];
      m = fmaxf(m, __shfl_xor(m, 1));
      m = fmaxf(m, __shfl_xor(m, 2));
      m = fmaxf(m, __shfl_xor(m, 4));
      m = fmaxf(m, __shfl_xor(m, 8));
      mrow[mt][r] = m;
    }

  float srow[2][4] = {};
#pragma unroll
  for (int nt = 0; nt < 8; ++nt)
#pragma unroll
    for (int mt = 0; mt < 2; ++mt) {
      u16 pv[4];
#pragma unroll
      for (int r = 0; r < 4; ++r) {
        float e = __expf(lg[mt][nt][r] - mrow[mt][r]);
        srow[mt][r] += e;
        pv[r] = f2bf(e);
      }
      ushort4 uv; uv.x = pv[0]; uv.y = pv[1]; uv.z = pv[2]; uv.w = pv[3];
      *(ushort4*)(Pt + (nt * 16 + l15) * 36 + mt * 16 + quad * 4) = uv;
    }
#pragma unroll
  for (int mt = 0; mt < 2; ++mt)
#pragma unroll
    for (int r = 0; r < 4; ++r) {
      float ssum = srow[mt][r];
      ssum += __shfl_xor(ssum, 1);
      ssum += __shfl_xor(ssum, 2);
      ssum += __shfl_xor(ssum, 4);
      ssum += __shfl_xor(ssum, 8);
      if (l15 == 0) inv_s[mt * 16 + quad * 4 + r] = 1.f / ssum;
    }
  __syncthreads();

  floatx4 oacc[2][2] = {};
#pragma unroll
  for (int ks = 0; ks < 4; ++ks) {
    short8 pf[2];
#pragma unroll
    for (int ntq = 0; ntq < 2; ++ntq)
#pragma unroll
      for (int j = 0; j < 8; ++j)
        pf[ntq][j] = (short)Pt[(ks * 32 + quad * 8 + j) * 36 + ntq * 16 + l15];
    int tb = tok0 + ks * 32 + quad * 8;
    tb = min(max(tb, 0), NN - 8);
#pragma unroll
    for (int mtd = 0; mtd < 2; ++mtd) {
      short8 vf = *(const short8*)(Vtb + (size_t)(b * CA + h * DD + mtd * 16 + l15) * NN + tb);
#pragma unroll
      for (int ntq = 0; ntq < 2; ++ntq)
        oacc[mtd][ntq] = __builtin_amdgcn_mfma_f32_16x16x32_bf16(vf, pf[ntq], oacc[mtd][ntq], 0, 0, 0);
    }
  }

#pragma unroll
  for (int mtd = 0; mtd < 2; ++mtd)
#pragma unroll
    for (int ntq = 0; ntq < 2; ++ntq) {
      int qq = ntq * 16 + l15;
      float inv = inv_s[qq];
      int tok = w * NQW + qq;
      size_t base = (size_t)(b * NN + tok) * CA + h * DD + mtd * 16 + quad * 4;
      ushort4 gv = *(const ushort4*)(Gb + base);
      floatx4 v = oacc[mtd][ntq];
      ushort4 o;
      o.x = f2bf(bf2f(gv.x) * v[0] * inv);
      o.y = f2bf(bf2f(gv.y) * v[1] * inv);
      o.z = f2bf(bf2f(gv.z) * v[2] * inv);
      o.w = f2bf(bf2f(gv.w) * v[3] * inv);
      *(ushort4*)(Ob + base) = o;
    }
}

// ---------------------------------------------------------------------------
// Host-side orchestration.
// ---------------------------------------------------------------------------
extern "C" void kernel_launch(void* const* d_in, const int* in_sizes, int n_in,
                              void* d_out, int out_size, void* d_ws, size_t ws_size,
                              hipStream_t stream) {
  const float* q             = (const float*)d_in[0];
  const float* s             = (const float*)d_in[1];
  const float* p             = (const float*)d_in[2];
  const float* adaln_scale_w = (const float*)d_in[3];
  const float* adaln_scale_b = (const float*)d_in[4];
  const float* adaln_shift_w = (const float*)d_in[5];
  const float* wq            = (const float*)d_in[6];
  const float* bq            = (const float*)d_in[7];
  const float* wk            = (const float*)d_in[8];
  const float* wv            = (const float*)d_in[9];
  const float* lnz_w         = (const float*)d_in[10];
  const float* lnz_b         = (const float*)d_in[11];
  const float* wb_pair       = (const float*)d_in[12];
  const float* wg            = (const float*)d_in[13];
  const float* wo            = (const float*)d_in[14];
  const float* sgate_w       = (const float*)d_in[15];
  const float* sgate_b       = (const float*)d_in[16];
  const float* t_scale_w     = (const float*)d_in[17];
  const float* t_scale_b     = (const float*)d_in[18];
  const float* t_shift_w     = (const float*)d_in[19];
  const float* t_wa          = (const float*)d_in[20];
  const float* t_wb          = (const float*)d_in[21];
  const float* t_wo          = (const float*)d_in[22];
  const float* t_sgate_w     = (const float*)d_in[23];
  const float* t_sgate_b     = (const float*)d_in[24];
  float* out = (float*)d_out;

  const size_t MC = (size_t)MR * CA; // 2097152
  float* fws   = (float*)d_ws;
  float* abuf0 = fws;
  float* abuf1 = abuf0 + MC;
  u16* uws     = (u16*)(abuf1 + MC);
  u16* s_ln_bf = uws;                          // MR*CS
  u16* SP      = s_ln_bf + (size_t)MR * CS;    // 18*MC
  u16* amod    = SP + 18*MC;
  u16* tmod    = amod + MC;
  u16* Qb      = tmod + MC;
  u16* Kb      = Qb + MC;
  u16* Vtb     = Kb + MC;                      // [b][128][NN]
  u16* Gb      = Vtb + MC;
  u16* Ob      = Gb + MC;
  u16* HIDb    = Ob + MC;                      // MR*HIDN = 2*MC
  u16* biasT   = HIDb + 2*MC;                  // 3*BB*WW*HH*4096
  u16* wbuf    = biasT + (size_t)3*BB*WW*HH*NQW*NKW;

  const size_t WBLK = 6*(size_t)CA*CS + 5*(size_t)CA*CA + 3*(size_t)CA*HIDN;
  const size_t o_ascale = 0;
  const size_t o_ashift = o_ascale + (size_t)CA*CS;
  const size_t o_sgate  = o_ashift + (size_t)CA*CS;
  const size_t o_tscale = o_sgate  + (size_t)CA*CS;
  const size_t o_tshift = o_tscale + (size_t)CA*CS;
  const size_t o_tsgate = o_tshift + (size_t)CA*CS;
  const size_t o_wq     = o_tsgate + (size_t)CA*CS;
  const size_t o_wk     = o_wq + (size_t)CA*CA;
  const size_t o_wv     = o_wk + (size_t)CA*CA;
  const size_t o_wg     = o_wv + (size_t)CA*CA;
  const size_t o_wo     = o_wg + (size_t)CA*CA;
  const size_t o_twa    = o_wo + (size_t)CA*CA;
  const size_t o_twb    = o_twa + (size_t)HIDN*CA;
  const size_t o_two    = o_twb + (size_t)HIDN*CA;

  // ---- one-time work ----
  ln_s_kernel<<<MR/4, 256, 0, stream>>>(s, s_ln_bf);

  TJobs tj;
  for (int i = 0; i < NBLK; ++i) {
    u16* wb0 = wbuf + (size_t)i * WBLK;
    int b14 = i * 14;
    tj.j[b14+0]  = TJob{adaln_scale_w + (size_t)i*CS*CA, wb0 + o_ascale, CS, CA};
    tj.j[b14+1]  = TJob{adaln_shift_w + (size_t)i*CS*CA, wb0 + o_ashift, CS, CA};
    tj.j[b14+2]  = TJob{sgate_w       + (size_t)i*CS*CA, wb0 + o_sgate,  CS, CA};
    tj.j[b14+3]  = TJob{t_scale_w     + (size_t)i*CS*CA, wb0 + o_tscale, CS, CA};
    tj.j[b14+4]  = TJob{t_shift_w     + (size_t)i*CS*CA, wb0 + o_tshift, CS, CA};
    tj.j[b14+5]  = TJob{t_sgate_w     + (size_t)i*CS*CA, wb0 + o_tsgate, CS, CA};
    tj.j[b14+6]  = TJob{wq   + (size_t)i*CA*CA,   wb0 + o_wq,  CA, CA};
    tj.j[b14+7]  = TJob{wk   + (size_t)i*CA*CA,   wb0 + o_wk,  CA, CA};
    tj.j[b14+8]  = TJob{wv   + (size_t)i*CA*CA,   wb0 + o_wv,  CA, CA};
    tj.j[b14+9]  = TJob{wg   + (size_t)i*CA*CA,   wb0 + o_wg,  CA, CA};
    tj.j[b14+10] = TJob{wo   + (size_t)i*CA*CA,   wb0 + o_wo,  CA, CA};
    tj.j[b14+11] = TJob{t_wa + (size_t)i*CA*HIDN, wb0 + o_twa, CA, HIDN};
    tj.j[b14+12] = TJob{t_wb + (size_t)i*CA*HIDN, wb0 + o_twb, CA, HIDN};
    tj.j[b14+13] = TJob{t_wo + (size_t)i*HIDN*CA, wb0 + o_two, HIDN, CA};
  }
  transpose_bf16<<<dim3(12, 8, 42), 256, 0, stream>>>(tj);

  bias3_kernel<<<dim3(4, WW, BB), 256, 0, stream>>>(p, lnz_w, lnz_b, wb_pair, biasT);

  // ALL 18 s_ln projections (iteration-invariant) in one launch
  {
    GemmJobs js = {};
    for (int i = 0; i < NBLK; ++i) {
      u16* wb0 = wbuf + (size_t)i * WBLK;
      js.j[i*6+0] = GemmJob{s_ln_bf, wb0 + o_ascale, nullptr, adaln_scale_b + i*CA, SP + (i*6+0)*MC, CS, CA, 1, 0};
      js.j[i*6+1] = GemmJob{s_ln_bf, wb0 + o_ashift, nullptr, nullptr,              SP + (i*6+1)*MC, CS, CA, 0, 0};
      js.j[i*6+2] = GemmJob{s_ln_bf, wb0 + o_sgate,  nullptr, sgate_b   + i*CA,     SP + (i*6+2)*MC, CS, CA, 1, 0};
      js.j[i*6+3] = GemmJob{s_ln_bf, wb0 + o_tscale, nullptr, t_scale_b + i*CA,     SP + (i*6+3)*MC, CS, CA, 1, 0};
      js.j[i*6+4] = GemmJob{s_ln_bf, wb0 + o_tshift, nullptr, nullptr,              SP + (i*6+4)*MC, CS, CA, 0, 0};
      js.j[i*6+5] = GemmJob{s_ln_bf, wb0 + o_tsgate, nullptr, t_sgate_b + i*CA,     SP + (i*6+5)*MC, CS, CA, 1, 0};
    }
    gemm_mfma<false><<<dim3(1, MR/128, 18), 256, 0, stream>>>(js);
  }

  for (int i = 0; i < NBLK; ++i) {
    const float* a_in = (i == 0) ? q : (i == 1 ? abuf0 : abuf1);
    float* a_out = (i == 2) ? out : (i == 0 ? abuf0 : abuf1);
    u16* wb0 = wbuf + (size_t)i * WBLK;

    // LN(a) + both modulations -> bf16
    modln_kernel<<<MR/4, 256, 0, stream>>>(a_in, SP + (i*6+0)*MC, SP + (i*6+1)*MC,
                                           SP + (i*6+3)*MC, SP + (i*6+4)*MC, amod, tmod);

    // Q, K, V(transposed), G projections -> bf16
    GemmJobs jq = {};
    jq.j[0] = GemmJob{amod, wb0 + o_wq, nullptr, bq + i*CA, Qb,  CA, CA, 0, 0};
    jq.j[1] = GemmJob{amod, wb0 + o_wk, nullptr, nullptr,   Kb,  CA, CA, 0, 0};
    jq.j[2] = GemmJob{amod, wb0 + o_wv, nullptr, nullptr,   Vtb, CA, CA, 5, 0};
    jq.j[3] = GemmJob{amod, wb0 + o_wg, nullptr, nullptr,   Gb,  CA, CA, 1, 0};
    gemm_mfma<false><<<dim3(1, MR/128, 4), 256, 0, stream>>>(jq);

    // hidden = silu(tmod @ t_wa) * (tmod @ t_wb)  -> bf16 (N=256)
    GemmJobs jh = {};
    jh.j[0] = GemmJob{tmod, wb0 + o_twa, wb0 + o_twb, nullptr, HIDb, CA, HIDN, 4, 0};
    gemm_mfma<true><<<dim3(2, MR/128, 1), 256, 0, stream>>>(jh);

    // windowed attention (MFMA, g-gated bf16 out)
    attn_mfma<<<dim3(WW, HH, BB), 64, 0, stream>>>(
        Qb, Kb, Vtb, Gb, biasT + (size_t)i * BB*WW*HH*4096, Ob);

    // a_out = (O @ wo)*sgate + (HID @ two)*tsgate
    combo_kernel<<<dim3(1, MR/64), 256, 0, stream>>>(
        Ob, HIDb, wb0 + o_wo, wb0 + o_two,
        SP + (i*6+2)*MC, SP + (i*6+5)*MC, a_out);
  }
}

// Round 7
// 559.990 us; speedup vs baseline: 1.1389x; 1.0234x over previous
//
#include <hip/hip_runtime.h>
#include <hip/hip_bf16.h>
#include <cstddef>
#include <cstdint>

// Problem constants
#define BB   2
#define NN   8192
#define CA   128
#define CS   384
#define CZ   16
#define HH   4
#define DD   32
#define NQW  32      // NQ
#define NKW  128     // NK
#define NBLK 3
#define WW   256     // N / NQ
#define MR   (BB*NN) // 16384 rows
#define HIDN 256     // 2*CA

typedef unsigned short u16;
typedef __attribute__((ext_vector_type(8))) short short8;
typedef __attribute__((ext_vector_type(4))) float floatx4;

__device__ __forceinline__ float sigmoidf_(float x) { return 1.f / (1.f + __expf(-x)); }

__device__ __forceinline__ u16 f2bf(float x) {
  unsigned u = __float_as_uint(x);
  unsigned r = (u + 0x7fffu + ((u >> 16) & 1u)) >> 16;
  return (u16)r;
}
__device__ __forceinline__ float bf2f(u16 u) {
  return __uint_as_float(((unsigned)u) << 16);
}

// Async global->LDS, 16B per lane. LDS dest is wave-uniform base + lane*16.
// LDS layout must be linear in lane order (no padding) -- m173.
__device__ __forceinline__ void gload16(const u16* g, u16* l) {
  __builtin_amdgcn_global_load_lds(
      (const __attribute__((address_space(1))) unsigned int*)g,
      (__attribute__((address_space(3))) unsigned int*)l, 16, 0, 0);
}

// ---------------------------------------------------------------------------
// LayerNorm of s (C_S = 384), one wave per row -> bf16 out.
// ---------------------------------------------------------------------------
__global__ __launch_bounds__(256) void ln_s_kernel(const float* __restrict__ s,
                                                   u16* __restrict__ s_ln_bf) {
  int row  = blockIdx.x * 4 + (threadIdx.x >> 6);
  int lane = threadIdx.x & 63;
  const float* sr = s + (size_t)row * CS;
  float x[6];
  float sum = 0.f, sq = 0.f;
#pragma unroll
  for (int t = 0; t < 6; ++t) { x[t] = sr[lane + 64*t]; sum += x[t]; sq += x[t]*x[t]; }
#pragma unroll
  for (int off = 32; off; off >>= 1) { sum += __shfl_down(sum, off); sq += __shfl_down(sq, off); }
  sum = __shfl(sum, 0); sq = __shfl(sq, 0);
  float mean = sum * (1.f/CS);
  float var  = sq  * (1.f/CS) - mean*mean;
  float rstd = rsqrtf(var + 1e-5f);
  u16* orow = s_ln_bf + (size_t)row * CS;
#pragma unroll
  for (int t = 0; t < 6; ++t) orow[lane + 64*t] = f2bf((x[t]-mean)*rstd);
}

// ---------------------------------------------------------------------------
// LN(a) + adaLN modulation (iter 0 only: a == q input).
// ---------------------------------------------------------------------------
__global__ __launch_bounds__(256) void modln_kernel(const float* __restrict__ a,
                                                    const u16* __restrict__ sp0,
                                                    const u16* __restrict__ sp1,
                                                    const u16* __restrict__ sp3,
                                                    const u16* __restrict__ sp4,
                                                    u16* __restrict__ amod,
                                                    u16* __restrict__ tmod) {
  int row  = blockIdx.x * 4 + (threadIdx.x >> 6);
  int lane = threadIdx.x & 63;
  const float* ar = a + (size_t)row * CA;
  float x0 = ar[lane], x1 = ar[lane + 64];
  float sum = x0 + x1, sq = x0*x0 + x1*x1;
#pragma unroll
  for (int off = 32; off; off >>= 1) { sum += __shfl_down(sum, off); sq += __shfl_down(sq, off); }
  sum = __shfl(sum, 0); sq = __shfl(sq, 0);
  float mean = sum * (1.f/CA);
  float var  = sq  * (1.f/CA) - mean*mean;
  float rstd = rsqrtf(var + 1e-5f);
  float n0 = (x0-mean)*rstd, n1 = (x1-mean)*rstd;
  size_t i0 = (size_t)row * CA + lane;
  amod[i0]      = f2bf(bf2f(sp0[i0])     *n0 + bf2f(sp1[i0]));
  amod[i0 + 64] = f2bf(bf2f(sp0[i0 + 64])*n1 + bf2f(sp1[i0 + 64]));
  tmod[i0]      = f2bf(bf2f(sp3[i0])     *n0 + bf2f(sp4[i0]));
  tmod[i0 + 64] = f2bf(bf2f(sp3[i0 + 64])*n1 + bf2f(sp4[i0 + 64]));
}

// ---------------------------------------------------------------------------
// Weight transpose+convert: src fp32 K x N (row-major)  ->  dst bf16 N x K.
// ---------------------------------------------------------------------------
struct TJob { const float* src; u16* dst; int K; int N; };
struct TJobs { TJob j[42]; };

__global__ __launch_bounds__(256) void transpose_bf16(TJobs jobs) {
  TJob jb = jobs.j[blockIdx.z];
  int tk = blockIdx.x * 32, tn = blockIdx.y * 32;
  if (tk >= jb.K || tn >= jb.N) return;
  __shared__ float tile[32][33];
  int tx = threadIdx.x & 31;
  int ty = threadIdx.x >> 5;
#pragma unroll
  for (int r = ty; r < 32; r += 8) tile[r][tx] = jb.src[(size_t)(tk + r) * jb.N + tn + tx];
  __syncthreads();
#pragma unroll
  for (int r = ty; r < 32; r += 8)
    jb.dst[(size_t)(tn + r) * jb.K + tk + tx] = f2bf(tile[tx][r]);
}

// ---------------------------------------------------------------------------
// bf16 MFMA GEMM.  128x128 block tile, BK=32, 4 waves (2x2 of 64x64).
// Counted-vmcnt pipeline (unchanged from round 6; equal-best measured).
// modes: 0 = (+bias)->bf16, 1 = sigmoid(+bias)->bf16,
// 4 (DUAL) = silu(A@B)*(A@B2) -> bf16, 5 = transposed bf16 write (V).
// ---------------------------------------------------------------------------
struct GemmJob {
  const u16* A;
  const u16* Bt;
  const u16* Bt2;
  const float* bias;
  u16* outbf;
  int K;
  int ostride;
  int mode;
  int pad;
};
struct GemmJobs { GemmJob j[18]; };

template <bool DUAL>
__global__ __launch_bounds__(256) void gemm_mfma(GemmJobs jobs) {
  GemmJob jb = jobs.j[blockIdx.z];
  const int bm = blockIdx.y * 128, bn = blockIdx.x * 128;
  const int K = jb.K;

  __shared__ u16 As[3][4096];
  __shared__ u16 Bs[3][4096];
  __shared__ u16 Bs2[DUAL ? 3 : 1][DUAL ? 4096 : 8];

  const int tid  = threadIdx.x;
  const int lane = tid & 63;
  const int wave = tid >> 6;
  const int wr = wave >> 1, wc = wave & 1;
  const int l15 = lane & 15, quad = lane >> 4;

  floatx4 acc[4][4] = {};
  floatx4 acc2[DUAL ? 4 : 1][DUAL ? 4 : 1] = {};

  const u16* Ab0  = jb.A  + ((size_t)bm + lane) * K + wave * 8;
  const u16* Ab1  = jb.A  + ((size_t)bm + 64 + lane) * K + wave * 8;
  const u16* Bb0  = jb.Bt + ((size_t)bn + lane) * K + wave * 8;
  const u16* Bb1  = jb.Bt + ((size_t)bn + 64 + lane) * K + wave * 8;
  const u16* B2b0 = DUAL ? (jb.Bt2 + ((size_t)bn + lane) * K + wave * 8) : nullptr;
  const u16* B2b1 = DUAL ? (jb.Bt2 + ((size_t)bn + 64 + lane) * K + wave * 8) : nullptr;

  auto stage = [&](int k0, int pb) {
    gload16(Ab0 + k0, As[pb] + wave * 1024);
    gload16(Ab1 + k0, As[pb] + wave * 1024 + 512);
    gload16(Bb0 + k0, Bs[pb] + wave * 1024);
    gload16(Bb1 + k0, Bs[pb] + wave * 1024 + 512);
    if constexpr (DUAL) {
      gload16(B2b0 + k0, Bs2[pb] + wave * 1024);
      gload16(B2b1 + k0, Bs2[pb] + wave * 1024 + 512);
    }
  };

  auto compute = [&](int pb) {
    short8 a_frag[4], b_frag[4];
#pragma unroll
    for (int mt = 0; mt < 4; ++mt)
      a_frag[mt] = *(const short8*)(As[pb] + quad * 1024 + (wr * 64 + mt * 16 + l15) * 8);
#pragma unroll
    for (int nt = 0; nt < 4; ++nt)
      b_frag[nt] = *(const short8*)(Bs[pb] + quad * 1024 + (wc * 64 + nt * 16 + l15) * 8);
#pragma unroll
    for (int mt = 0; mt < 4; ++mt)
#pragma unroll
      for (int nt = 0; nt < 4; ++nt)
        acc[mt][nt] = __builtin_amdgcn_mfma_f32_16x16x32_bf16(a_frag[mt], b_frag[nt], acc[mt][nt], 0, 0, 0);
    if constexpr (DUAL) {
      short8 b2_frag[4];
#pragma unroll
      for (int nt = 0; nt < 4; ++nt)
        b2_frag[nt] = *(const short8*)(Bs2[pb] + quad * 1024 + (wc * 64 + nt * 16 + l15) * 8);
#pragma unroll
      for (int mt = 0; mt < 4; ++mt)
#pragma unroll
        for (int nt = 0; nt < 4; ++nt)
          acc2[mt][nt] = __builtin_amdgcn_mfma_f32_16x16x32_bf16(a_frag[mt], b2_frag[nt], acc2[mt][nt], 0, 0, 0);
    }
  };

  stage(0, 0);
  stage(32, 1);
  int cur = 0;
  for (int k0 = 0; k0 + 64 < K; k0 += 32) {
    stage(k0 + 64, (cur + 2) % 3);
    if constexpr (DUAL) asm volatile("s_waitcnt vmcnt(12)" ::: "memory");
    else                asm volatile("s_waitcnt vmcnt(8)"  ::: "memory");
    __builtin_amdgcn_s_barrier();
    compute(cur);
    __builtin_amdgcn_s_barrier();
    cur = (cur + 1) % 3;
  }
  if constexpr (DUAL) asm volatile("s_waitcnt vmcnt(6)" ::: "memory");
  else                asm volatile("s_waitcnt vmcnt(4)" ::: "memory");
  __builtin_amdgcn_s_barrier();
  compute(cur);
  __builtin_amdgcn_s_barrier();
  cur = (cur + 1) % 3;
  asm volatile("s_waitcnt vmcnt(0)" ::: "memory");
  __builtin_amdgcn_s_barrier();
  compute(cur);

  // Epilogue.  C/D layout: col = lane&15, row = quad*4 + reg.
#pragma unroll
  for (int mt = 0; mt < 4; ++mt) {
#pragma unroll
    for (int nt = 0; nt < 4; ++nt) {
      int n = bn + wc * 64 + nt * 16 + l15;
      int mbase = bm + wr * 64 + mt * 16 + quad * 4;
      floatx4 v = acc[mt][nt];
      if constexpr (DUAL) {
        floatx4 v2 = acc2[mt][nt];
#pragma unroll
        for (int r = 0; r < 4; ++r) {
          size_t idx = (size_t)(mbase + r) * jb.ostride + n;
          float x1 = v[r];
          jb.outbf[idx] = f2bf(x1 * sigmoidf_(x1) * v2[r]);
        }
      } else if (jb.mode == 5) {
        int bidx = mbase >> 13;          // m / NN
        int tok  = mbase & (NN - 1);
        ushort4 o;
        o.x = f2bf(v[0]); o.y = f2bf(v[1]); o.z = f2bf(v[2]); o.w = f2bf(v[3]);
        *(ushort4*)(jb.outbf + (size_t)(bidx * CA + n) * NN + tok) = o;
      } else {
        float bias = jb.bias ? jb.bias[n] : 0.f;
#pragma unroll
        for (int r = 0; r < 4; ++r) {
          size_t idx = (size_t)(mbase + r) * jb.ostride + n;
          float x = v[r] + bias;
          jb.outbf[idx] = f2bf(jb.mode == 1 ? sigmoidf_(x) : x);
        }
      }
    }
  }
}

// ---------------------------------------------------------------------------
// Combo output kernel, fused with next-iteration modln.
// aval = (O @ woT)*g1 + (HID @ twoT)*g2   (this is the new `a`, fp32 in regs)
// MODE 0: row-LN(aval) in-epilogue (2-wave LDS combine), write
//         amod = sig_sp0*n + sp1, tmod = sig_sp3*n + sp4 (bf16) for iter i+1.
//         `a` itself is never written to memory.
// MODE 1: write aval as fp32 (final output).
// ---------------------------------------------------------------------------
template <int MODE>
__global__ __launch_bounds__(256) void combo_kernel(const u16* __restrict__ O,
                                                    const u16* __restrict__ HID,
                                                    const u16* __restrict__ woT,
                                                    const u16* __restrict__ twoT,
                                                    const u16* __restrict__ g1,
                                                    const u16* __restrict__ g2,
                                                    const u16* __restrict__ sp0,
                                                    const u16* __restrict__ sp1,
                                                    const u16* __restrict__ sp3,
                                                    const u16* __restrict__ sp4,
                                                    u16* __restrict__ amod,
                                                    u16* __restrict__ tmod,
                                                    float* __restrict__ outp) {
  const int bm = blockIdx.y * 64;
  __shared__ u16 As1[2][2048];
  __shared__ u16 Bs1[2][4096];
  __shared__ u16 As2[2][2048];
  __shared__ u16 Bs2h[2][4096];
  __shared__ float hsum[2][64];
  __shared__ float hsq[2][64];
  const int tid  = threadIdx.x;
  const int lane = tid & 63;
  const int wave = tid >> 6;
  const int wr = wave >> 1, wc = wave & 1;
  const int l15 = lane & 15, quad = lane >> 4;

  floatx4 acc1[2][4] = {};
  floatx4 acc2[2][4] = {};

  const u16* A1  = O    + ((size_t)bm + lane) * CA + wave * 8;
  const u16* B10 = woT  + ((size_t)lane) * CA + wave * 8;
  const u16* B11 = woT  + ((size_t)64 + lane) * CA + wave * 8;
  const u16* A2  = HID  + ((size_t)bm + lane) * HIDN + wave * 8;
  const u16* B20 = twoT + ((size_t)lane) * HIDN + wave * 8;
  const u16* B21 = twoT + ((size_t)64 + lane) * HIDN + wave * 8;

  auto stage1 = [&](int k0, int pb) {
    gload16(A1  + k0, As1[pb] + wave * 512);
    gload16(B10 + k0, Bs1[pb] + wave * 1024);
    gload16(B11 + k0, Bs1[pb] + wave * 1024 + 512);
  };
  auto stage2 = [&](int k0, int pb) {
    gload16(A2  + k0, As2[pb] + wave * 512);
    gload16(B20 + k0, Bs2h[pb] + wave * 1024);
    gload16(B21 + k0, Bs2h[pb] + wave * 1024 + 512);
  };

  stage1(0, 0);
  stage2(0, 0);
  __syncthreads();
  int cur = 0;
  for (int t = 0; t < 8; ++t) {
    if (t + 1 < 4) stage1((t + 1) * 32, cur ^ 1);
    if (t + 1 < 8) stage2((t + 1) * 32, cur ^ 1);

    if (t < 4) {
      short8 a_frag[2], b_frag[4];
#pragma unroll
      for (int mt = 0; mt < 2; ++mt)
        a_frag[mt] = *(const short8*)(As1[cur] + quad * 512 + (wr * 32 + mt * 16 + l15) * 8);
#pragma unroll
      for (int nt = 0; nt < 4; ++nt)
        b_frag[nt] = *(const short8*)(Bs1[cur] + quad * 1024 + (wc * 64 + nt * 16 + l15) * 8);
#pragma unroll
      for (int mt = 0; mt < 2; ++mt)
#pragma unroll
        for (int nt = 0; nt < 4; ++nt)
          acc1[mt][nt] = __builtin_amdgcn_mfma_f32_16x16x32_bf16(a_frag[mt], b_frag[nt], acc1[mt][nt], 0, 0, 0);
    }
    {
      short8 a_frag[2], b_frag[4];
#pragma unroll
      for (int mt = 0; mt < 2; ++mt)
        a_frag[mt] = *(const short8*)(As2[cur] + quad * 512 + (wr * 32 + mt * 16 + l15) * 8);
#pragma unroll
      for (int nt = 0; nt < 4; ++nt)
        b_frag[nt] = *(const short8*)(Bs2h[cur] + quad * 1024 + (wc * 64 + nt * 16 + l15) * 8);
#pragma unroll
      for (int mt = 0; mt < 2; ++mt)
#pragma unroll
        for (int nt = 0; nt < 4; ++nt)
          acc2[mt][nt] = __builtin_amdgcn_mfma_f32_16x16x32_bf16(a_frag[mt], b_frag[nt], acc2[mt][nt], 0, 0, 0);
    }
    __syncthreads();
    cur ^= 1;
  }

  if constexpr (MODE == 1) {
#pragma unroll
    for (int mt = 0; mt < 2; ++mt) {
#pragma unroll
      for (int nt = 0; nt < 4; ++nt) {
        int n = wc * 64 + nt * 16 + l15;
        int mbase = bm + wr * 32 + mt * 16 + quad * 4;
#pragma unroll
        for (int r = 0; r < 4; ++r) {
          size_t idx = (size_t)(mbase + r) * CA + n;
          outp[idx] = acc1[mt][nt][r] * bf2f(g1[idx]) + acc2[mt][nt][r] * bf2f(g2[idx]);
        }
      }
    }
  } else {
    float aval[2][4][4];
#pragma unroll
    for (int mt = 0; mt < 2; ++mt)
#pragma unroll
      for (int nt = 0; nt < 4; ++nt) {
        int n = wc * 64 + nt * 16 + l15;
        int mbase = bm + wr * 32 + mt * 16 + quad * 4;
#pragma unroll
        for (int r = 0; r < 4; ++r) {
          size_t idx = (size_t)(mbase + r) * CA + n;
          aval[mt][nt][r] = acc1[mt][nt][r] * bf2f(g1[idx]) + acc2[mt][nt][r] * bf2f(g2[idx]);
        }
      }
    // row stats: each wave holds a 64-col half of rows wr*32..wr*32+31
#pragma unroll
    for (int mt = 0; mt < 2; ++mt)
#pragma unroll
      for (int r = 0; r < 4; ++r) {
        float s = 0.f, sq = 0.f;
#pragma unroll
        for (int nt = 0; nt < 4; ++nt) { float v = aval[mt][nt][r]; s += v; sq += v * v; }
        s  += __shfl_xor(s, 1);  s  += __shfl_xor(s, 2);  s  += __shfl_xor(s, 4);  s  += __shfl_xor(s, 8);
        sq += __shfl_xor(sq, 1); sq += __shfl_xor(sq, 2); sq += __shfl_xor(sq, 4); sq += __shfl_xor(sq, 8);
        if (l15 == 0) {
          int row = wr * 32 + mt * 16 + quad * 4 + r;
          hsum[wc][row] = s;
          hsq[wc][row]  = sq;
        }
      }
    __syncthreads();
#pragma unroll
    for (int mt = 0; mt < 2; ++mt)
#pragma unroll
      for (int r = 0; r < 4; ++r) {
        int row = wr * 32 + mt * 16 + quad * 4 + r;
        float tot  = hsum[0][row] + hsum[1][row];
        float totq = hsq[0][row]  + hsq[1][row];
        float mean = tot * (1.f / CA);
        float var  = totq * (1.f / CA) - mean * mean;
        float rstd = rsqrtf(var + 1e-5f);
        int mrow = bm + row;
#pragma unroll
        for (int nt = 0; nt < 4; ++nt) {
          int n = wc * 64 + nt * 16 + l15;
          size_t idx = (size_t)mrow * CA + n;
          float nv = (aval[mt][nt][r] - mean) * rstd;
          amod[idx] = f2bf(bf2f(sp0[idx]) * nv + bf2f(sp1[idx]));
          tmod[idx] = f2bf(bf2f(sp3[idx]) * nv + bf2f(sp4[idx]));
        }
      }
  }
}

// ---------------------------------------------------------------------------
// Pair bias for ALL 3 blocks in one pass over p; no LDS transpose, direct
// ushort4 stores.  Grid (4 k-chunks, W, B).
// Output layout: biasT[i][b][w][h][k][q] (bf16).
// ---------------------------------------------------------------------------
__global__ __launch_bounds__(256) void bias3_kernel(const float* __restrict__ p,
                                                    const float* __restrict__ lnz_w,
                                                    const float* __restrict__ lnz_b,
                                                    const float* __restrict__ wb,
                                                    u16* __restrict__ biasT) {
  const int kc = blockIdx.x, w = blockIdx.y, b = blockIdx.z;
  __shared__ float effW[12][16];
  __shared__ float effb[12];
  const int t = threadIdx.x;
  if (t < 192) {
    int i = t >> 6, rem = t & 63, z = rem >> 2, hh = rem & 3;
    effW[i*4 + hh][z] = lnz_w[i*CZ + z] * wb[(i*CZ + z)*HH + hh];
  }
  if (t < 12) {
    int i = t >> 2, hh = t & 3;
    float acc = 0.f;
    for (int z = 0; z < 16; ++z) acc += lnz_b[i*CZ + z] * wb[(i*CZ + z)*HH + hh];
    effb[t] = acc;
  }
  __syncthreads();

  const int kk = t & 31, qg = (t >> 5) * 4;
  const int k = kc * 32 + kk;
  u16 out4[12][4];
#pragma unroll
  for (int r = 0; r < 4; ++r) {
    int qq = qg + r;
    const float4* pr = (const float4*)(p + (size_t)(((b * WW + w) * NQW + qq) * NKW + k) * 16);
    float4 p0 = pr[0], p1 = pr[1], p2 = pr[2], p3 = pr[3];
    float x[16] = {p0.x,p0.y,p0.z,p0.w, p1.x,p1.y,p1.z,p1.w,
                   p2.x,p2.y,p2.z,p2.w, p3.x,p3.y,p3.z,p3.w};
    float sum = 0.f, sq = 0.f;
#pragma unroll
    for (int z = 0; z < 16; ++z) { sum += x[z]; sq += x[z]*x[z]; }
    float mean = sum * (1.f/16.f);
    float var  = sq  * (1.f/16.f) - mean*mean;
    float rstd = rsqrtf(var + 1e-5f);
#pragma unroll
    for (int ih = 0; ih < 12; ++ih) {
      float acc = effb[ih];
#pragma unroll
      for (int z = 0; z < 16; ++z) acc += (x[z]-mean)*rstd * effW[ih][z];
      out4[ih][r] = f2bf(acc);
    }
  }
#pragma unroll
  for (int ih = 0; ih < 12; ++ih) {
    int i = ih >> 2, hh = ih & 3;
    u16* dst = biasT + ((((size_t)i * BB + b) * WW + w) * HH + hh) * 4096 + (size_t)k * 32 + qg;
    ushort4 uv; uv.x = out4[ih][0]; uv.y = out4[ih][1]; uv.z = out4[ih][2]; uv.w = out4[ih][3];
    *(ushort4*)dst = uv;
  }
}

// ---------------------------------------------------------------------------
// MFMA windowed attention: one WAVE per (w, h, b).  1-D grid with XCD chunk
// swizzle: each XCD owns one (b,h) and ALL 256 windows -> K/V/bias slices
// (~3 MB) stay L2-resident across the 96/128-token window overlap.
// ---------------------------------------------------------------------------
__global__ __launch_bounds__(64) void attn_mfma(const u16* __restrict__ Qb,
                                                const u16* __restrict__ Kb,
                                                const u16* __restrict__ Vtb,
                                                const u16* __restrict__ Gb,
                                                const u16* __restrict__ biasT,
                                                u16* __restrict__ Ob) {
  const int lin = blockIdx.x;                      // 2048 blocks
  const int swz = (lin & 7) * 256 + (lin >> 3);    // XCD chunk swizzle
  const int b = swz >> 10;                         // swz = b*1024 + h*256 + w
  const int h = (swz >> 8) & 3;
  const int w = swz & 255;
  __shared__ u16 Pt[128 * 36];
  __shared__ float inv_s[32];
  const int lane = threadIdx.x;
  const int l15 = lane & 15, quad = lane >> 4;
  const int tok0 = w * NQW - 48;

  short8 qf[2];
#pragma unroll
  for (int mt = 0; mt < 2; ++mt) {
    int qq = w * NQW + mt * 16 + l15;
    qf[mt] = *(const short8*)(Qb + (size_t)(b * NN + qq) * CA + h * DD + quad * 8);
  }
  floatx4 lg[2][8] = {};
#pragma unroll
  for (int nt = 0; nt < 8; ++nt) {
    int tk = tok0 + nt * 16 + l15;
    int tc = min(max(tk, 0), NN - 1);
    short8 kf = *(const short8*)(Kb + (size_t)(b * NN + tc) * CA + h * DD + quad * 8);
#pragma unroll
    for (int mt = 0; mt < 2; ++mt)
      lg[mt][nt] = __builtin_amdgcn_mfma_f32_16x16x32_bf16(qf[mt], kf, lg[mt][nt], 0, 0, 0);
  }

  const float scale = 0.17677669529663687f;   // 1/sqrt(32)
  const u16* bb = biasT + ((((size_t)b * WW + w) * HH + h) << 12);
  float mrow[2][4];
#pragma unroll
  for (int mt = 0; mt < 2; ++mt)
#pragma unroll
    for (int r = 0; r < 4; ++r) mrow[mt][r] = -3.0e38f;
#pragma unroll
  for (int nt = 0; nt < 8; ++nt) {
    int tk = tok0 + nt * 16 + l15;
    bool valid = (tk >= 0) && (tk < NN);
#pragma unroll
    for (int mt = 0; mt < 2; ++mt) {
      ushort4 bv = *(const ushort4*)(bb + (nt * 16 + l15) * 32 + mt * 16 + quad * 4);
      float bvf[4] = {bf2f(bv.x), bf2f(bv.y), bf2f(bv.z), bf2f(bv.w)};
#pragma unroll
      for (int r = 0; r < 4; ++r) {
        float l = valid ? (lg[mt][nt][r] * scale + bvf[r]) : -1e9f;
        lg[mt][nt][r] = l;
        mrow[mt][r] = fmaxf(mrow[mt][r], l);
      }
    }
  }
#pragma unroll
  for (int mt = 0; mt < 2; ++mt)
#pragma unroll
    for (int r = 0; r < 4; ++r) {
      float m = mrow[mt][r];
      m = fmaxf(m, __shfl_xor(m, 1));
      m = fmaxf(m, __shfl_xor(m, 2));
      m = fmaxf(m, __shfl_xor(m, 4));
      m = fmaxf(m, __shfl_xor(m, 8));
      mrow[mt][r] = m;
    }

  float srow[2][4] = {};
#pragma unroll
  for (int nt = 0; nt < 8; ++nt)
#pragma unroll
    for (int mt = 0; mt < 2; ++mt) {
      u16 pv[4];
#pragma unroll
      for (int r = 0; r < 4; ++r) {
        float e = __expf(lg[mt][nt][r] - mrow[mt][r]);
        srow[mt][r] += e;
        pv[r] = f2bf(e);
      }
      ushort4 uv; uv.x = pv[0]; uv.y = pv[1]; uv.z = pv[2]; uv.w = pv[3];
      *(ushort4*)(Pt + (nt * 16 + l15) * 36 + mt * 16 + quad * 4) = uv;
    }
#pragma unroll
  for (int mt = 0; mt < 2; ++mt)
#pragma unroll
    for (int r = 0; r < 4; ++r) {
      float ssum = srow[mt][r];
      ssum += __shfl_xor(ssum, 1);
      ssum += __shfl_xor(ssum, 2);
      ssum += __shfl_xor(ssum, 4);
      ssum += __shfl_xor(ssum, 8);
      if (l15 == 0) inv_s[mt * 16 + quad * 4 + r] = 1.f / ssum;
    }
  __syncthreads();

  floatx4 oacc[2][2] = {};
#pragma unroll
  for (int ks = 0; ks < 4; ++ks) {
    short8 pf[2];
#pragma unroll
    for (int ntq = 0; ntq < 2; ++ntq)
#pragma unroll
      for (int j = 0; j < 8; ++j)
        pf[ntq][j] = (short)Pt[(ks * 32 + quad * 8 + j) * 36 + ntq * 16 + l15];
    int tb = tok0 + ks * 32 + quad * 8;
    tb = min(max(tb, 0), NN - 8);
#pragma unroll
    for (int mtd = 0; mtd < 2; ++mtd) {
      short8 vf = *(const short8*)(Vtb + (size_t)(b * CA + h * DD + mtd * 16 + l15) * NN + tb);
#pragma unroll
      for (int ntq = 0; ntq < 2; ++ntq)
        oacc[mtd][ntq] = __builtin_amdgcn_mfma_f32_16x16x32_bf16(vf, pf[ntq], oacc[mtd][ntq], 0, 0, 0);
    }
  }

#pragma unroll
  for (int mtd = 0; mtd < 2; ++mtd)
#pragma unroll
    for (int ntq = 0; ntq < 2; ++ntq) {
      int qq = ntq * 16 + l15;
      float inv = inv_s[qq];
      int tok = w * NQW + qq;
      size_t base = (size_t)(b * NN + tok) * CA + h * DD + mtd * 16 + quad * 4;
      ushort4 gv = *(const ushort4*)(Gb + base);
      floatx4 v = oacc[mtd][ntq];
      ushort4 o;
      o.x = f2bf(bf2f(gv.x) * v[0] * inv);
      o.y = f2bf(bf2f(gv.y) * v[1] * inv);
      o.z = f2bf(bf2f(gv.z) * v[2] * inv);
      o.w = f2bf(bf2f(gv.w) * v[3] * inv);
      *(ushort4*)(Ob + base) = o;
    }
}

// ---------------------------------------------------------------------------
// Host-side orchestration.
// ---------------------------------------------------------------------------
extern "C" void kernel_launch(void* const* d_in, const int* in_sizes, int n_in,
                              void* d_out, int out_size, void* d_ws, size_t ws_size,
                              hipStream_t stream) {
  const float* q             = (const float*)d_in[0];
  const float* s             = (const float*)d_in[1];
  const float* p             = (const float*)d_in[2];
  const float* adaln_scale_w = (const float*)d_in[3];
  const float* adaln_scale_b = (const float*)d_in[4];
  const float* adaln_shift_w = (const float*)d_in[5];
  const float* wq            = (const float*)d_in[6];
  const float* bq            = (const float*)d_in[7];
  const float* wk            = (const float*)d_in[8];
  const float* wv            = (const float*)d_in[9];
  const float* lnz_w         = (const float*)d_in[10];
  const float* lnz_b         = (const float*)d_in[11];
  const float* wb_pair       = (const float*)d_in[12];
  const float* wg            = (const float*)d_in[13];
  const float* wo            = (const float*)d_in[14];
  const float* sgate_w       = (const float*)d_in[15];
  const float* sgate_b       = (const float*)d_in[16];
  const float* t_scale_w     = (const float*)d_in[17];
  const float* t_scale_b     = (const float*)d_in[18];
  const float* t_shift_w     = (const float*)d_in[19];
  const float* t_wa          = (const float*)d_in[20];
  const float* t_wb          = (const float*)d_in[21];
  const float* t_wo          = (const float*)d_in[22];
  const float* t_sgate_w     = (const float*)d_in[23];
  const float* t_sgate_b     = (const float*)d_in[24];
  float* out = (float*)d_out;

  const size_t MC = (size_t)MR * CA; // 2097152
  float* fws   = (float*)d_ws;
  float* abuf0 = fws;                          // (unused; layout kept)
  float* abuf1 = abuf0 + MC;
  u16* uws     = (u16*)(abuf1 + MC);
  u16* s_ln_bf = uws;                          // MR*CS
  u16* SP      = s_ln_bf + (size_t)MR * CS;    // 18*MC
  u16* amod    = SP + 18*MC;
  u16* tmod    = amod + MC;
  u16* Qb      = tmod + MC;
  u16* Kb      = Qb + MC;
  u16* Vtb     = Kb + MC;                      // [b][128][NN]
  u16* Gb      = Vtb + MC;
  u16* Ob      = Gb + MC;
  u16* HIDb    = Ob + MC;                      // MR*HIDN = 2*MC
  u16* biasT   = HIDb + 2*MC;                  // 3*BB*WW*HH*4096
  u16* wbuf    = biasT + (size_t)3*BB*WW*HH*NQW*NKW;

  const size_t WBLK = 6*(size_t)CA*CS + 5*(size_t)CA*CA + 3*(size_t)CA*HIDN;
  const size_t o_ascale = 0;
  const size_t o_ashift = o_ascale + (size_t)CA*CS;
  const size_t o_sgate  = o_ashift + (size_t)CA*CS;
  const size_t o_tscale = o_sgate  + (size_t)CA*CS;
  const size_t o_tshift = o_tscale + (size_t)CA*CS;
  const size_t o_tsgate = o_tshift + (size_t)CA*CS;
  const size_t o_wq     = o_tsgate + (size_t)CA*CS;
  const size_t o_wk     = o_wq + (size_t)CA*CA;
  const size_t o_wv     = o_wk + (size_t)CA*CA;
  const size_t o_wg     = o_wv + (size_t)CA*CA;
  const size_t o_wo     = o_wg + (size_t)CA*CA;
  const size_t o_twa    = o_wo + (size_t)CA*CA;
  const size_t o_twb    = o_twa + (size_t)HIDN*CA;
  const size_t o_two    = o_twb + (size_t)HIDN*CA;

  // ---- one-time work ----
  ln_s_kernel<<<MR/4, 256, 0, stream>>>(s, s_ln_bf);

  TJobs tj;
  for (int i = 0; i < NBLK; ++i) {
    u16* wb0 = wbuf + (size_t)i * WBLK;
    int b14 = i * 14;
    tj.j[b14+0]  = TJob{adaln_scale_w + (size_t)i*CS*CA, wb0 + o_ascale, CS, CA};
    tj.j[b14+1]  = TJob{adaln_shift_w + (size_t)i*CS*CA, wb0 + o_ashift, CS, CA};
    tj.j[b14+2]  = TJob{sgate_w       + (size_t)i*CS*CA, wb0 + o_sgate,  CS, CA};
    tj.j[b14+3]  = TJob{t_scale_w     + (size_t)i*CS*CA, wb0 + o_tscale, CS, CA};
    tj.j[b14+4]  = TJob{t_shift_w     + (size_t)i*CS*CA, wb0 + o_tshift, CS, CA};
    tj.j[b14+5]  = TJob{t_sgate_w     + (size_t)i*CS*CA, wb0 + o_tsgate, CS, CA};
    tj.j[b14+6]  = TJob{wq   + (size_t)i*CA*CA,   wb0 + o_wq,  CA, CA};
    tj.j[b14+7]  = TJob{wk   + (size_t)i*CA*CA,   wb0 + o_wk,  CA, CA};
    tj.j[b14+8]  = TJob{wv   + (size_t)i*CA*CA,   wb0 + o_wv,  CA, CA};
    tj.j[b14+9]  = TJob{wg   + (size_t)i*CA*CA,   wb0 + o_wg,  CA, CA};
    tj.j[b14+10] = TJob{wo   + (size_t)i*CA*CA,   wb0 + o_wo,  CA, CA};
    tj.j[b14+11] = TJob{t_wa + (size_t)i*CA*HIDN, wb0 + o_twa, CA, HIDN};
    tj.j[b14+12] = TJob{t_wb + (size_t)i*CA*HIDN, wb0 + o_twb, CA, HIDN};
    tj.j[b14+13] = TJob{t_wo + (size_t)i*HIDN*CA, wb0 + o_two, HIDN, CA};
  }
  transpose_bf16<<<dim3(12, 8, 42), 256, 0, stream>>>(tj);

  bias3_kernel<<<dim3(4, WW, BB), 256, 0, stream>>>(p, lnz_w, lnz_b, wb_pair, biasT);

  // ALL 18 s_ln projections (iteration-invariant) in one launch
  {
    GemmJobs js = {};
    for (int i = 0; i < NBLK; ++i) {
      u16* wb0 = wbuf + (size_t)i * WBLK;
      js.j[i*6+0] = GemmJob{s_ln_bf, wb0 + o_ascale, nullptr, adaln_scale_b + i*CA, SP + (i*6+0)*MC, CS, CA, 1, 0};
      js.j[i*6+1] = GemmJob{s_ln_bf, wb0 + o_ashift, nullptr, nullptr,              SP + (i*6+1)*MC, CS, CA, 0, 0};
      js.j[i*6+2] = GemmJob{s_ln_bf, wb0 + o_sgate,  nullptr, sgate_b   + i*CA,     SP + (i*6+2)*MC, CS, CA, 1, 0};
      js.j[i*6+3] = GemmJob{s_ln_bf, wb0 + o_tscale, nullptr, t_scale_b + i*CA,     SP + (i*6+3)*MC, CS, CA, 1, 0};
      js.j[i*6+4] = GemmJob{s_ln_bf, wb0 + o_tshift, nullptr, nullptr,              SP + (i*6+4)*MC, CS, CA, 0, 0};
      js.j[i*6+5] = GemmJob{s_ln_bf, wb0 + o_tsgate, nullptr, t_sgate_b + i*CA,     SP + (i*6+5)*MC, CS, CA, 1, 0};
    }
    gemm_mfma<false><<<dim3(1, MR/128, 18), 256, 0, stream>>>(js);
  }

  // iter 0 modulations come from q via standalone modln
  modln_kernel<<<MR/4, 256, 0, stream>>>(q, SP + 0*MC, SP + 1*MC,
                                         SP + 3*MC, SP + 4*MC, amod, tmod);

  for (int i = 0; i < NBLK; ++i) {
    u16* wb0 = wbuf + (size_t)i * WBLK;

    // Q, K, V(transposed), G projections -> bf16
    GemmJobs jq = {};
    jq.j[0] = GemmJob{amod, wb0 + o_wq, nullptr, bq + i*CA, Qb,  CA, CA, 0, 0};
    jq.j[1] = GemmJob{amod, wb0 + o_wk, nullptr, nullptr,   Kb,  CA, CA, 0, 0};
    jq.j[2] = GemmJob{amod, wb0 + o_wv, nullptr, nullptr,   Vtb, CA, CA, 5, 0};
    jq.j[3] = GemmJob{amod, wb0 + o_wg, nullptr, nullptr,   Gb,  CA, CA, 1, 0};
    gemm_mfma<false><<<dim3(1, MR/128, 4), 256, 0, stream>>>(jq);

    // hidden = silu(tmod @ t_wa) * (tmod @ t_wb)  -> bf16 (N=256)
    GemmJobs jh = {};
    jh.j[0] = GemmJob{tmod, wb0 + o_twa, wb0 + o_twb, nullptr, HIDb, CA, HIDN, 4, 0};
    gemm_mfma<true><<<dim3(2, MR/128, 1), 256, 0, stream>>>(jh);

    // windowed attention (MFMA, g-gated bf16 out), XCD-swizzled 1-D grid
    attn_mfma<<<WW * HH * BB, 64, 0, stream>>>(
        Qb, Kb, Vtb, Gb, biasT + (size_t)i * BB*WW*HH*4096, Ob);

    // a = (O @ wo)*sgate + (HID @ two)*tsgate, fused with next-iter modln
    if (i < NBLK - 1) {
      combo_kernel<0><<<dim3(1, MR/64), 256, 0, stream>>>(
          Ob, HIDb, wb0 + o_wo, wb0 + o_two,
          SP + (i*6+2)*MC, SP + (i*6+5)*MC,
          SP + ((i+1)*6+0)*MC, SP + ((i+1)*6+1)*MC,
          SP + ((i+1)*6+3)*MC, SP + ((i+1)*6+4)*MC,
          amod, tmod, nullptr);
    } else {
      combo_kernel<1><<<dim3(1, MR/64), 256, 0, stream>>>(
          Ob, HIDb, wb0 + o_wo, wb0 + o_two,
          SP + (i*6+2)*MC, SP + (i*6+5)*MC,
          nullptr, nullptr, nullptr, nullptr,
          nullptr, nullptr, out);
    }
  }
}

// Round 8
// 556.607 us; speedup vs baseline: 1.1459x; 1.0061x over previous
//
#include <hip/hip_runtime.h>
#include <hip/hip_bf16.h>
#include <cstddef>
#include <cstdint>

// Problem constants
#define BB   2
#define NN   8192
#define CA   128
#define CS   384
#define CZ   16
#define HH   4
#define DD   32
#define NQW  32      // NQ
#define NKW  128     // NK
#define NBLK 3
#define WW   256     // N / NQ
#define MR   (BB*NN) // 16384 rows
#define HIDN 256     // 2*CA

typedef unsigned short u16;
typedef __attribute__((ext_vector_type(8))) short short8;
typedef __attribute__((ext_vector_type(4))) float floatx4;

__device__ __forceinline__ float sigmoidf_(float x) { return 1.f / (1.f + __expf(-x)); }

__device__ __forceinline__ u16 f2bf(float x) {
  unsigned u = __float_as_uint(x);
  unsigned r = (u + 0x7fffu + ((u >> 16) & 1u)) >> 16;
  return (u16)r;
}
__device__ __forceinline__ float bf2f(u16 u) {
  return __uint_as_float(((unsigned)u) << 16);
}

// Async global->LDS, 16B per lane. LDS dest is wave-uniform base + lane*16.
// LDS layout must be linear in lane order (no padding) -- m173.
__device__ __forceinline__ void gload16(const u16* g, u16* l) {
  __builtin_amdgcn_global_load_lds(
      (const __attribute__((address_space(1))) unsigned int*)g,
      (__attribute__((address_space(3))) unsigned int*)l, 16, 0, 0);
}

// ---------------------------------------------------------------------------
// LayerNorm of s (C_S = 384), one wave per row -> bf16 out.
// ---------------------------------------------------------------------------
__global__ __launch_bounds__(256) void ln_s_kernel(const float* __restrict__ s,
                                                   u16* __restrict__ s_ln_bf) {
  int row  = blockIdx.x * 4 + (threadIdx.x >> 6);
  int lane = threadIdx.x & 63;
  const float* sr = s + (size_t)row * CS;
  float x[6];
  float sum = 0.f, sq = 0.f;
#pragma unroll
  for (int t = 0; t < 6; ++t) { x[t] = sr[lane + 64*t]; sum += x[t]; sq += x[t]*x[t]; }
#pragma unroll
  for (int off = 32; off; off >>= 1) { sum += __shfl_down(sum, off); sq += __shfl_down(sq, off); }
  sum = __shfl(sum, 0); sq = __shfl(sq, 0);
  float mean = sum * (1.f/CS);
  float var  = sq  * (1.f/CS) - mean*mean;
  float rstd = rsqrtf(var + 1e-5f);
  u16* orow = s_ln_bf + (size_t)row * CS;
#pragma unroll
  for (int t = 0; t < 6; ++t) orow[lane + 64*t] = f2bf((x[t]-mean)*rstd);
}

// ---------------------------------------------------------------------------
// LN(a) + adaLN modulation (iter 0 only: a == q input).
// ---------------------------------------------------------------------------
__global__ __launch_bounds__(256) void modln_kernel(const float* __restrict__ a,
                                                    const u16* __restrict__ sp0,
                                                    const u16* __restrict__ sp1,
                                                    const u16* __restrict__ sp3,
                                                    const u16* __restrict__ sp4,
                                                    u16* __restrict__ amod,
                                                    u16* __restrict__ tmod) {
  int row  = blockIdx.x * 4 + (threadIdx.x >> 6);
  int lane = threadIdx.x & 63;
  const float* ar = a + (size_t)row * CA;
  float x0 = ar[lane], x1 = ar[lane + 64];
  float sum = x0 + x1, sq = x0*x0 + x1*x1;
#pragma unroll
  for (int off = 32; off; off >>= 1) { sum += __shfl_down(sum, off); sq += __shfl_down(sq, off); }
  sum = __shfl(sum, 0); sq = __shfl(sq, 0);
  float mean = sum * (1.f/CA);
  float var  = sq  * (1.f/CA) - mean*mean;
  float rstd = rsqrtf(var + 1e-5f);
  float n0 = (x0-mean)*rstd, n1 = (x1-mean)*rstd;
  size_t i0 = (size_t)row * CA + lane;
  amod[i0]      = f2bf(bf2f(sp0[i0])     *n0 + bf2f(sp1[i0]));
  amod[i0 + 64] = f2bf(bf2f(sp0[i0 + 64])*n1 + bf2f(sp1[i0 + 64]));
  tmod[i0]      = f2bf(bf2f(sp3[i0])     *n0 + bf2f(sp4[i0]));
  tmod[i0 + 64] = f2bf(bf2f(sp3[i0 + 64])*n1 + bf2f(sp4[i0 + 64]));
}

// ---------------------------------------------------------------------------
// Weight transpose+convert: src fp32 K x N (row-major)  ->  dst bf16 N x K.
// ---------------------------------------------------------------------------
struct TJob { const float* src; u16* dst; int K; int N; };
struct TJobs { TJob j[42]; };

__global__ __launch_bounds__(256) void transpose_bf16(TJobs jobs) {
  TJob jb = jobs.j[blockIdx.z];
  int tk = blockIdx.x * 32, tn = blockIdx.y * 32;
  if (tk >= jb.K || tn >= jb.N) return;
  __shared__ float tile[32][33];
  int tx = threadIdx.x & 31;
  int ty = threadIdx.x >> 5;
#pragma unroll
  for (int r = ty; r < 32; r += 8) tile[r][tx] = jb.src[(size_t)(tk + r) * jb.N + tn + tx];
  __syncthreads();
#pragma unroll
  for (int r = ty; r < 32; r += 8)
    jb.dst[(size_t)(tn + r) * jb.K + tk + tx] = f2bf(tile[tx][r]);
}

// ---------------------------------------------------------------------------
// bf16 MFMA GEMM.  128x128 block tile, BK=32, 4 waves (2x2 of 64x64).
// Counted-vmcnt pipeline (unchanged from round 6; equal-best measured).
// modes: 0 = (+bias)->bf16, 1 = sigmoid(+bias)->bf16,
// 4 (DUAL) = silu(A@B)*(A@B2) -> bf16, 5 = transposed bf16 write (V).
// ---------------------------------------------------------------------------
struct GemmJob {
  const u16* A;
  const u16* Bt;
  const u16* Bt2;
  const float* bias;
  u16* outbf;
  int K;
  int ostride;
  int mode;
  int pad;
};
struct GemmJobs { GemmJob j[18]; };

template <bool DUAL>
__global__ __launch_bounds__(256) void gemm_mfma(GemmJobs jobs) {
  GemmJob jb = jobs.j[blockIdx.z];
  const int bm = blockIdx.y * 128, bn = blockIdx.x * 128;
  const int K = jb.K;

  __shared__ u16 As[3][4096];
  __shared__ u16 Bs[3][4096];
  __shared__ u16 Bs2[DUAL ? 3 : 1][DUAL ? 4096 : 8];

  const int tid  = threadIdx.x;
  const int lane = tid & 63;
  const int wave = tid >> 6;
  const int wr = wave >> 1, wc = wave & 1;
  const int l15 = lane & 15, quad = lane >> 4;

  floatx4 acc[4][4] = {};
  floatx4 acc2[DUAL ? 4 : 1][DUAL ? 4 : 1] = {};

  const u16* Ab0  = jb.A  + ((size_t)bm + lane) * K + wave * 8;
  const u16* Ab1  = jb.A  + ((size_t)bm + 64 + lane) * K + wave * 8;
  const u16* Bb0  = jb.Bt + ((size_t)bn + lane) * K + wave * 8;
  const u16* Bb1  = jb.Bt + ((size_t)bn + 64 + lane) * K + wave * 8;
  const u16* B2b0 = DUAL ? (jb.Bt2 + ((size_t)bn + lane) * K + wave * 8) : nullptr;
  const u16* B2b1 = DUAL ? (jb.Bt2 + ((size_t)bn + 64 + lane) * K + wave * 8) : nullptr;

  auto stage = [&](int k0, int pb) {
    gload16(Ab0 + k0, As[pb] + wave * 1024);
    gload16(Ab1 + k0, As[pb] + wave * 1024 + 512);
    gload16(Bb0 + k0, Bs[pb] + wave * 1024);
    gload16(Bb1 + k0, Bs[pb] + wave * 1024 + 512);
    if constexpr (DUAL) {
      gload16(B2b0 + k0, Bs2[pb] + wave * 1024);
      gload16(B2b1 + k0, Bs2[pb] + wave * 1024 + 512);
    }
  };

  auto compute = [&](int pb) {
    short8 a_frag[4], b_frag[4];
#pragma unroll
    for (int mt = 0; mt < 4; ++mt)
      a_frag[mt] = *(const short8*)(As[pb] + quad * 1024 + (wr * 64 + mt * 16 + l15) * 8);
#pragma unroll
    for (int nt = 0; nt < 4; ++nt)
      b_frag[nt] = *(const short8*)(Bs[pb] + quad * 1024 + (wc * 64 + nt * 16 + l15) * 8);
#pragma unroll
    for (int mt = 0; mt < 4; ++mt)
#pragma unroll
      for (int nt = 0; nt < 4; ++nt)
        acc[mt][nt] = __builtin_amdgcn_mfma_f32_16x16x32_bf16(a_frag[mt], b_frag[nt], acc[mt][nt], 0, 0, 0);
    if constexpr (DUAL) {
      short8 b2_frag[4];
#pragma unroll
      for (int nt = 0; nt < 4; ++nt)
        b2_frag[nt] = *(const short8*)(Bs2[pb] + quad * 1024 + (wc * 64 + nt * 16 + l15) * 8);
#pragma unroll
      for (int mt = 0; mt < 4; ++mt)
#pragma unroll
        for (int nt = 0; nt < 4; ++nt)
          acc2[mt][nt] = __builtin_amdgcn_mfma_f32_16x16x32_bf16(a_frag[mt], b2_frag[nt], acc2[mt][nt], 0, 0, 0);
    }
  };

  stage(0, 0);
  stage(32, 1);
  int cur = 0;
  for (int k0 = 0; k0 + 64 < K; k0 += 32) {
    stage(k0 + 64, (cur + 2) % 3);
    if constexpr (DUAL) asm volatile("s_waitcnt vmcnt(12)" ::: "memory");
    else                asm volatile("s_waitcnt vmcnt(8)"  ::: "memory");
    __builtin_amdgcn_s_barrier();
    compute(cur);
    __builtin_amdgcn_s_barrier();
    cur = (cur + 1) % 3;
  }
  if constexpr (DUAL) asm volatile("s_waitcnt vmcnt(6)" ::: "memory");
  else                asm volatile("s_waitcnt vmcnt(4)" ::: "memory");
  __builtin_amdgcn_s_barrier();
  compute(cur);
  __builtin_amdgcn_s_barrier();
  cur = (cur + 1) % 3;
  asm volatile("s_waitcnt vmcnt(0)" ::: "memory");
  __builtin_amdgcn_s_barrier();
  compute(cur);

  // Epilogue.  C/D layout: col = lane&15, row = quad*4 + reg.
#pragma unroll
  for (int mt = 0; mt < 4; ++mt) {
#pragma unroll
    for (int nt = 0; nt < 4; ++nt) {
      int n = bn + wc * 64 + nt * 16 + l15;
      int mbase = bm + wr * 64 + mt * 16 + quad * 4;
      floatx4 v = acc[mt][nt];
      if constexpr (DUAL) {
        floatx4 v2 = acc2[mt][nt];
#pragma unroll
        for (int r = 0; r < 4; ++r) {
          size_t idx = (size_t)(mbase + r) * jb.ostride + n;
          float x1 = v[r];
          jb.outbf[idx] = f2bf(x1 * sigmoidf_(x1) * v2[r]);
        }
      } else if (jb.mode == 5) {
        int bidx = mbase >> 13;          // m / NN
        int tok  = mbase & (NN - 1);
        ushort4 o;
        o.x = f2bf(v[0]); o.y = f2bf(v[1]); o.z = f2bf(v[2]); o.w = f2bf(v[3]);
        *(ushort4*)(jb.outbf + (size_t)(bidx * CA + n) * NN + tok) = o;
      } else {
        float bias = jb.bias ? jb.bias[n] : 0.f;
#pragma unroll
        for (int r = 0; r < 4; ++r) {
          size_t idx = (size_t)(mbase + r) * jb.ostride + n;
          float x = v[r] + bias;
          jb.outbf[idx] = f2bf(jb.mode == 1 ? sigmoidf_(x) : x);
        }
      }
    }
  }
}

// ---------------------------------------------------------------------------
// Combo output kernel, fused with next-iteration modln.
// aval = (O @ woT)*g1 + (HID @ twoT)*g2   (this is the new `a`, fp32 in regs)
// MODE 0: row-LN(aval) in-epilogue (2-wave LDS combine), write
//         amod = sig_sp0*n + sp1, tmod = sig_sp3*n + sp4 (bf16) for iter i+1.
// MODE 1: write aval as fp32 (final output).
// ---------------------------------------------------------------------------
template <int MODE>
__global__ __launch_bounds__(256) void combo_kernel(const u16* __restrict__ O,
                                                    const u16* __restrict__ HID,
                                                    const u16* __restrict__ woT,
                                                    const u16* __restrict__ twoT,
                                                    const u16* __restrict__ g1,
                                                    const u16* __restrict__ g2,
                                                    const u16* __restrict__ sp0,
                                                    const u16* __restrict__ sp1,
                                                    const u16* __restrict__ sp3,
                                                    const u16* __restrict__ sp4,
                                                    u16* __restrict__ amod,
                                                    u16* __restrict__ tmod,
                                                    float* __restrict__ outp) {
  const int bm = blockIdx.y * 64;
  __shared__ u16 As1[2][2048];
  __shared__ u16 Bs1[2][4096];
  __shared__ u16 As2[2][2048];
  __shared__ u16 Bs2h[2][4096];
  __shared__ float hsum[2][64];
  __shared__ float hsq[2][64];
  const int tid  = threadIdx.x;
  const int lane = tid & 63;
  const int wave = tid >> 6;
  const int wr = wave >> 1, wc = wave & 1;
  const int l15 = lane & 15, quad = lane >> 4;

  floatx4 acc1[2][4] = {};
  floatx4 acc2[2][4] = {};

  const u16* A1  = O    + ((size_t)bm + lane) * CA + wave * 8;
  const u16* B10 = woT  + ((size_t)lane) * CA + wave * 8;
  const u16* B11 = woT  + ((size_t)64 + lane) * CA + wave * 8;
  const u16* A2  = HID  + ((size_t)bm + lane) * HIDN + wave * 8;
  const u16* B20 = twoT + ((size_t)lane) * HIDN + wave * 8;
  const u16* B21 = twoT + ((size_t)64 + lane) * HIDN + wave * 8;

  auto stage1 = [&](int k0, int pb) {
    gload16(A1  + k0, As1[pb] + wave * 512);
    gload16(B10 + k0, Bs1[pb] + wave * 1024);
    gload16(B11 + k0, Bs1[pb] + wave * 1024 + 512);
  };
  auto stage2 = [&](int k0, int pb) {
    gload16(A2  + k0, As2[pb] + wave * 512);
    gload16(B20 + k0, Bs2h[pb] + wave * 1024);
    gload16(B21 + k0, Bs2h[pb] + wave * 1024 + 512);
  };

  stage1(0, 0);
  stage2(0, 0);
  __syncthreads();
  int cur = 0;
  for (int t = 0; t < 8; ++t) {
    if (t + 1 < 4) stage1((t + 1) * 32, cur ^ 1);
    if (t + 1 < 8) stage2((t + 1) * 32, cur ^ 1);

    if (t < 4) {
      short8 a_frag[2], b_frag[4];
#pragma unroll
      for (int mt = 0; mt < 2; ++mt)
        a_frag[mt] = *(const short8*)(As1[cur] + quad * 512 + (wr * 32 + mt * 16 + l15) * 8);
#pragma unroll
      for (int nt = 0; nt < 4; ++nt)
        b_frag[nt] = *(const short8*)(Bs1[cur] + quad * 1024 + (wc * 64 + nt * 16 + l15) * 8);
#pragma unroll
      for (int mt = 0; mt < 2; ++mt)
#pragma unroll
        for (int nt = 0; nt < 4; ++nt)
          acc1[mt][nt] = __builtin_amdgcn_mfma_f32_16x16x32_bf16(a_frag[mt], b_frag[nt], acc1[mt][nt], 0, 0, 0);
    }
    {
      short8 a_frag[2], b_frag[4];
#pragma unroll
      for (int mt = 0; mt < 2; ++mt)
        a_frag[mt] = *(const short8*)(As2[cur] + quad * 512 + (wr * 32 + mt * 16 + l15) * 8);
#pragma unroll
      for (int nt = 0; nt < 4; ++nt)
        b_frag[nt] = *(const short8*)(Bs2h[cur] + quad * 1024 + (wc * 64 + nt * 16 + l15) * 8);
#pragma unroll
      for (int mt = 0; mt < 2; ++mt)
#pragma unroll
        for (int nt = 0; nt < 4; ++nt)
          acc2[mt][nt] = __builtin_amdgcn_mfma_f32_16x16x32_bf16(a_frag[mt], b_frag[nt], acc2[mt][nt], 0, 0, 0);
    }
    __syncthreads();
    cur ^= 1;
  }

  if constexpr (MODE == 1) {
#pragma unroll
    for (int mt = 0; mt < 2; ++mt) {
#pragma unroll
      for (int nt = 0; nt < 4; ++nt) {
        int n = wc * 64 + nt * 16 + l15;
        int mbase = bm + wr * 32 + mt * 16 + quad * 4;
#pragma unroll
        for (int r = 0; r < 4; ++r) {
          size_t idx = (size_t)(mbase + r) * CA + n;
          outp[idx] = acc1[mt][nt][r] * bf2f(g1[idx]) + acc2[mt][nt][r] * bf2f(g2[idx]);
        }
      }
    }
  } else {
    float aval[2][4][4];
#pragma unroll
    for (int mt = 0; mt < 2; ++mt)
#pragma unroll
      for (int nt = 0; nt < 4; ++nt) {
        int n = wc * 64 + nt * 16 + l15;
        int mbase = bm + wr * 32 + mt * 16 + quad * 4;
#pragma unroll
        for (int r = 0; r < 4; ++r) {
          size_t idx = (size_t)(mbase + r) * CA + n;
          aval[mt][nt][r] = acc1[mt][nt][r] * bf2f(g1[idx]) + acc2[mt][nt][r] * bf2f(g2[idx]);
        }
      }
    // row stats: each wave holds a 64-col half of rows wr*32..wr*32+31
#pragma unroll
    for (int mt = 0; mt < 2; ++mt)
#pragma unroll
      for (int r = 0; r < 4; ++r) {
        float s = 0.f, sq = 0.f;
#pragma unroll
        for (int nt = 0; nt < 4; ++nt) { float v = aval[mt][nt][r]; s += v; sq += v * v; }
        s  += __shfl_xor(s, 1);  s  += __shfl_xor(s, 2);  s  += __shfl_xor(s, 4);  s  += __shfl_xor(s, 8);
        sq += __shfl_xor(sq, 1); sq += __shfl_xor(sq, 2); sq += __shfl_xor(sq, 4); sq += __shfl_xor(sq, 8);
        if (l15 == 0) {
          int row = wr * 32 + mt * 16 + quad * 4 + r;
          hsum[wc][row] = s;
          hsq[wc][row]  = sq;
        }
      }
    __syncthreads();
#pragma unroll
    for (int mt = 0; mt < 2; ++mt)
#pragma unroll
      for (int r = 0; r < 4; ++r) {
        int row = wr * 32 + mt * 16 + quad * 4 + r;
        float tot  = hsum[0][row] + hsum[1][row];
        float totq = hsq[0][row]  + hsq[1][row];
        float mean = tot * (1.f / CA);
        float var  = totq * (1.f / CA) - mean * mean;
        float rstd = rsqrtf(var + 1e-5f);
        int mrow = bm + row;
#pragma unroll
        for (int nt = 0; nt < 4; ++nt) {
          int n = wc * 64 + nt * 16 + l15;
          size_t idx = (size_t)mrow * CA + n;
          float nv = (aval[mt][nt][r] - mean) * rstd;
          amod[idx] = f2bf(bf2f(sp0[idx]) * nv + bf2f(sp1[idx]));
          tmod[idx] = f2bf(bf2f(sp3[idx]) * nv + bf2f(sp4[idx]));
        }
      }
  }
}

// ---------------------------------------------------------------------------
// Pair bias for ALL 3 blocks in one pass over p; no LDS transpose, direct
// ushort4 stores.  Grid (4 k-chunks, W, B).
// Output layout: biasT[i][b][w][h][k][q] (bf16).
// ---------------------------------------------------------------------------
__global__ __launch_bounds__(256) void bias3_kernel(const float* __restrict__ p,
                                                    const float* __restrict__ lnz_w,
                                                    const float* __restrict__ lnz_b,
                                                    const float* __restrict__ wb,
                                                    u16* __restrict__ biasT) {
  const int kc = blockIdx.x, w = blockIdx.y, b = blockIdx.z;
  __shared__ float effW[12][16];
  __shared__ float effb[12];
  const int t = threadIdx.x;
  if (t < 192) {
    int i = t >> 6, rem = t & 63, z = rem >> 2, hh = rem & 3;
    effW[i*4 + hh][z] = lnz_w[i*CZ + z] * wb[(i*CZ + z)*HH + hh];
  }
  if (t < 12) {
    int i = t >> 2, hh = t & 3;
    float acc = 0.f;
    for (int z = 0; z < 16; ++z) acc += lnz_b[i*CZ + z] * wb[(i*CZ + z)*HH + hh];
    effb[t] = acc;
  }
  __syncthreads();

  const int kk = t & 31, qg = (t >> 5) * 4;
  const int k = kc * 32 + kk;
  u16 out4[12][4];
#pragma unroll
  for (int r = 0; r < 4; ++r) {
    int qq = qg + r;
    const float4* pr = (const float4*)(p + (size_t)(((b * WW + w) * NQW + qq) * NKW + k) * 16);
    float4 p0 = pr[0], p1 = pr[1], p2 = pr[2], p3 = pr[3];
    float x[16] = {p0.x,p0.y,p0.z,p0.w, p1.x,p1.y,p1.z,p1.w,
                   p2.x,p2.y,p2.z,p2.w, p3.x,p3.y,p3.z,p3.w};
    float sum = 0.f, sq = 0.f;
#pragma unroll
    for (int z = 0; z < 16; ++z) { sum += x[z]; sq += x[z]*x[z]; }
    float mean = sum * (1.f/16.f);
    float var  = sq  * (1.f/16.f) - mean*mean;
    float rstd = rsqrtf(var + 1e-5f);
#pragma unroll
    for (int ih = 0; ih < 12; ++ih) {
      float acc = effb[ih];
#pragma unroll
      for (int z = 0; z < 16; ++z) acc += (x[z]-mean)*rstd * effW[ih][z];
      out4[ih][r] = f2bf(acc);
    }
  }
#pragma unroll
  for (int ih = 0; ih < 12; ++ih) {
    int i = ih >> 2, hh = ih & 3;
    u16* dst = biasT + ((((size_t)i * BB + b) * WW + w) * HH + hh) * 4096 + (size_t)k * 32 + qg;
    ushort4 uv; uv.x = out4[ih][0]; uv.y = out4[ih][1]; uv.z = out4[ih][2]; uv.w = out4[ih][3];
    *(ushort4*)dst = uv;
  }
}

// ---------------------------------------------------------------------------
// MFMA windowed attention, QUERY-SPLIT: one WAVE per (w, h, b, half).
// Each wave handles 16 queries (half of a window) against the full 128-token
// K window.  Softmax is per-query-row -> halves are fully independent.
// Grid 4096 blocks (16 waves/CU, 2x round-7 parallelism).  XCD chunk swizzle
// with half-fastest decode (both halves of a window share an XCD/L2).
// ---------------------------------------------------------------------------
__global__ __launch_bounds__(64) void attn_mfma(const u16* __restrict__ Qb,
                                                const u16* __restrict__ Kb,
                                                const u16* __restrict__ Vtb,
                                                const u16* __restrict__ Gb,
                                                const u16* __restrict__ biasT,
                                                u16* __restrict__ Ob) {
  const int lin = blockIdx.x;                      // 4096 blocks
  const int swz = (lin & 7) * 512 + (lin >> 3);    // XCD chunk swizzle
  const int b    = swz >> 11;                      // swz = b*2048 + h*512 + w*2 + half
  const int h    = (swz >> 9) & 3;
  const int w    = (swz >> 1) & 255;
  const int half = swz & 1;
  __shared__ u16 Pt[128 * 20];                     // [token][query(16)+pad]
  __shared__ float inv_s[16];
  const int lane = threadIdx.x;
  const int l15 = lane & 15, quad = lane >> 4;
  const int tok0 = w * NQW - 48;

  // Q fragment: 16 queries of this half
  const int qq = w * NQW + half * 16 + l15;
  short8 qf = *(const short8*)(Qb + (size_t)(b * NN + qq) * CA + h * DD + quad * 8);

  floatx4 lg[8] = {};
#pragma unroll
  for (int nt = 0; nt < 8; ++nt) {
    int tk = tok0 + nt * 16 + l15;
    int tc = min(max(tk, 0), NN - 1);
    short8 kf = *(const short8*)(Kb + (size_t)(b * NN + tc) * CA + h * DD + quad * 8);
    lg[nt] = __builtin_amdgcn_mfma_f32_16x16x32_bf16(qf, kf, lg[nt], 0, 0, 0);
  }

  const float scale = 0.17677669529663687f;   // 1/sqrt(32)
  const u16* bb = biasT + ((((size_t)b * WW + w) * HH + h) << 12);
  float mrow[4] = {-3.0e38f, -3.0e38f, -3.0e38f, -3.0e38f};
#pragma unroll
  for (int nt = 0; nt < 8; ++nt) {
    int tk = tok0 + nt * 16 + l15;
    bool valid = (tk >= 0) && (tk < NN);
    ushort4 bv = *(const ushort4*)(bb + (nt * 16 + l15) * 32 + half * 16 + quad * 4);
    float bvf[4] = {bf2f(bv.x), bf2f(bv.y), bf2f(bv.z), bf2f(bv.w)};
#pragma unroll
    for (int r = 0; r < 4; ++r) {
      float l = valid ? (lg[nt][r] * scale + bvf[r]) : -1e9f;
      lg[nt][r] = l;
      mrow[r] = fmaxf(mrow[r], l);
    }
  }
#pragma unroll
  for (int r = 0; r < 4; ++r) {
    float m = mrow[r];
    m = fmaxf(m, __shfl_xor(m, 1));
    m = fmaxf(m, __shfl_xor(m, 2));
    m = fmaxf(m, __shfl_xor(m, 4));
    m = fmaxf(m, __shfl_xor(m, 8));
    mrow[r] = m;
  }

  float srow[4] = {};
#pragma unroll
  for (int nt = 0; nt < 8; ++nt) {
    u16 pv[4];
#pragma unroll
    for (int r = 0; r < 4; ++r) {
      float e = __expf(lg[nt][r] - mrow[r]);
      srow[r] += e;
      pv[r] = f2bf(e);
    }
    ushort4 uv; uv.x = pv[0]; uv.y = pv[1]; uv.z = pv[2]; uv.w = pv[3];
    *(ushort4*)(Pt + (nt * 16 + l15) * 20 + quad * 4) = uv;
  }
#pragma unroll
  for (int r = 0; r < 4; ++r) {
    float ssum = srow[r];
    ssum += __shfl_xor(ssum, 1);
    ssum += __shfl_xor(ssum, 2);
    ssum += __shfl_xor(ssum, 4);
    ssum += __shfl_xor(ssum, 8);
    if (l15 == 0) inv_s[quad * 4 + r] = 1.f / ssum;
  }
  __syncthreads();

  floatx4 oacc[2] = {};
#pragma unroll
  for (int ks = 0; ks < 4; ++ks) {
    short8 pf;
#pragma unroll
    for (int j = 0; j < 8; ++j)
      pf[j] = (short)Pt[(ks * 32 + quad * 8 + j) * 20 + l15];
    int tb = tok0 + ks * 32 + quad * 8;
    tb = min(max(tb, 0), NN - 8);
#pragma unroll
    for (int mtd = 0; mtd < 2; ++mtd) {
      short8 vf = *(const short8*)(Vtb + (size_t)(b * CA + h * DD + mtd * 16 + l15) * NN + tb);
      oacc[mtd] = __builtin_amdgcn_mfma_f32_16x16x32_bf16(vf, pf, oacc[mtd], 0, 0, 0);
    }
  }

#pragma unroll
  for (int mtd = 0; mtd < 2; ++mtd) {
    float inv = inv_s[l15];
    int tok = w * NQW + half * 16 + l15;
    size_t base = (size_t)(b * NN + tok) * CA + h * DD + mtd * 16 + quad * 4;
    ushort4 gv = *(const ushort4*)(Gb + base);
    floatx4 v = oacc[mtd];
    ushort4 o;
    o.x = f2bf(bf2f(gv.x) * v[0] * inv);
    o.y = f2bf(bf2f(gv.y) * v[1] * inv);
    o.z = f2bf(bf2f(gv.z) * v[2] * inv);
    o.w = f2bf(bf2f(gv.w) * v[3] * inv);
    *(ushort4*)(Ob + base) = o;
  }
}

// ---------------------------------------------------------------------------
// Host-side orchestration.
// ---------------------------------------------------------------------------
extern "C" void kernel_launch(void* const* d_in, const int* in_sizes, int n_in,
                              void* d_out, int out_size, void* d_ws, size_t ws_size,
                              hipStream_t stream) {
  const float* q             = (const float*)d_in[0];
  const float* s             = (const float*)d_in[1];
  const float* p             = (const float*)d_in[2];
  const float* adaln_scale_w = (const float*)d_in[3];
  const float* adaln_scale_b = (const float*)d_in[4];
  const float* adaln_shift_w = (const float*)d_in[5];
  const float* wq            = (const float*)d_in[6];
  const float* bq            = (const float*)d_in[7];
  const float* wk            = (const float*)d_in[8];
  const float* wv            = (const float*)d_in[9];
  const float* lnz_w         = (const float*)d_in[10];
  const float* lnz_b         = (const float*)d_in[11];
  const float* wb_pair       = (const float*)d_in[12];
  const float* wg            = (const float*)d_in[13];
  const float* wo            = (const float*)d_in[14];
  const float* sgate_w       = (const float*)d_in[15];
  const float* sgate_b       = (const float*)d_in[16];
  const float* t_scale_w     = (const float*)d_in[17];
  const float* t_scale_b     = (const float*)d_in[18];
  const float* t_shift_w     = (const float*)d_in[19];
  const float* t_wa          = (const float*)d_in[20];
  const float* t_wb          = (const float*)d_in[21];
  const float* t_wo          = (const float*)d_in[22];
  const float* t_sgate_w     = (const float*)d_in[23];
  const float* t_sgate_b     = (const float*)d_in[24];
  float* out = (float*)d_out;

  const size_t MC = (size_t)MR * CA; // 2097152
  float* fws   = (float*)d_ws;
  float* abuf0 = fws;                          // (unused; layout kept)
  float* abuf1 = abuf0 + MC;
  u16* uws     = (u16*)(abuf1 + MC);
  u16* s_ln_bf = uws;                          // MR*CS
  u16* SP      = s_ln_bf + (size_t)MR * CS;    // 18*MC
  u16* amod    = SP + 18*MC;
  u16* tmod    = amod + MC;
  u16* Qb      = tmod + MC;
  u16* Kb      = Qb + MC;
  u16* Vtb     = Kb + MC;                      // [b][128][NN]
  u16* Gb      = Vtb + MC;
  u16* Ob      = Gb + MC;
  u16* HIDb    = Ob + MC;                      // MR*HIDN = 2*MC
  u16* biasT   = HIDb + 2*MC;                  // 3*BB*WW*HH*4096
  u16* wbuf    = biasT + (size_t)3*BB*WW*HH*NQW*NKW;

  const size_t WBLK = 6*(size_t)CA*CS + 5*(size_t)CA*CA + 3*(size_t)CA*HIDN;
  const size_t o_ascale = 0;
  const size_t o_ashift = o_ascale + (size_t)CA*CS;
  const size_t o_sgate  = o_ashift + (size_t)CA*CS;
  const size_t o_tscale = o_sgate  + (size_t)CA*CS;
  const size_t o_tshift = o_tscale + (size_t)CA*CS;
  const size_t o_tsgate = o_tshift + (size_t)CA*CS;
  const size_t o_wq     = o_tsgate + (size_t)CA*CS;
  const size_t o_wk     = o_wq + (size_t)CA*CA;
  const size_t o_wv     = o_wk + (size_t)CA*CA;
  const size_t o_wg     = o_wv + (size_t)CA*CA;
  const size_t o_wo     = o_wg + (size_t)CA*CA;
  const size_t o_twa    = o_wo + (size_t)CA*CA;
  const size_t o_twb    = o_twa + (size_t)HIDN*CA;
  const size_t o_two    = o_twb + (size_t)HIDN*CA;

  // ---- one-time work ----
  ln_s_kernel<<<MR/4, 256, 0, stream>>>(s, s_ln_bf);

  TJobs tj;
  for (int i = 0; i < NBLK; ++i) {
    u16* wb0 = wbuf + (size_t)i * WBLK;
    int b14 = i * 14;
    tj.j[b14+0]  = TJob{adaln_scale_w + (size_t)i*CS*CA, wb0 + o_ascale, CS, CA};
    tj.j[b14+1]  = TJob{adaln_shift_w + (size_t)i*CS*CA, wb0 + o_ashift, CS, CA};
    tj.j[b14+2]  = TJob{sgate_w       + (size_t)i*CS*CA, wb0 + o_sgate,  CS, CA};
    tj.j[b14+3]  = TJob{t_scale_w     + (size_t)i*CS*CA, wb0 + o_tscale, CS, CA};
    tj.j[b14+4]  = TJob{t_shift_w     + (size_t)i*CS*CA, wb0 + o_tshift, CS, CA};
    tj.j[b14+5]  = TJob{t_sgate_w     + (size_t)i*CS*CA, wb0 + o_tsgate, CS, CA};
    tj.j[b14+6]  = TJob{wq   + (size_t)i*CA*CA,   wb0 + o_wq,  CA, CA};
    tj.j[b14+7]  = TJob{wk   + (size_t)i*CA*CA,   wb0 + o_wk,  CA, CA};
    tj.j[b14+8]  = TJob{wv   + (size_t)i*CA*CA,   wb0 + o_wv,  CA, CA};
    tj.j[b14+9]  = TJob{wg   + (size_t)i*CA*CA,   wb0 + o_wg,  CA, CA};
    tj.j[b14+10] = TJob{wo   + (size_t)i*CA*CA,   wb0 + o_wo,  CA, CA};
    tj.j[b14+11] = TJob{t_wa + (size_t)i*CA*HIDN, wb0 + o_twa, CA, HIDN};
    tj.j[b14+12] = TJob{t_wb + (size_t)i*CA*HIDN, wb0 + o_twb, CA, HIDN};
    tj.j[b14+13] = TJob{t_wo + (size_t)i*HIDN*CA, wb0 + o_two, HIDN, CA};
  }
  transpose_bf16<<<dim3(12, 8, 42), 256, 0, stream>>>(tj);

  bias3_kernel<<<dim3(4, WW, BB), 256, 0, stream>>>(p, lnz_w, lnz_b, wb_pair, biasT);

  // ALL 18 s_ln projections (iteration-invariant) in one launch
  {
    GemmJobs js = {};
    for (int i = 0; i < NBLK; ++i) {
      u16* wb0 = wbuf + (size_t)i * WBLK;
      js.j[i*6+0] = GemmJob{s_ln_bf, wb0 + o_ascale, nullptr, adaln_scale_b + i*CA, SP + (i*6+0)*MC, CS, CA, 1, 0};
      js.j[i*6+1] = GemmJob{s_ln_bf, wb0 + o_ashift, nullptr, nullptr,              SP + (i*6+1)*MC, CS, CA, 0, 0};
      js.j[i*6+2] = GemmJob{s_ln_bf, wb0 + o_sgate,  nullptr, sgate_b   + i*CA,     SP + (i*6+2)*MC, CS, CA, 1, 0};
      js.j[i*6+3] = GemmJob{s_ln_bf, wb0 + o_tscale, nullptr, t_scale_b + i*CA,     SP + (i*6+3)*MC, CS, CA, 1, 0};
      js.j[i*6+4] = GemmJob{s_ln_bf, wb0 + o_tshift, nullptr, nullptr,              SP + (i*6+4)*MC, CS, CA, 0, 0};
      js.j[i*6+5] = GemmJob{s_ln_bf, wb0 + o_tsgate, nullptr, t_sgate_b + i*CA,     SP + (i*6+5)*MC, CS, CA, 1, 0};
    }
    gemm_mfma<false><<<dim3(1, MR/128, 18), 256, 0, stream>>>(js);
  }

  // iter 0 modulations come from q via standalone modln
  modln_kernel<<<MR/4, 256, 0, stream>>>(q, SP + 0*MC, SP + 1*MC,
                                         SP + 3*MC, SP + 4*MC, amod, tmod);

  for (int i = 0; i < NBLK; ++i) {
    u16* wb0 = wbuf + (size_t)i * WBLK;

    // Q, K, V(transposed), G projections -> bf16
    GemmJobs jq = {};
    jq.j[0] = GemmJob{amod, wb0 + o_wq, nullptr, bq + i*CA, Qb,  CA, CA, 0, 0};
    jq.j[1] = GemmJob{amod, wb0 + o_wk, nullptr, nullptr,   Kb,  CA, CA, 0, 0};
    jq.j[2] = GemmJob{amod, wb0 + o_wv, nullptr, nullptr,   Vtb, CA, CA, 5, 0};
    jq.j[3] = GemmJob{amod, wb0 + o_wg, nullptr, nullptr,   Gb,  CA, CA, 1, 0};
    gemm_mfma<false><<<dim3(1, MR/128, 4), 256, 0, stream>>>(jq);

    // hidden = silu(tmod @ t_wa) * (tmod @ t_wb)  -> bf16 (N=256)
    GemmJobs jh = {};
    jh.j[0] = GemmJob{tmod, wb0 + o_twa, wb0 + o_twb, nullptr, HIDb, CA, HIDN, 4, 0};
    gemm_mfma<true><<<dim3(2, MR/128, 1), 256, 0, stream>>>(jh);

    // windowed attention (MFMA, g-gated bf16 out), query-split 1-D grid
    attn_mfma<<<WW * HH * BB * 2, 64, 0, stream>>>(
        Qb, Kb, Vtb, Gb, biasT + (size_t)i * BB*WW*HH*4096, Ob);

    // a = (O @ wo)*sgate + (HID @ two)*tsgate, fused with next-iter modln
    if (i < NBLK - 1) {
      combo_kernel<0><<<dim3(1, MR/64), 256, 0, stream>>>(
          Ob, HIDb, wb0 + o_wo, wb0 + o_two,
          SP + (i*6+2)*MC, SP + (i*6+5)*MC,
          SP + ((i+1)*6+0)*MC, SP + ((i+1)*6+1)*MC,
          SP + ((i+1)*6+3)*MC, SP + ((i+1)*6+4)*MC,
          amod, tmod, nullptr);
    } else {
      combo_kernel<1><<<dim3(1, MR/64), 256, 0, stream>>>(
          Ob, HIDb, wb0 + o_wo, wb0 + o_two,
          SP + (i*6+2)*MC, SP + (i*6+5)*MC,
          nullptr, nullptr, nullptr, nullptr,
          nullptr, nullptr, out);
    }
  }
}

// Round 9
// 556.607 us; speedup vs baseline: 1.1459x; 1.0000x over previous
//
#include <hip/hip_runtime.h>
#include <hip/hip_bf16.h>
#include <cstddef>
#include <cstdint>

// Problem constants
#define BB   2
#define NN   8192
#define CA   128
#define CS   384
#define CZ   16
#define HH   4
#define DD   32
#define NQW  32      // NQ
#define NKW  128     // NK
#define NBLK 3
#define WW   256     // N / NQ
#define MR   (BB*NN) // 16384 rows
#define HIDN 256     // 2*CA

typedef unsigned short u16;
typedef __attribute__((ext_vector_type(8))) short short8;
typedef __attribute__((ext_vector_type(4))) float floatx4;

__device__ __forceinline__ float sigmoidf_(float x) { return 1.f / (1.f + __expf(-x)); }

__device__ __forceinline__ u16 f2bf(float x) {
  unsigned u = __float_as_uint(x);
  unsigned r = (u + 0x7fffu + ((u >> 16) & 1u)) >> 16;
  return (u16)r;
}
__device__ __forceinline__ float bf2f(u16 u) {
  return __uint_as_float(((unsigned)u) << 16);
}

// Async global->LDS, 16B per lane. LDS dest is wave-uniform base + lane*16.
// LDS layout must be linear in lane order (no padding) -- m173.
__device__ __forceinline__ void gload16(const u16* g, u16* l) {
  __builtin_amdgcn_global_load_lds(
      (const __attribute__((address_space(1))) unsigned int*)g,
      (__attribute__((address_space(3))) unsigned int*)l, 16, 0, 0);
}

// ---------------------------------------------------------------------------
// LayerNorm of s (C_S = 384), one wave per row -> bf16 out.
// ---------------------------------------------------------------------------
__global__ __launch_bounds__(256) void ln_s_kernel(const float* __restrict__ s,
                                                   u16* __restrict__ s_ln_bf) {
  int row  = blockIdx.x * 4 + (threadIdx.x >> 6);
  int lane = threadIdx.x & 63;
  const float* sr = s + (size_t)row * CS;
  float x[6];
  float sum = 0.f, sq = 0.f;
#pragma unroll
  for (int t = 0; t < 6; ++t) { x[t] = sr[lane + 64*t]; sum += x[t]; sq += x[t]*x[t]; }
#pragma unroll
  for (int off = 32; off; off >>= 1) { sum += __shfl_down(sum, off); sq += __shfl_down(sq, off); }
  sum = __shfl(sum, 0); sq = __shfl(sq, 0);
  float mean = sum * (1.f/CS);
  float var  = sq  * (1.f/CS) - mean*mean;
  float rstd = rsqrtf(var + 1e-5f);
  u16* orow = s_ln_bf + (size_t)row * CS;
#pragma unroll
  for (int t = 0; t < 6; ++t) orow[lane + 64*t] = f2bf((x[t]-mean)*rstd);
}

// ---------------------------------------------------------------------------
// LN(a) + adaLN modulation (iter 0 only: a == q input).
// ---------------------------------------------------------------------------
__global__ __launch_bounds__(256) void modln_kernel(const float* __restrict__ a,
                                                    const u16* __restrict__ sp0,
                                                    const u16* __restrict__ sp1,
                                                    const u16* __restrict__ sp3,
                                                    const u16* __restrict__ sp4,
                                                    u16* __restrict__ amod,
                                                    u16* __restrict__ tmod) {
  int row  = blockIdx.x * 4 + (threadIdx.x >> 6);
  int lane = threadIdx.x & 63;
  const float* ar = a + (size_t)row * CA;
  float x0 = ar[lane], x1 = ar[lane + 64];
  float sum = x0 + x1, sq = x0*x0 + x1*x1;
#pragma unroll
  for (int off = 32; off; off >>= 1) { sum += __shfl_down(sum, off); sq += __shfl_down(sq, off); }
  sum = __shfl(sum, 0); sq = __shfl(sq, 0);
  float mean = sum * (1.f/CA);
  float var  = sq  * (1.f/CA) - mean*mean;
  float rstd = rsqrtf(var + 1e-5f);
  float n0 = (x0-mean)*rstd, n1 = (x1-mean)*rstd;
  size_t i0 = (size_t)row * CA + lane;
  amod[i0]      = f2bf(bf2f(sp0[i0])     *n0 + bf2f(sp1[i0]));
  amod[i0 + 64] = f2bf(bf2f(sp0[i0 + 64])*n1 + bf2f(sp1[i0 + 64]));
  tmod[i0]      = f2bf(bf2f(sp3[i0])     *n0 + bf2f(sp4[i0]));
  tmod[i0 + 64] = f2bf(bf2f(sp3[i0 + 64])*n1 + bf2f(sp4[i0 + 64]));
}

// ---------------------------------------------------------------------------
// Weight transpose+convert: src fp32 K x N (row-major)  ->  dst bf16 N x K.
// ---------------------------------------------------------------------------
struct TJob { const float* src; u16* dst; int K; int N; };
struct TJobs { TJob j[42]; };

__global__ __launch_bounds__(256) void transpose_bf16(TJobs jobs) {
  TJob jb = jobs.j[blockIdx.z];
  int tk = blockIdx.x * 32, tn = blockIdx.y * 32;
  if (tk >= jb.K || tn >= jb.N) return;
  __shared__ float tile[32][33];
  int tx = threadIdx.x & 31;
  int ty = threadIdx.x >> 5;
#pragma unroll
  for (int r = ty; r < 32; r += 8) tile[r][tx] = jb.src[(size_t)(tk + r) * jb.N + tn + tx];
  __syncthreads();
#pragma unroll
  for (int r = ty; r < 32; r += 8)
    jb.dst[(size_t)(tn + r) * jb.K + tk + tx] = f2bf(tile[tx][r]);
}

// ---------------------------------------------------------------------------
// bf16 MFMA GEMM.  128x128 block tile, BK=32, 4 waves (2x2 of 64x64).
// Counted-vmcnt pipeline (round-6 schedule, equal-best measured).
// modes: 0 = (+bias)->bf16, 1 = sigmoid(+bias)->bf16,
// 4 (DUAL) = silu(A@B)*(A@B2) -> bf16,
// 5 = transposed bf16 write (V) -- NOW via LDS transpose + coalesced 256B
//     row segments (old path scattered 8B pieces at 16KB stride).
// ---------------------------------------------------------------------------
struct GemmJob {
  const u16* A;
  const u16* Bt;
  const u16* Bt2;
  const float* bias;
  u16* outbf;
  int K;
  int ostride;
  int mode;
  int pad;
};
struct GemmJobs { GemmJob j[18]; };

template <bool DUAL>
__global__ __launch_bounds__(256) void gemm_mfma(GemmJobs jobs) {
  GemmJob jb = jobs.j[blockIdx.z];
  const int bm = blockIdx.y * 128, bn = blockIdx.x * 128;
  const int K = jb.K;

  // As = smem[0..12288), Bs = smem[12288..24576).  Mode-5 epilogue reuses
  // smem as a 128x136 u16 transpose tile (17408 u16 <= 24576).
  __shared__ u16 smem[24576];
  __shared__ u16 Bs2s[DUAL ? 12288 : 8];
  u16* As = smem;
  u16* Bs = smem + 12288;

  const int tid  = threadIdx.x;
  const int lane = tid & 63;
  const int wave = tid >> 6;
  const int wr = wave >> 1, wc = wave & 1;
  const int l15 = lane & 15, quad = lane >> 4;

  floatx4 acc[4][4] = {};
  floatx4 acc2[DUAL ? 4 : 1][DUAL ? 4 : 1] = {};

  const u16* Ab0  = jb.A  + ((size_t)bm + lane) * K + wave * 8;
  const u16* Ab1  = jb.A  + ((size_t)bm + 64 + lane) * K + wave * 8;
  const u16* Bb0  = jb.Bt + ((size_t)bn + lane) * K + wave * 8;
  const u16* Bb1  = jb.Bt + ((size_t)bn + 64 + lane) * K + wave * 8;
  const u16* B2b0 = DUAL ? (jb.Bt2 + ((size_t)bn + lane) * K + wave * 8) : nullptr;
  const u16* B2b1 = DUAL ? (jb.Bt2 + ((size_t)bn + 64 + lane) * K + wave * 8) : nullptr;

  auto stage = [&](int k0, int pb) {
    gload16(Ab0 + k0, As + pb * 4096 + wave * 1024);
    gload16(Ab1 + k0, As + pb * 4096 + wave * 1024 + 512);
    gload16(Bb0 + k0, Bs + pb * 4096 + wave * 1024);
    gload16(Bb1 + k0, Bs + pb * 4096 + wave * 1024 + 512);
    if constexpr (DUAL) {
      gload16(B2b0 + k0, Bs2s + pb * 4096 + wave * 1024);
      gload16(B2b1 + k0, Bs2s + pb * 4096 + wave * 1024 + 512);
    }
  };

  auto compute = [&](int pb) {
    short8 a_frag[4], b_frag[4];
#pragma unroll
    for (int mt = 0; mt < 4; ++mt)
      a_frag[mt] = *(const short8*)(As + pb * 4096 + quad * 1024 + (wr * 64 + mt * 16 + l15) * 8);
#pragma unroll
    for (int nt = 0; nt < 4; ++nt)
      b_frag[nt] = *(const short8*)(Bs + pb * 4096 + quad * 1024 + (wc * 64 + nt * 16 + l15) * 8);
#pragma unroll
    for (int mt = 0; mt < 4; ++mt)
#pragma unroll
      for (int nt = 0; nt < 4; ++nt)
        acc[mt][nt] = __builtin_amdgcn_mfma_f32_16x16x32_bf16(a_frag[mt], b_frag[nt], acc[mt][nt], 0, 0, 0);
    if constexpr (DUAL) {
      short8 b2_frag[4];
#pragma unroll
      for (int nt = 0; nt < 4; ++nt)
        b2_frag[nt] = *(const short8*)(Bs2s + pb * 4096 + quad * 1024 + (wc * 64 + nt * 16 + l15) * 8);
#pragma unroll
      for (int mt = 0; mt < 4; ++mt)
#pragma unroll
        for (int nt = 0; nt < 4; ++nt)
          acc2[mt][nt] = __builtin_amdgcn_mfma_f32_16x16x32_bf16(a_frag[mt], b2_frag[nt], acc2[mt][nt], 0, 0, 0);
    }
  };

  stage(0, 0);
  stage(32, 1);
  int cur = 0;
  for (int k0 = 0; k0 + 64 < K; k0 += 32) {
    stage(k0 + 64, (cur + 2) % 3);
    if constexpr (DUAL) asm volatile("s_waitcnt vmcnt(12)" ::: "memory");
    else                asm volatile("s_waitcnt vmcnt(8)"  ::: "memory");
    __builtin_amdgcn_s_barrier();
    compute(cur);
    __builtin_amdgcn_s_barrier();
    cur = (cur + 1) % 3;
  }
  if constexpr (DUAL) asm volatile("s_waitcnt vmcnt(6)" ::: "memory");
  else                asm volatile("s_waitcnt vmcnt(4)" ::: "memory");
  __builtin_amdgcn_s_barrier();
  compute(cur);
  __builtin_amdgcn_s_barrier();
  cur = (cur + 1) % 3;
  asm volatile("s_waitcnt vmcnt(0)" ::: "memory");
  __builtin_amdgcn_s_barrier();
  compute(cur);

  // Epilogue.  C/D layout: col = lane&15, row = quad*4 + reg.
  if constexpr (DUAL) {
#pragma unroll
    for (int mt = 0; mt < 4; ++mt) {
#pragma unroll
      for (int nt = 0; nt < 4; ++nt) {
        int n = bn + wc * 64 + nt * 16 + l15;
        int mbase = bm + wr * 64 + mt * 16 + quad * 4;
        floatx4 v = acc[mt][nt];
        floatx4 v2 = acc2[mt][nt];
#pragma unroll
        for (int r = 0; r < 4; ++r) {
          size_t idx = (size_t)(mbase + r) * jb.ostride + n;
          float x1 = v[r];
          jb.outbf[idx] = f2bf(x1 * sigmoidf_(x1) * v2[r]);
        }
      }
    }
  } else if (jb.mode == 5) {
    // LDS transpose -> coalesced V^T write (256B contiguous row segments).
    __syncthreads();                       // all waves done reading As/Bs
    u16* tile = smem;                      // [n(dim)][m(token)], ld=136
#pragma unroll
    for (int mt = 0; mt < 4; ++mt) {
#pragma unroll
      for (int nt = 0; nt < 4; ++nt) {
        int nloc = wc * 64 + nt * 16 + l15;
        int mloc = wr * 64 + mt * 16 + quad * 4;
        floatx4 v = acc[mt][nt];
        ushort4 o;
        o.x = f2bf(v[0]); o.y = f2bf(v[1]); o.z = f2bf(v[2]); o.w = f2bf(v[3]);
        *(ushort4*)(tile + nloc * 136 + mloc) = o;
      }
    }
    __syncthreads();
    int bidx = bm >> 13;                   // batch index
    int tokb = bm & (NN - 1);              // token base
#pragma unroll
    for (int pass = 0; pass < 8; ++pass) {
      int d = pass * 16 + (tid >> 4);      // output dim
      int c = tid & 15;                    // 16B chunk along tokens
      *(uint4*)(jb.outbf + (size_t)(bidx * CA + bn + d) * NN + tokb + c * 8) =
          *(const uint4*)(tile + d * 136 + c * 8);
    }
  } else {
#pragma unroll
    for (int mt = 0; mt < 4; ++mt) {
#pragma unroll
      for (int nt = 0; nt < 4; ++nt) {
        int n = bn + wc * 64 + nt * 16 + l15;
        int mbase = bm + wr * 64 + mt * 16 + quad * 4;
        floatx4 v = acc[mt][nt];
        float bias = jb.bias ? jb.bias[n] : 0.f;
#pragma unroll
        for (int r = 0; r < 4; ++r) {
          size_t idx = (size_t)(mbase + r) * jb.ostride + n;
          float x = v[r] + bias;
          jb.outbf[idx] = f2bf(jb.mode == 1 ? sigmoidf_(x) : x);
        }
      }
    }
  }
}

// ---------------------------------------------------------------------------
// Combo output kernel, fused with next-iteration modln.
// aval = (O @ woT)*g1 + (HID @ twoT)*g2   (this is the new `a`, fp32 in regs)
// MODE 0: row-LN(aval) in-epilogue (2-wave LDS combine), write
//         amod = sig_sp0*n + sp1, tmod = sig_sp3*n + sp4 (bf16) for iter i+1.
// MODE 1: write aval as fp32 (final output).
// ---------------------------------------------------------------------------
template <int MODE>
__global__ __launch_bounds__(256) void combo_kernel(const u16* __restrict__ O,
                                                    const u16* __restrict__ HID,
                                                    const u16* __restrict__ woT,
                                                    const u16* __restrict__ twoT,
                                                    const u16* __restrict__ g1,
                                                    const u16* __restrict__ g2,
                                                    const u16* __restrict__ sp0,
                                                    const u16* __restrict__ sp1,
                                                    const u16* __restrict__ sp3,
                                                    const u16* __restrict__ sp4,
                                                    u16* __restrict__ amod,
                                                    u16* __restrict__ tmod,
                                                    float* __restrict__ outp) {
  const int bm = blockIdx.y * 64;
  __shared__ u16 As1[2][2048];
  __shared__ u16 Bs1[2][4096];
  __shared__ u16 As2[2][2048];
  __shared__ u16 Bs2h[2][4096];
  __shared__ float hsum[2][64];
  __shared__ float hsq[2][64];
  const int tid  = threadIdx.x;
  const int lane = tid & 63;
  const int wave = tid >> 6;
  const int wr = wave >> 1, wc = wave & 1;
  const int l15 = lane & 15, quad = lane >> 4;

  floatx4 acc1[2][4] = {};
  floatx4 acc2[2][4] = {};

  const u16* A1  = O    + ((size_t)bm + lane) * CA + wave * 8;
  const u16* B10 = woT  + ((size_t)lane) * CA + wave * 8;
  const u16* B11 = woT  + ((size_t)64 + lane) * CA + wave * 8;
  const u16* A2  = HID  + ((size_t)bm + lane) * HIDN + wave * 8;
  const u16* B20 = twoT + ((size_t)lane) * HIDN + wave * 8;
  const u16* B21 = twoT + ((size_t)64 + lane) * HIDN + wave * 8;

  auto stage1 = [&](int k0, int pb) {
    gload16(A1  + k0, As1[pb] + wave * 512);
    gload16(B10 + k0, Bs1[pb] + wave * 1024);
    gload16(B11 + k0, Bs1[pb] + wave * 1024 + 512);
  };
  auto stage2 = [&](int k0, int pb) {
    gload16(A2  + k0, As2[pb] + wave * 512);
    gload16(B20 + k0, Bs2h[pb] + wave * 1024);
    gload16(B21 + k0, Bs2h[pb] + wave * 1024 + 512);
  };

  stage1(0, 0);
  stage2(0, 0);
  __syncthreads();
  int cur = 0;
  for (int t = 0; t < 8; ++t) {
    if (t + 1 < 4) stage1((t + 1) * 32, cur ^ 1);
    if (t + 1 < 8) stage2((t + 1) * 32, cur ^ 1);

    if (t < 4) {
      short8 a_frag[2], b_frag[4];
#pragma unroll
      for (int mt = 0; mt < 2; ++mt)
        a_frag[mt] = *(const short8*)(As1[cur] + quad * 512 + (wr * 32 + mt * 16 + l15) * 8);
#pragma unroll
      for (int nt = 0; nt < 4; ++nt)
        b_frag[nt] = *(const short8*)(Bs1[cur] + quad * 1024 + (wc * 64 + nt * 16 + l15) * 8);
#pragma unroll
      for (int mt = 0; mt < 2; ++mt)
#pragma unroll
        for (int nt = 0; nt < 4; ++nt)
          acc1[mt][nt] = __builtin_amdgcn_mfma_f32_16x16x32_bf16(a_frag[mt], b_frag[nt], acc1[mt][nt], 0, 0, 0);
    }
    {
      short8 a_frag[2], b_frag[4];
#pragma unroll
      for (int mt = 0; mt < 2; ++mt)
        a_frag[mt] = *(const short8*)(As2[cur] + quad * 512 + (wr * 32 + mt * 16 + l15) * 8);
#pragma unroll
      for (int nt = 0; nt < 4; ++nt)
        b_frag[nt] = *(const short8*)(Bs2h[cur] + quad * 1024 + (wc * 64 + nt * 16 + l15) * 8);
#pragma unroll
      for (int mt = 0; mt < 2; ++mt)
#pragma unroll
        for (int nt = 0; nt < 4; ++nt)
          acc2[mt][nt] = __builtin_amdgcn_mfma_f32_16x16x32_bf16(a_frag[mt], b_frag[nt], acc2[mt][nt], 0, 0, 0);
    }
    __syncthreads();
    cur ^= 1;
  }

  if constexpr (MODE == 1) {
#pragma unroll
    for (int mt = 0; mt < 2; ++mt) {
#pragma unroll
      for (int nt = 0; nt < 4; ++nt) {
        int n = wc * 64 + nt * 16 + l15;
        int mbase = bm + wr * 32 + mt * 16 + quad * 4;
#pragma unroll
        for (int r = 0; r < 4; ++r) {
          size_t idx = (size_t)(mbase + r) * CA + n;
          outp[idx] = acc1[mt][nt][r] * bf2f(g1[idx]) + acc2[mt][nt][r] * bf2f(g2[idx]);
        }
      }
    }
  } else {
    float aval[2][4][4];
#pragma unroll
    for (int mt = 0; mt < 2; ++mt)
#pragma unroll
      for (int nt = 0; nt < 4; ++nt) {
        int n = wc * 64 + nt * 16 + l15;
        int mbase = bm + wr * 32 + mt * 16 + quad * 4;
#pragma unroll
        for (int r = 0; r < 4; ++r) {
          size_t idx = (size_t)(mbase + r) * CA + n;
          aval[mt][nt][r] = acc1[mt][nt][r] * bf2f(g1[idx]) + acc2[mt][nt][r] * bf2f(g2[idx]);
        }
      }
    // row stats: each wave holds a 64-col half of rows wr*32..wr*32+31
#pragma unroll
    for (int mt = 0; mt < 2; ++mt)
#pragma unroll
      for (int r = 0; r < 4; ++r) {
        float s = 0.f, sq = 0.f;
#pragma unroll
        for (int nt = 0; nt < 4; ++nt) { float v = aval[mt][nt][r]; s += v; sq += v * v; }
        s  += __shfl_xor(s, 1);  s  += __shfl_xor(s, 2);  s  += __shfl_xor(s, 4);  s  += __shfl_xor(s, 8);
        sq += __shfl_xor(sq, 1); sq += __shfl_xor(sq, 2); sq += __shfl_xor(sq, 4); sq += __shfl_xor(sq, 8);
        if (l15 == 0) {
          int row = wr * 32 + mt * 16 + quad * 4 + r;
          hsum[wc][row] = s;
          hsq[wc][row]  = sq;
        }
      }
    __syncthreads();
#pragma unroll
    for (int mt = 0; mt < 2; ++mt)
#pragma unroll
      for (int r = 0; r < 4; ++r) {
        int row = wr * 32 + mt * 16 + quad * 4 + r;
        float tot  = hsum[0][row] + hsum[1][row];
        float totq = hsq[0][row]  + hsq[1][row];
        float mean = tot * (1.f / CA);
        float var  = totq * (1.f / CA) - mean * mean;
        float rstd = rsqrtf(var + 1e-5f);
        int mrow = bm + row;
#pragma unroll
        for (int nt = 0; nt < 4; ++nt) {
          int n = wc * 64 + nt * 16 + l15;
          size_t idx = (size_t)mrow * CA + n;
          float nv = (aval[mt][nt][r] - mean) * rstd;
          amod[idx] = f2bf(bf2f(sp0[idx]) * nv + bf2f(sp1[idx]));
          tmod[idx] = f2bf(bf2f(sp3[idx]) * nv + bf2f(sp4[idx]));
        }
      }
  }
}

// ---------------------------------------------------------------------------
// Pair bias for ALL 3 blocks in one pass over p; no LDS transpose, direct
// ushort4 stores.  Grid (4 k-chunks, W, B).
// Output layout: biasT[i][b][w][h][k][q] (bf16).
// ---------------------------------------------------------------------------
__global__ __launch_bounds__(256) void bias3_kernel(const float* __restrict__ p,
                                                    const float* __restrict__ lnz_w,
                                                    const float* __restrict__ lnz_b,
                                                    const float* __restrict__ wb,
                                                    u16* __restrict__ biasT) {
  const int kc = blockIdx.x, w = blockIdx.y, b = blockIdx.z;
  __shared__ float effW[12][16];
  __shared__ float effb[12];
  const int t = threadIdx.x;
  if (t < 192) {
    int i = t >> 6, rem = t & 63, z = rem >> 2, hh = rem & 3;
    effW[i*4 + hh][z] = lnz_w[i*CZ + z] * wb[(i*CZ + z)*HH + hh];
  }
  if (t < 12) {
    int i = t >> 2, hh = t & 3;
    float acc = 0.f;
    for (int z = 0; z < 16; ++z) acc += lnz_b[i*CZ + z] * wb[(i*CZ + z)*HH + hh];
    effb[t] = acc;
  }
  __syncthreads();

  const int kk = t & 31, qg = (t >> 5) * 4;
  const int k = kc * 32 + kk;
  u16 out4[12][4];
#pragma unroll
  for (int r = 0; r < 4; ++r) {
    int qq = qg + r;
    const float4* pr = (const float4*)(p + (size_t)(((b * WW + w) * NQW + qq) * NKW + k) * 16);
    float4 p0 = pr[0], p1 = pr[1], p2 = pr[2], p3 = pr[3];
    float x[16] = {p0.x,p0.y,p0.z,p0.w, p1.x,p1.y,p1.z,p1.w,
                   p2.x,p2.y,p2.z,p2.w, p3.x,p3.y,p3.z,p3.w};
    float sum = 0.f, sq = 0.f;
#pragma unroll
    for (int z = 0; z < 16; ++z) { sum += x[z]; sq += x[z]*x[z]; }
    float mean = sum * (1.f/16.f);
    float var  = sq  * (1.f/16.f) - mean*mean;
    float rstd = rsqrtf(var + 1e-5f);
#pragma unroll
    for (int ih = 0; ih < 12; ++ih) {
      float acc = effb[ih];
#pragma unroll
      for (int z = 0; z < 16; ++z) acc += (x[z]-mean)*rstd * effW[ih][z];
      out4[ih][r] = f2bf(acc);
    }
  }
#pragma unroll
  for (int ih = 0; ih < 12; ++ih) {
    int i = ih >> 2, hh = ih & 3;
    u16* dst = biasT + ((((size_t)i * BB + b) * WW + w) * HH + hh) * 4096 + (size_t)k * 32 + qg;
    ushort4 uv; uv.x = out4[ih][0]; uv.y = out4[ih][1]; uv.z = out4[ih][2]; uv.w = out4[ih][3];
    *(ushort4*)dst = uv;
  }
}

// ---------------------------------------------------------------------------
// MFMA windowed attention, QUERY-SPLIT: one WAVE per (w, h, b, half).
// ---------------------------------------------------------------------------
__global__ __launch_bounds__(64) void attn_mfma(const u16* __restrict__ Qb,
                                                const u16* __restrict__ Kb,
                                                const u16* __restrict__ Vtb,
                                                const u16* __restrict__ Gb,
                                                const u16* __restrict__ biasT,
                                                u16* __restrict__ Ob) {
  const int lin = blockIdx.x;                      // 4096 blocks
  const int swz = (lin & 7) * 512 + (lin >> 3);    // XCD chunk swizzle
  const int b    = swz >> 11;                      // swz = b*2048 + h*512 + w*2 + half
  const int h    = (swz >> 9) & 3;
  const int w    = (swz >> 1) & 255;
  const int half = swz & 1;
  __shared__ u16 Pt[128 * 20];                     // [token][query(16)+pad]
  __shared__ float inv_s[16];
  const int lane = threadIdx.x;
  const int l15 = lane & 15, quad = lane >> 4;
  const int tok0 = w * NQW - 48;

  // Q fragment: 16 queries of this half
  const int qq = w * NQW + half * 16 + l15;
  short8 qf = *(const short8*)(Qb + (size_t)(b * NN + qq) * CA + h * DD + quad * 8);

  floatx4 lg[8] = {};
#pragma unroll
  for (int nt = 0; nt < 8; ++nt) {
    int tk = tok0 + nt * 16 + l15;
    int tc = min(max(tk, 0), NN - 1);
    short8 kf = *(const short8*)(Kb + (size_t)(b * NN + tc) * CA + h * DD + quad * 8);
    lg[nt] = __builtin_amdgcn_mfma_f32_16x16x32_bf16(qf, kf, lg[nt], 0, 0, 0);
  }

  const float scale = 0.17677669529663687f;   // 1/sqrt(32)
  const u16* bb = biasT + ((((size_t)b * WW + w) * HH + h) << 12);
  float mrow[4] = {-3.0e38f, -3.0e38f, -3.0e38f, -3.0e38f};
#pragma unroll
  for (int nt = 0; nt < 8; ++nt) {
    int tk = tok0 + nt * 16 + l15;
    bool valid = (tk >= 0) && (tk < NN);
    ushort4 bv = *(const ushort4*)(bb + (nt * 16 + l15) * 32 + half * 16 + quad * 4);
    float bvf[4] = {bf2f(bv.x), bf2f(bv.y), bf2f(bv.z), bf2f(bv.w)};
#pragma unroll
    for (int r = 0; r < 4; ++r) {
      float l = valid ? (lg[nt][r] * scale + bvf[r]) : -1e9f;
      lg[nt][r] = l;
      mrow[r] = fmaxf(mrow[r], l);
    }
  }
#pragma unroll
  for (int r = 0; r < 4; ++r) {
    float m = mrow[r];
    m = fmaxf(m, __shfl_xor(m, 1));
    m = fmaxf(m, __shfl_xor(m, 2));
    m = fmaxf(m, __shfl_xor(m, 4));
    m = fmaxf(m, __shfl_xor(m, 8));
    mrow[r] = m;
  }

  float srow[4] = {};
#pragma unroll
  for (int nt = 0; nt < 8; ++nt) {
    u16 pv[4];
#pragma unroll
    for (int r = 0; r < 4; ++r) {
      float e = __expf(lg[nt][r] - mrow[r]);
      srow[r] += e;
      pv[r] = f2bf(e);
    }
    ushort4 uv; uv.x = pv[0]; uv.y = pv[1]; uv.z = pv[2]; uv.w = pv[3];
    *(ushort4*)(Pt + (nt * 16 + l15) * 20 + quad * 4) = uv;
  }
#pragma unroll
  for (int r = 0; r < 4; ++r) {
    float ssum = srow[r];
    ssum += __shfl_xor(ssum, 1);
    ssum += __shfl_xor(ssum, 2);
    ssum += __shfl_xor(ssum, 4);
    ssum += __shfl_xor(ssum, 8);
    if (l15 == 0) inv_s[quad * 4 + r] = 1.f / ssum;
  }
  __syncthreads();

  floatx4 oacc[2] = {};
#pragma unroll
  for (int ks = 0; ks < 4; ++ks) {
    short8 pf;
#pragma unroll
    for (int j = 0; j < 8; ++j)
      pf[j] = (short)Pt[(ks * 32 + quad * 8 + j) * 20 + l15];
    int tb = tok0 + ks * 32 + quad * 8;
    tb = min(max(tb, 0), NN - 8);
#pragma unroll
    for (int mtd = 0; mtd < 2; ++mtd) {
      short8 vf = *(const short8*)(Vtb + (size_t)(b * CA + h * DD + mtd * 16 + l15) * NN + tb);
      oacc[mtd] = __builtin_amdgcn_mfma_f32_16x16x32_bf16(vf, pf, oacc[mtd], 0, 0, 0);
    }
  }

#pragma unroll
  for (int mtd = 0; mtd < 2; ++mtd) {
    float inv = inv_s[l15];
    int tok = w * NQW + half * 16 + l15;
    size_t base = (size_t)(b * NN + tok) * CA + h * DD + mtd * 16 + quad * 4;
    ushort4 gv = *(const ushort4*)(Gb + base);
    floatx4 v = oacc[mtd];
    ushort4 o;
    o.x = f2bf(bf2f(gv.x) * v[0] * inv);
    o.y = f2bf(bf2f(gv.y) * v[1] * inv);
    o.z = f2bf(bf2f(gv.z) * v[2] * inv);
    o.w = f2bf(bf2f(gv.w) * v[3] * inv);
    *(ushort4*)(Ob + base) = o;
  }
}

// ---------------------------------------------------------------------------
// Host-side orchestration.
// ---------------------------------------------------------------------------
extern "C" void kernel_launch(void* const* d_in, const int* in_sizes, int n_in,
                              void* d_out, int out_size, void* d_ws, size_t ws_size,
                              hipStream_t stream) {
  const float* q             = (const float*)d_in[0];
  const float* s             = (const float*)d_in[1];
  const float* p             = (const float*)d_in[2];
  const float* adaln_scale_w = (const float*)d_in[3];
  const float* adaln_scale_b = (const float*)d_in[4];
  const float* adaln_shift_w = (const float*)d_in[5];
  const float* wq            = (const float*)d_in[6];
  const float* bq            = (const float*)d_in[7];
  const float* wk            = (const float*)d_in[8];
  const float* wv            = (const float*)d_in[9];
  const float* lnz_w         = (const float*)d_in[10];
  const float* lnz_b         = (const float*)d_in[11];
  const float* wb_pair       = (const float*)d_in[12];
  const float* wg            = (const float*)d_in[13];
  const float* wo            = (const float*)d_in[14];
  const float* sgate_w       = (const float*)d_in[15];
  const float* sgate_b       = (const float*)d_in[16];
  const float* t_scale_w     = (const float*)d_in[17];
  const float* t_scale_b     = (const float*)d_in[18];
  const float* t_shift_w     = (const float*)d_in[19];
  const float* t_wa          = (const float*)d_in[20];
  const float* t_wb          = (const float*)d_in[21];
  const float* t_wo          = (const float*)d_in[22];
  const float* t_sgate_w     = (const float*)d_in[23];
  const float* t_sgate_b     = (const float*)d_in[24];
  float* out = (float*)d_out;

  const size_t MC = (size_t)MR * CA; // 2097152
  float* fws   = (float*)d_ws;
  float* abuf0 = fws;                          // (unused; layout kept)
  float* abuf1 = abuf0 + MC;
  u16* uws     = (u16*)(abuf1 + MC);
  u16* s_ln_bf = uws;                          // MR*CS
  u16* SP      = s_ln_bf + (size_t)MR * CS;    // 18*MC
  u16* amod    = SP + 18*MC;
  u16* tmod    = amod + MC;
  u16* Qb      = tmod + MC;
  u16* Kb      = Qb + MC;
  u16* Vtb     = Kb + MC;                      // [b][128][NN]
  u16* Gb      = Vtb + MC;
  u16* Ob      = Gb + MC;
  u16* HIDb    = Ob + MC;                      // MR*HIDN = 2*MC
  u16* biasT   = HIDb + 2*MC;                  // 3*BB*WW*HH*4096
  u16* wbuf    = biasT + (size_t)3*BB*WW*HH*NQW*NKW;

  const size_t WBLK = 6*(size_t)CA*CS + 5*(size_t)CA*CA + 3*(size_t)CA*HIDN;
  const size_t o_ascale = 0;
  const size_t o_ashift = o_ascale + (size_t)CA*CS;
  const size_t o_sgate  = o_ashift + (size_t)CA*CS;
  const size_t o_tscale = o_sgate  + (size_t)CA*CS;
  const size_t o_tshift = o_tscale + (size_t)CA*CS;
  const size_t o_tsgate = o_tshift + (size_t)CA*CS;
  const size_t o_wq     = o_tsgate + (size_t)CA*CS;
  const size_t o_wk     = o_wq + (size_t)CA*CA;
  const size_t o_wv     = o_wk + (size_t)CA*CA;
  const size_t o_wg     = o_wv + (size_t)CA*CA;
  const size_t o_wo     = o_wg + (size_t)CA*CA;
  const size_t o_twa    = o_wo + (size_t)CA*CA;
  const size_t o_twb    = o_twa + (size_t)HIDN*CA;
  const size_t o_two    = o_twb + (size_t)HIDN*CA;

  // ---- one-time work ----
  ln_s_kernel<<<MR/4, 256, 0, stream>>>(s, s_ln_bf);

  TJobs tj;
  for (int i = 0; i < NBLK; ++i) {
    u16* wb0 = wbuf + (size_t)i * WBLK;
    int b14 = i * 14;
    tj.j[b14+0]  = TJob{adaln_scale_w + (size_t)i*CS*CA, wb0 + o_ascale, CS, CA};
    tj.j[b14+1]  = TJob{adaln_shift_w + (size_t)i*CS*CA, wb0 + o_ashift, CS, CA};
    tj.j[b14+2]  = TJob{sgate_w       + (size_t)i*CS*CA, wb0 + o_sgate,  CS, CA};
    tj.j[b14+3]  = TJob{t_scale_w     + (size_t)i*CS*CA, wb0 + o_tscale, CS, CA};
    tj.j[b14+4]  = TJob{t_shift_w     + (size_t)i*CS*CA, wb0 + o_tshift, CS, CA};
    tj.j[b14+5]  = TJob{t_sgate_w     + (size_t)i*CS*CA, wb0 + o_tsgate, CS, CA};
    tj.j[b14+6]  = TJob{wq   + (size_t)i*CA*CA,   wb0 + o_wq,  CA, CA};
    tj.j[b14+7]  = TJob{wk   + (size_t)i*CA*CA,   wb0 + o_wk,  CA, CA};
    tj.j[b14+8]  = TJob{wv   + (size_t)i*CA*CA,   wb0 + o_wv,  CA, CA};
    tj.j[b14+9]  = TJob{wg   + (size_t)i*CA*CA,   wb0 + o_wg,  CA, CA};
    tj.j[b14+10] = TJob{wo   + (size_t)i*CA*CA,   wb0 + o_wo,  CA, CA};
    tj.j[b14+11] = TJob{t_wa + (size_t)i*CA*HIDN, wb0 + o_twa, CA, HIDN};
    tj.j[b14+12] = TJob{t_wb + (size_t)i*CA*HIDN, wb0 + o_twb, CA, HIDN};
    tj.j[b14+13] = TJob{t_wo + (size_t)i*HIDN*CA, wb0 + o_two, HIDN, CA};
  }
  transpose_bf16<<<dim3(12, 8, 42), 256, 0, stream>>>(tj);

  bias3_kernel<<<dim3(4, WW, BB), 256, 0, stream>>>(p, lnz_w, lnz_b, wb_pair, biasT);

  // 18 s_ln projections, SPLIT into 3 launches of 6 jobs (visibility probe:
  // second-tier kernels >~31us must now surface in the top-5 table).
  for (int i = 0; i < NBLK; ++i) {
    u16* wb0 = wbuf + (size_t)i * WBLK;
    GemmJobs js = {};
    js.j[0] = GemmJob{s_ln_bf, wb0 + o_ascale, nullptr, adaln_scale_b + i*CA, SP + (i*6+0)*MC, CS, CA, 1, 0};
    js.j[1] = GemmJob{s_ln_bf, wb0 + o_ashift, nullptr, nullptr,              SP + (i*6+1)*MC, CS, CA, 0, 0};
    js.j[2] = GemmJob{s_ln_bf, wb0 + o_sgate,  nullptr, sgate_b   + i*CA,     SP + (i*6+2)*MC, CS, CA, 1, 0};
    js.j[3] = GemmJob{s_ln_bf, wb0 + o_tscale, nullptr, t_scale_b + i*CA,     SP + (i*6+3)*MC, CS, CA, 1, 0};
    js.j[4] = GemmJob{s_ln_bf, wb0 + o_tshift, nullptr, nullptr,              SP + (i*6+4)*MC, CS, CA, 0, 0};
    js.j[5] = GemmJob{s_ln_bf, wb0 + o_tsgate, nullptr, t_sgate_b + i*CA,     SP + (i*6+5)*MC, CS, CA, 1, 0};
    gemm_mfma<false><<<dim3(1, MR/128, 6), 256, 0, stream>>>(js);
  }

  // iter 0 modulations come from q via standalone modln
  modln_kernel<<<MR/4, 256, 0, stream>>>(q, SP + 0*MC, SP + 1*MC,
                                         SP + 3*MC, SP + 4*MC, amod, tmod);

  for (int i = 0; i < NBLK; ++i) {
    u16* wb0 = wbuf + (size_t)i * WBLK;

    // Q, K, V(transposed via LDS), G projections -> bf16
    GemmJobs jq = {};
    jq.j[0] = GemmJob{amod, wb0 + o_wq, nullptr, bq + i*CA, Qb,  CA, CA, 0, 0};
    jq.j[1] = GemmJob{amod, wb0 + o_wk, nullptr, nullptr,   Kb,  CA, CA, 0, 0};
    jq.j[2] = GemmJob{amod, wb0 + o_wv, nullptr, nullptr,   Vtb, CA, CA, 5, 0};
    jq.j[3] = GemmJob{amod, wb0 + o_wg, nullptr, nullptr,   Gb,  CA, CA, 1, 0};
    gemm_mfma<false><<<dim3(1, MR/128, 4), 256, 0, stream>>>(jq);

    // hidden = silu(tmod @ t_wa) * (tmod @ t_wb)  -> bf16 (N=256)
    GemmJobs jh = {};
    jh.j[0] = GemmJob{tmod, wb0 + o_twa, wb0 + o_twb, nullptr, HIDb, CA, HIDN, 4, 0};
    gemm_mfma<true><<<dim3(2, MR/128, 1), 256, 0, stream>>>(jh);

    // windowed attention (MFMA, g-gated bf16 out), query-split 1-D grid
    attn_mfma<<<WW * HH * BB * 2, 64, 0, stream>>>(
        Qb, Kb, Vtb, Gb, biasT + (size_t)i * BB*WW*HH*4096, Ob);

    // a = (O @ wo)*sgate + (HID @ two)*tsgate, fused with next-iter modln
    if (i < NBLK - 1) {
      combo_kernel<0><<<dim3(1, MR/64), 256, 0, stream>>>(
          Ob, HIDb, wb0 + o_wo, wb0 + o_two,
          SP + (i*6+2)*MC, SP + (i*6+5)*MC,
          SP + ((i+1)*6+0)*MC, SP + ((i+1)*6+1)*MC,
          SP + ((i+1)*6+3)*MC, SP + ((i+1)*6+4)*MC,
          amod, tmod, nullptr);
    } else {
      combo_kernel<1><<<dim3(1, MR/64), 256, 0, stream>>>(
          Ob, HIDb, wb0 + o_wo, wb0 + o_two,
          SP + (i*6+2)*MC, SP + (i*6+5)*MC,
          nullptr, nullptr, nullptr, nullptr,
          nullptr, nullptr, out);
    }
  }
}